// Round 2
// baseline (2008.352 us; speedup 1.0000x reference)
//
#include <hip/hip_runtime.h>
#include <hip/hip_bf16.h>

// Problem constants
#define NB   2
#define NC   96
#define NW   128
#define NPIX 16384   // 128*128
#define NHD  8
#define CHD  12
#define HIDC 255
#define H2C  510
#define H4C  1020

typedef __hip_bfloat16 bf16;

__device__ __forceinline__ float toF(float v) { return v; }
__device__ __forceinline__ float toF(bf16 v)  { return __bfloat162float(v); }
__device__ __forceinline__ void stV(float* p, float v) { *p = v; }
__device__ __forceinline__ void stV(bf16* p, float v)  { *p = __float2bfloat16(v); }

// ---------------- LayerNorm over channel axis (per pixel) ----------------
__global__ __launch_bounds__(256) void ln_kernel(
    const float* __restrict__ x, const float* __restrict__ g,
    const float* __restrict__ bta, float* __restrict__ out) {
    int t = blockIdx.x * blockDim.x + threadIdx.x;
    if (t >= NB * NPIX) return;
    int b = t / NPIX, p = t % NPIX;
    const float* xb = x + (size_t)b * NC * NPIX + p;
    float s = 0.f, s2 = 0.f;
    for (int c = 0; c < NC; ++c) { float v = xb[(size_t)c * NPIX]; s += v; s2 += v * v; }
    float mu  = s * (1.f / NC);
    float var = s2 * (1.f / NC) - mu * mu;
    float inv = rsqrtf(var + 1e-5f);
    float* ob = out + (size_t)b * NC * NPIX + p;
    for (int c = 0; c < NC; ++c) {
        float v = xb[(size_t)c * NPIX];
        ob[(size_t)c * NPIX] = (v - mu) * inv * g[c] + bta[c];
    }
}

// ---------------- 1x1 conv (pointwise GEMM), 8 oc per thread ----------------
// For per-batch calls: pass pointers pre-offset to the batch and grid.y = ceil(OC/8).
template <typename TIn, typename TOut, bool RES>
__global__ __launch_bounds__(256) void conv1x1_kernel(
    const TIn* __restrict__ in, const float* __restrict__ w,
    const float* __restrict__ res, TOut* __restrict__ out, int IC, int OC) {
    int p = blockIdx.x * blockDim.x + threadIdx.x;
    int nOcB = (OC + 7) >> 3;
    int b    = blockIdx.y / nOcB;
    int oc0  = (blockIdx.y % nOcB) << 3;
    const TIn* inb = in + (size_t)b * IC * NPIX + p;
    float acc[8] = {0.f,0.f,0.f,0.f,0.f,0.f,0.f,0.f};
    for (int ic = 0; ic < IC; ++ic) {
        float v = toF(inb[(size_t)ic * NPIX]);
        #pragma unroll
        for (int j = 0; j < 8; ++j) {
            int oc = oc0 + j;
            float wv = (oc < OC) ? w[(size_t)oc * IC + ic] : 0.f;
            acc[j] += wv * v;
        }
    }
    size_t ob = (size_t)b * OC * NPIX + p;
    #pragma unroll
    for (int j = 0; j < 8; ++j) {
        int oc = oc0 + j;
        if (oc < OC) {
            float v = acc[j];
            if (RES) v += res[(size_t)b * OC * NPIX + (size_t)oc * NPIX + p];
            stV(out + ob + (size_t)oc * NPIX, v);
        }
    }
}

// ---------------- depthwise / grouped-1-in 3x3 conv, zero pad ----------------
// ic = oc / idiv  (idiv=1: depthwise; idiv=2: main_w 2-out-per-group)
// For per-batch calls: pointers pre-offset, grid.y = CHN.
template <typename TIn, typename TOut, bool RELU>
__global__ __launch_bounds__(256) void dwconv3x3_kernel(
    const TIn* __restrict__ in, const float* __restrict__ w,
    TOut* __restrict__ out, int CHN, int ICN, int idiv) {
    int p  = blockIdx.x * blockDim.x + threadIdx.x;
    int b  = blockIdx.y / CHN, oc = blockIdx.y % CHN;
    int ic = oc / idiv;
    int y = p >> 7, x = p & (NW - 1);
    const TIn* ib = in + ((size_t)b * ICN + ic) * NPIX;
    const float* wr = w + (size_t)oc * 9;
    float acc = 0.f;
    #pragma unroll
    for (int ky = 0; ky < 3; ++ky) {
        int iy = y + ky - 1;
        if (iy < 0 || iy >= NW) continue;
        #pragma unroll
        for (int kx = 0; kx < 3; ++kx) {
            int ix = x + kx - 1;
            if (ix < 0 || ix >= NW) continue;
            acc += wr[ky * 3 + kx] * toF(ib[iy * NW + ix]);
        }
    }
    if (RELU) acc = fmaxf(acc, 0.f);
    stV(out + ((size_t)b * CHN + oc) * NPIX + p, acc);
}

// ---------------- 3x3 box filter (replicate pad) + high band ----------------
// Per-batch: grid.y = H4C, pointers pre-offset.
__global__ __launch_bounds__(256) void boxhb_kernel(
    const bf16* __restrict__ ym, bf16* __restrict__ l, bf16* __restrict__ hb) {
    int p = blockIdx.x * blockDim.x + threadIdx.x;
    size_t chb = (size_t)blockIdx.y * NPIX;
    int y = p >> 7, x = p & (NW - 1);
    const bf16* ib = ym + chb;
    float acc = 0.f;
    #pragma unroll
    for (int ky = 0; ky < 3; ++ky) {
        int iy = min(max(y + ky - 1, 0), NW - 1);
        #pragma unroll
        for (int kx = 0; kx < 3; ++kx) {
            int ix = min(max(x + kx - 1, 0), NW - 1);
            acc += toF(ib[iy * NW + ix]);
        }
    }
    acc *= (1.f / 9.f);
    float c = toF(ib[y * NW + x]);
    l[chb + p]  = __float2bfloat16(acc);
    hb[chb + p] = __float2bfloat16(c - acc);
}

// ---------------- q/k row L2 norms -> reciprocal scales ----------------
template <typename TIn>
__global__ __launch_bounds__(256) void qknorm_kernel(
    const TIn* __restrict__ qkv2, float* __restrict__ scales) {
    int r = blockIdx.x;           // 0 .. NB*192
    int b = r / 192, ch = r % 192;
    const TIn* src = qkv2 + ((size_t)b * 288 + ch) * NPIX;
    float s = 0.f;
    for (int p = threadIdx.x; p < NPIX; p += 256) { float v = toF(src[p]); s += v * v; }
    #pragma unroll
    for (int off = 32; off > 0; off >>= 1) s += __shfl_down(s, off, 64);
    __shared__ float part[4];
    int wid = threadIdx.x >> 6;
    if ((threadIdx.x & 63) == 0) part[wid] = s;
    __syncthreads();
    if (threadIdx.x == 0) {
        float tot = part[0] + part[1] + part[2] + part[3];
        scales[r] = 1.f / fmaxf(sqrtf(tot), 1e-12f);
    }
}

// ---------------- attn[b,h,i,:] = scaled q_i . k_j * temperature ----------------
template <typename TIn>
__global__ __launch_bounds__(256) void attn_kernel(
    const TIn* __restrict__ qkv2, const float* __restrict__ scales,
    const float* __restrict__ temp, float* __restrict__ attn) {
    int blk = blockIdx.x;  // ((b*NHD+h)*CHD+i)
    int i = blk % CHD; int h = (blk / CHD) % NHD; int b = blk / (CHD * NHD);
    const TIn* q = qkv2 + ((size_t)b * 288 + h * CHD + i) * NPIX;
    const TIn* k = qkv2 + ((size_t)b * 288 + 96 + h * CHD) * NPIX;
    float acc[CHD];
    #pragma unroll
    for (int j = 0; j < CHD; ++j) acc[j] = 0.f;
    for (int p = threadIdx.x; p < NPIX; p += 256) {
        float qv = toF(q[p]);
        #pragma unroll
        for (int j = 0; j < CHD; ++j) acc[j] += qv * toF(k[(size_t)j * NPIX + p]);
    }
    __shared__ float part[4][CHD];
    int wid = threadIdx.x >> 6, lane = threadIdx.x & 63;
    #pragma unroll
    for (int j = 0; j < CHD; ++j) {
        float v = acc[j];
        #pragma unroll
        for (int off = 32; off > 0; off >>= 1) v += __shfl_down(v, off, 64);
        if (lane == 0) part[wid][j] = v;
    }
    __syncthreads();
    if (threadIdx.x < CHD) {
        int j = threadIdx.x;
        float d = part[0][j] + part[1][j] + part[2][j] + part[3][j];
        float val = d * scales[b * 192 + h * CHD + i]
                      * scales[b * 192 + 96 + h * CHD + j] * temp[h];
        attn[(size_t)blk * CHD + j] = val;
    }
}

// ---------------- STS threshold generation + softmax mix ----------------
__global__ __launch_bounds__(256) void sts_kernel(
    const float* __restrict__ attn, const float* __restrict__ tw,
    const float* __restrict__ w1, const float* __restrict__ b1,
    const float* __restrict__ w2, const float* __restrict__ b2,
    float* __restrict__ attn_c) {
    int b = blockIdx.x;
    __shared__ float sat[NHD * CHD * CHD];   // 1152
    __shared__ float avg[NHD];
    __shared__ float thr[4][NHD];
    for (int idx = threadIdx.x; idx < NHD * CHD * CHD; idx += 256)
        sat[idx] = attn[(size_t)b * NHD * CHD * CHD + idx];
    __syncthreads();
    if (threadIdx.x < NHD) {
        float s = 0.f;
        for (int t = 0; t < CHD * CHD; ++t) s += fabsf(sat[threadIdx.x * CHD * CHD + t]);
        avg[threadIdx.x] = s * (1.f / (CHD * CHD));
    }
    __syncthreads();
    if (threadIdx.x < 4) {
        int s = threadIdx.x;
        float t1[NHD];
        for (int hp = 0; hp < NHD; ++hp) {
            float u = b1[s * NHD + hp];
            for (int h = 0; h < NHD; ++h) u += avg[h] * w1[s * 64 + hp * NHD + h];
            t1[hp] = fmaxf(u, 0.f);
        }
        for (int hp = 0; hp < NHD; ++hp) {
            float u = b2[s * NHD + hp];
            for (int h = 0; h < NHD; ++h) u += t1[h] * w2[s * 64 + hp * NHD + h];
            float gg = 1.f / (1.f + expf(-u));
            thr[s][hp] = avg[hp] * gg;
        }
    }
    __syncthreads();
    if (threadIdx.x < NHD * CHD) {
        int h = threadIdx.x / CHD, i = threadIdx.x % CHD;
        const float* arow = sat + (h * CHD + i) * CHD;
        float acc[CHD];
        #pragma unroll
        for (int j = 0; j < CHD; ++j) acc[j] = 0.f;
        for (int s = 0; s < 4; ++s) {
            float comp[CHD]; float m = -1e30f;
            #pragma unroll
            for (int j = 0; j < CHD; ++j) {
                float a = arow[j];
                float sg = (a > 0.f) ? 1.f : ((a < 0.f) ? -1.f : 0.f);
                float c = sg * fmaxf(fabsf(a) - thr[s][h], 0.f);
                comp[j] = c; m = fmaxf(m, c);
            }
            float sum = 0.f;
            #pragma unroll
            for (int j = 0; j < CHD; ++j) { comp[j] = expf(comp[j] - m); sum += comp[j]; }
            float wts = tw[s] / sum;
            #pragma unroll
            for (int j = 0; j < CHD; ++j) acc[j] += wts * comp[j];
        }
        for (int j = 0; j < CHD; ++j)
            attn_c[(size_t)b * NHD * CHD * CHD + (h * CHD + i) * CHD + j] = acc[j];
    }
}

// ---------------- out = attn_c @ v ----------------
template <typename TIn>
__global__ __launch_bounds__(256) void av_kernel(
    const float* __restrict__ attn_c, const TIn* __restrict__ qkv2,
    float* __restrict__ outv) {
    int p  = blockIdx.x * blockDim.x + threadIdx.x;
    int bc = blockIdx.y;           // b*96 + hc
    int b = bc / NC, hc = bc % NC; int h = hc / CHD, i = hc % CHD;
    const float* a = attn_c + ((size_t)(b * NHD + h) * CHD + i) * CHD;
    const TIn* v = qkv2 + ((size_t)b * 288 + 192 + h * CHD) * NPIX;
    float acc = 0.f;
    #pragma unroll
    for (int j = 0; j < CHD; ++j) acc += a[j] * toF(v[(size_t)j * NPIX + p]);
    outv[((size_t)b * NC + hc) * NPIX + p] = acc;
}

// ---------------- ld/hd grouped 4->1 conv -> concat buffer ----------------
// Per-batch: grid.y = H2C, pointers pre-offset.
__global__ __launch_bounds__(256) void ldhd_kernel(
    const bf16* __restrict__ lp, const bf16* __restrict__ hp,
    const float* __restrict__ ldw, const float* __restrict__ hdw,
    bf16* __restrict__ cat) {
    int p  = blockIdx.x * blockDim.x + threadIdx.x;
    int cc = blockIdx.y;
    bool isl = cc < HIDC; int g = isl ? cc : cc - HIDC;
    const float* wr = (isl ? ldw : hdw) + (size_t)g * 36;
    int y = p >> 7, x = p & (NW - 1);
    float acc = 0.f;
    #pragma unroll
    for (int ii = 0; ii < 4; ++ii) {
        int ch = 4 * g + ii;
        // ld input ch: <510 -> lp, >=510 -> hp ; hd input ch: <510 -> hp, >=510 -> lp
        const bf16* src = ((ch < H2C) == isl) ? lp : hp;
        const bf16* ib = src + (size_t)ch * NPIX;
        #pragma unroll
        for (int ky = 0; ky < 3; ++ky) {
            int iy = y + ky - 1;
            if (iy < 0 || iy >= NW) continue;
            #pragma unroll
            for (int kx = 0; kx < 3; ++kx) {
                int ix = x + kx - 1;
                if (ix < 0 || ix >= NW) continue;
                acc += wr[ii * 9 + ky * 3 + kx] * toF(ib[iy * NW + ix]);
            }
        }
    }
    acc = fmaxf(acc, 0.f);
    cat[(size_t)cc * NPIX + p] = __float2bfloat16(acc);
}

// ---------------- launch ----------------
extern "C" void kernel_launch(void* const* d_in, const int* in_sizes, int n_in,
                              void* d_out, int out_size, void* d_ws, size_t ws_size,
                              hipStream_t stream) {
    const float* x       = (const float*)d_in[0];
    const float* norm1_w = (const float*)d_in[1];
    const float* norm1_b = (const float*)d_in[2];
    const float* qkv_w   = (const float*)d_in[3];
    const float* qkv_dw  = (const float*)d_in[4];
    const float* proj_w  = (const float*)d_in[5];
    const float* temp    = (const float*)d_in[6];
    const float* thw     = (const float*)d_in[7];
    const float* aw1     = (const float*)d_in[8];
    const float* ab1     = (const float*)d_in[9];
    const float* aw2     = (const float*)d_in[10];
    const float* ab2     = (const float*)d_in[11];
    const float* norm2_w = (const float*)d_in[12];
    const float* norm2_b = (const float*)d_in[13];
    const float* in_w    = (const float*)d_in[14];
    const float* main_w  = (const float*)d_in[15];
    const float* lp_w    = (const float*)d_in[16];
    const float* hp_w    = (const float*)d_in[17];
    const float* ld_w    = (const float*)d_in[18];
    const float* hd_w    = (const float*)d_in[19];
    const float* out_w   = (const float*)d_in[20];
    float* out = (float*)d_out;

    // ---- workspace layout (total ~113 MB) ----
    char* ws = (char*)d_ws;
    float* x1    = (float*)(ws + 0);            // 12,582,912  fp32 residual stream
    float* xn    = (float*)(ws + 12582912);     // 12,582,912  fp32 LN1 out / attn-out / LN2 out
    bf16*  qkv1  = (bf16*)(ws + 25165824);      // 18,874,368  bf16 288ch; later per-batch yi (16.7MB)
    bf16*  qkv2  = (bf16*)(ws + 44040192);      // 18,874,368  bf16 288ch; later per-batch cat (16.7MB)
    float* scl   = (float*)(ws + 62914560);     // 16 KB
    float* attn  = (float*)(ws + 62930944);     // 16 KB
    float* attnc = (float*)(ws + 62947328);     // 16 KB
    bf16*  fA    = (bf16*)(ws + 62963712);      // 16,711,680  per-batch ym -> lp_out
    bf16*  fB    = (bf16*)(ws + 79675392);      // 16,711,680  per-batch l  -> hp_out
    bf16*  fC    = (bf16*)(ws + 96387072);      // 16,711,680  per-batch hb
    // end: 113,098,752 bytes

    dim3 blk(256);
    // ---- attention half ----
    ln_kernel<<<dim3((NB * NPIX) / 256), blk, 0, stream>>>(x, norm1_w, norm1_b, xn);
    conv1x1_kernel<float, bf16, false><<<dim3(NPIX / 256, NB * 36), blk, 0, stream>>>(
        xn, qkv_w, nullptr, qkv1, 96, 288);
    dwconv3x3_kernel<bf16, bf16, false><<<dim3(NPIX / 256, NB * 288), blk, 0, stream>>>(
        qkv1, qkv_dw, qkv2, 288, 288, 1);
    qknorm_kernel<bf16><<<dim3(NB * 192), blk, 0, stream>>>(qkv2, scl);
    attn_kernel<bf16><<<dim3(NB * NHD * CHD), blk, 0, stream>>>(qkv2, scl, temp, attn);
    sts_kernel<<<dim3(NB), blk, 0, stream>>>(attn, thw, aw1, ab1, aw2, ab2, attnc);
    av_kernel<bf16><<<dim3(NPIX / 256, NB * NC), blk, 0, stream>>>(attnc, qkv2, xn);
    conv1x1_kernel<float, float, true><<<dim3(NPIX / 256, NB * 12), blk, 0, stream>>>(
        xn, proj_w, x, x1, 96, 96);
    // ---- FFN half ----
    ln_kernel<<<dim3((NB * NPIX) / 256), blk, 0, stream>>>(x1, norm2_w, norm2_b, xn);
    for (int b = 0; b < NB; ++b) {
        const float* ynb = xn + (size_t)b * NC * NPIX;
        bf16* yi  = qkv1;   // 16.7 MB per-batch, fits in 18.87 MB slot
        bf16* cat = qkv2;
        conv1x1_kernel<float, bf16, false><<<dim3(NPIX / 256, 64), blk, 0, stream>>>(
            ynb, in_w, nullptr, yi, 96, 510);
        dwconv3x3_kernel<bf16, bf16, true><<<dim3(NPIX / 256, H4C), blk, 0, stream>>>(
            yi, main_w, fA, H4C, H2C, 2);                      // ym -> fA
        boxhb_kernel<<<dim3(NPIX / 256, H4C), blk, 0, stream>>>(fA, fB, fC);  // l->fB, hb->fC
        dwconv3x3_kernel<bf16, bf16, true><<<dim3(NPIX / 256, H4C), blk, 0, stream>>>(
            fB, lp_w, fA, H4C, H4C, 1);                        // lp: reads l(fB), writes fA (ym dead)
        dwconv3x3_kernel<bf16, bf16, true><<<dim3(NPIX / 256, H4C), blk, 0, stream>>>(
            fC, hp_w, fB, H4C, H4C, 1);                        // hp: reads hb(fC), writes fB (l dead)
        ldhd_kernel<<<dim3(NPIX / 256, H2C), blk, 0, stream>>>(fA, fB, ld_w, hd_w, cat);
        conv1x1_kernel<bf16, float, true><<<dim3(NPIX / 256, 12), blk, 0, stream>>>(
            cat, out_w, x1 + (size_t)b * NC * NPIX, out + (size_t)b * NC * NPIX, H2C, 96);
    }
}

// Round 3
// 729.627 us; speedup vs baseline: 2.7526x; 2.7526x over previous
//
#include <hip/hip_runtime.h>
#include <hip/hip_bf16.h>

// Problem constants
#define NB   2
#define NC   96
#define NW   128
#define NPIX 16384   // 128*128
#define NHD  8
#define CHD  12
#define HIDC 255
#define H2C  510
#define H4C  1020

typedef __hip_bfloat16 bf16;
typedef unsigned short u16;
typedef unsigned int   u32;

__device__ __forceinline__ float bfu(u16 u)  { return __uint_as_float(((u32)u) << 16); }
__device__ __forceinline__ float bflo(u32 u) { return __uint_as_float(u << 16); }
__device__ __forceinline__ float bfhi(u32 u) { return __uint_as_float(u & 0xffff0000u); }
__device__ __forceinline__ u32 packbf(float a, float b) {
    bf16 x = __float2bfloat16(a), y = __float2bfloat16(b);
    u16 ux = *(u16*)&x, uy = *(u16*)&y;
    return (u32)ux | ((u32)uy << 16);
}

// vectorized 4-element load/store helpers (float or bf16 buffers)
__device__ __forceinline__ void load4(const float* p, float f[4]) {
    float4 t = *(const float4*)p; f[0]=t.x; f[1]=t.y; f[2]=t.z; f[3]=t.w;
}
__device__ __forceinline__ void load4(const bf16* p, float f[4]) {
    uint2 t = *(const uint2*)p;
    f[0]=bflo(t.x); f[1]=bfhi(t.x); f[2]=bflo(t.y); f[3]=bfhi(t.y);
}
__device__ __forceinline__ void store4(float* p, const float f[4]) {
    *(float4*)p = make_float4(f[0], f[1], f[2], f[3]);
}
__device__ __forceinline__ void store4(bf16* p, const float f[4]) {
    uint2 t; t.x = packbf(f[0], f[1]); t.y = packbf(f[2], f[3]);
    *(uint2*)p = t;
}

// ---------------- LayerNorm, channel-split blocks ----------------
// block = 256 threads = 32 pixels x 8 channel-groups(12 ch each); grid = NB*NPIX/32
__global__ __launch_bounds__(256) void ln_kernel(
    const float* __restrict__ x, const float* __restrict__ g,
    const float* __restrict__ bta, float* __restrict__ out) {
    int blk = blockIdx.x;
    int b = blk >> 9;                 // 512 blocks per batch
    int p = ((blk & 511) << 5) + (threadIdx.x & 31);
    int cg = threadIdx.x >> 5;        // 0..7
    const float* xb = x + (size_t)b * NC * NPIX + p;
    float v[12]; float s = 0.f, s2 = 0.f;
    #pragma unroll
    for (int j = 0; j < 12; ++j) {
        float t = xb[(size_t)(cg * 12 + j) * NPIX];
        v[j] = t; s += t; s2 += t * t;
    }
    __shared__ float ss[8][32], qq[8][32], smu[32], sinv[32];
    ss[cg][threadIdx.x & 31] = s; qq[cg][threadIdx.x & 31] = s2;
    __syncthreads();
    if (threadIdx.x < 32) {
        float S = 0.f, Q = 0.f;
        #pragma unroll
        for (int k = 0; k < 8; ++k) { S += ss[k][threadIdx.x]; Q += qq[k][threadIdx.x]; }
        float mu = S * (1.f / NC);
        float var = Q * (1.f / NC) - mu * mu;
        smu[threadIdx.x] = mu; sinv[threadIdx.x] = rsqrtf(var + 1e-5f);
    }
    __syncthreads();
    float mu = smu[threadIdx.x & 31], inv = sinv[threadIdx.x & 31];
    float* ob = out + (size_t)b * NC * NPIX + p;
    #pragma unroll
    for (int j = 0; j < 12; ++j) {
        int c = cg * 12 + j;
        ob[(size_t)c * NPIX] = (v[j] - mu) * inv * g[c] + bta[c];
    }
}

// ---------------- 1x1 conv: OCB out-channels x 4 pixels per thread ----------------
template <typename TIn, typename TOut, bool RES, int OCB>
__global__ __launch_bounds__(256) void conv1x1_kernel(
    const TIn* __restrict__ in, const float* __restrict__ w,
    const float* __restrict__ res, TOut* __restrict__ out, int IC, int OC) {
    int p0 = (blockIdx.x * 256 + threadIdx.x) * 4;
    int nOcB = (OC + OCB - 1) / OCB;
    int b    = blockIdx.y / nOcB;
    int oc0  = (blockIdx.y % nOcB) * OCB;
    const TIn* inb = in + (size_t)b * IC * NPIX + p0;
    float acc[OCB][4];
    #pragma unroll
    for (int j = 0; j < OCB; ++j)
        #pragma unroll
        for (int k = 0; k < 4; ++k) acc[j][k] = 0.f;
    #pragma unroll 4
    for (int ic = 0; ic < IC; ++ic) {
        float f[4];
        load4(inb + (size_t)ic * NPIX, f);
        #pragma unroll
        for (int j = 0; j < OCB; ++j) {
            int oc = oc0 + j;
            float wv = (oc < OC) ? w[(size_t)oc * IC + ic] : 0.f;
            #pragma unroll
            for (int k = 0; k < 4; ++k) acc[j][k] += wv * f[k];
        }
    }
    size_t ob = (size_t)b * OC * NPIX + p0;
    #pragma unroll
    for (int j = 0; j < OCB; ++j) {
        int oc = oc0 + j;
        if (oc < OC) {
            float o[4];
            #pragma unroll
            for (int k = 0; k < 4; ++k) o[k] = acc[j][k];
            if (RES) {
                float r[4];
                load4(res + (size_t)b * OC * NPIX + (size_t)oc * NPIX + p0, r);
                #pragma unroll
                for (int k = 0; k < 4; ++k) o[k] += r[k];
            }
            store4(out + ob + (size_t)oc * NPIX, o);
        }
    }
}

// load a 1x10 window row (8 aligned + 2 halo) with zero padding outside
__device__ __forceinline__ void load_row_zpad(const u16* ib, int iy, int x0, float a[10]) {
    if (iy < 0 || iy >= NW) {
        #pragma unroll
        for (int k = 0; k < 10; ++k) a[k] = 0.f;
        return;
    }
    const u16* rp = ib + iy * NW;
    uint4 v = *(const uint4*)(rp + x0);
    a[1]=bflo(v.x); a[2]=bfhi(v.x); a[3]=bflo(v.y); a[4]=bfhi(v.y);
    a[5]=bflo(v.z); a[6]=bfhi(v.z); a[7]=bflo(v.w); a[8]=bfhi(v.w);
    a[0] = (x0 > 0)   ? bfu(rp[x0 - 1]) : 0.f;
    a[9] = (x0 < 120) ? bfu(rp[x0 + 8]) : 0.f;
}

// ---------------- depthwise / grouped-1-in 3x3, zero pad, 8 px/thread ----------------
template <bool RELU>
__global__ __launch_bounds__(256) void dwconv3x3_kernel(
    const u16* __restrict__ in, const float* __restrict__ w,
    u16* __restrict__ out, int CHN, int ICN, int idiv) {
    int p0 = (blockIdx.x * 256 + threadIdx.x) * 8;
    int y = p0 >> 7, x0 = p0 & (NW - 1);
    int b = blockIdx.y / CHN, oc = blockIdx.y % CHN;
    int ic = oc / idiv;
    const u16* ib = in + ((size_t)b * ICN + ic) * NPIX;
    float a[3][10];
    #pragma unroll
    for (int r = 0; r < 3; ++r) load_row_zpad(ib, y + r - 1, x0, a[r]);
    const float* wr = w + (size_t)oc * 9;
    float w9[9];
    #pragma unroll
    for (int k = 0; k < 9; ++k) w9[k] = wr[k];
    float o[8];
    #pragma unroll
    for (int j = 0; j < 8; ++j) {
        float s = 0.f;
        #pragma unroll
        for (int r = 0; r < 3; ++r)
            #pragma unroll
            for (int kx = 0; kx < 3; ++kx) s += w9[r * 3 + kx] * a[r][j + kx];
        o[j] = RELU ? fmaxf(s, 0.f) : s;
    }
    uint4 ov;
    ov.x = packbf(o[0], o[1]); ov.y = packbf(o[2], o[3]);
    ov.z = packbf(o[4], o[5]); ov.w = packbf(o[6], o[7]);
    *(uint4*)(out + ((size_t)b * CHN + oc) * NPIX + p0) = ov;
}

// ---------------- 3x3 box (replicate pad) + high band, 8 px/thread ----------------
__global__ __launch_bounds__(256) void boxhb_kernel(
    const u16* __restrict__ ym, u16* __restrict__ l, u16* __restrict__ hb) {
    int p0 = (blockIdx.x * 256 + threadIdx.x) * 8;
    int y = p0 >> 7, x0 = p0 & (NW - 1);
    const u16* ib = ym + (size_t)blockIdx.y * NPIX;
    float a[3][10];
    #pragma unroll
    for (int r = 0; r < 3; ++r) {
        int iy = min(max(y + r - 1, 0), NW - 1);
        const u16* rp = ib + iy * NW;
        uint4 v = *(const uint4*)(rp + x0);
        a[r][1]=bflo(v.x); a[r][2]=bfhi(v.x); a[r][3]=bflo(v.y); a[r][4]=bfhi(v.y);
        a[r][5]=bflo(v.z); a[r][6]=bfhi(v.z); a[r][7]=bflo(v.w); a[r][8]=bfhi(v.w);
        a[r][0] = bfu(rp[max(x0 - 1, 0)]);
        a[r][9] = bfu(rp[min(x0 + 8, NW - 1)]);
    }
    float lo[8], ho[8];
    #pragma unroll
    for (int j = 0; j < 8; ++j) {
        float s = 0.f;
        #pragma unroll
        for (int r = 0; r < 3; ++r)
            #pragma unroll
            for (int kx = 0; kx < 3; ++kx) s += a[r][j + kx];
        s *= (1.f / 9.f);
        lo[j] = s; ho[j] = a[1][j + 1] - s;
    }
    uint4 lv, hv;
    lv.x = packbf(lo[0], lo[1]); lv.y = packbf(lo[2], lo[3]);
    lv.z = packbf(lo[4], lo[5]); lv.w = packbf(lo[6], lo[7]);
    hv.x = packbf(ho[0], ho[1]); hv.y = packbf(ho[2], ho[3]);
    hv.z = packbf(ho[4], ho[5]); hv.w = packbf(ho[6], ho[7]);
    *(uint4*)(l  + (size_t)blockIdx.y * NPIX + p0) = lv;
    *(uint4*)(hb + (size_t)blockIdx.y * NPIX + p0) = hv;
}

// ---------------- ld/hd grouped 4->1 conv -> concat, 8 px/thread ----------------
__global__ __launch_bounds__(256) void ldhd_kernel(
    const u16* __restrict__ lp, const u16* __restrict__ hp,
    const float* __restrict__ ldw, const float* __restrict__ hdw,
    u16* __restrict__ cat) {
    int p0 = (blockIdx.x * 256 + threadIdx.x) * 8;
    int y = p0 >> 7, x0 = p0 & (NW - 1);
    int cc = blockIdx.y;
    bool isl = cc < HIDC; int g = isl ? cc : cc - HIDC;
    const float* wr = (isl ? ldw : hdw) + (size_t)g * 36;
    float o[8];
    #pragma unroll
    for (int j = 0; j < 8; ++j) o[j] = 0.f;
    #pragma unroll
    for (int ii = 0; ii < 4; ++ii) {
        int ch = 4 * g + ii;
        const u16* src = ((ch < H2C) == isl) ? lp : hp;
        const u16* ib = src + (size_t)ch * NPIX;
        float a[3][10];
        #pragma unroll
        for (int r = 0; r < 3; ++r) load_row_zpad(ib, y + r - 1, x0, a[r]);
        #pragma unroll
        for (int j = 0; j < 8; ++j) {
            float s = 0.f;
            #pragma unroll
            for (int r = 0; r < 3; ++r)
                #pragma unroll
                for (int kx = 0; kx < 3; ++kx) s += wr[ii * 9 + r * 3 + kx] * a[r][j + kx];
            o[j] += s;
        }
    }
    uint4 ov;
    ov.x = packbf(fmaxf(o[0],0.f), fmaxf(o[1],0.f));
    ov.y = packbf(fmaxf(o[2],0.f), fmaxf(o[3],0.f));
    ov.z = packbf(fmaxf(o[4],0.f), fmaxf(o[5],0.f));
    ov.w = packbf(fmaxf(o[6],0.f), fmaxf(o[7],0.f));
    *(uint4*)(cat + (size_t)cc * NPIX + p0) = ov;
}

// ---------------- q/k row L2 norms -> reciprocal scales ----------------
__global__ __launch_bounds__(256) void qknorm_kernel(
    const u16* __restrict__ qkv2, float* __restrict__ scales) {
    int r = blockIdx.x;           // 0 .. NB*192
    int b = r / 192, ch = r % 192;
    const u16* src = qkv2 + ((size_t)b * 288 + ch) * NPIX;
    float s = 0.f;
    for (int p = threadIdx.x * 8; p < NPIX; p += 2048) {
        uint4 v = *(const uint4*)(src + p);
        float f[8];
        f[0]=bflo(v.x); f[1]=bfhi(v.x); f[2]=bflo(v.y); f[3]=bfhi(v.y);
        f[4]=bflo(v.z); f[5]=bfhi(v.z); f[6]=bflo(v.w); f[7]=bfhi(v.w);
        #pragma unroll
        for (int k = 0; k < 8; ++k) s += f[k] * f[k];
    }
    #pragma unroll
    for (int off = 32; off > 0; off >>= 1) s += __shfl_down(s, off, 64);
    __shared__ float part[4];
    int wid = threadIdx.x >> 6;
    if ((threadIdx.x & 63) == 0) part[wid] = s;
    __syncthreads();
    if (threadIdx.x == 0) {
        float tot = part[0] + part[1] + part[2] + part[3];
        scales[r] = 1.f / fmaxf(sqrtf(tot), 1e-12f);
    }
}

// ---------------- attn[b,h,i,:] = scaled q_i . k_j * temperature ----------------
__global__ __launch_bounds__(256) void attn_kernel(
    const u16* __restrict__ qkv2, const float* __restrict__ scales,
    const float* __restrict__ temp, float* __restrict__ attn) {
    int blk = blockIdx.x;  // ((b*NHD+h)*CHD+i)
    int i = blk % CHD; int h = (blk / CHD) % NHD; int b = blk / (CHD * NHD);
    const u16* q = qkv2 + ((size_t)b * 288 + h * CHD + i) * NPIX;
    const u16* k = qkv2 + ((size_t)b * 288 + 96 + h * CHD) * NPIX;
    float acc[CHD];
    #pragma unroll
    for (int j = 0; j < CHD; ++j) acc[j] = 0.f;
    for (int p = threadIdx.x * 8; p < NPIX; p += 2048) {
        uint4 qv = *(const uint4*)(q + p);
        float qf[8];
        qf[0]=bflo(qv.x); qf[1]=bfhi(qv.x); qf[2]=bflo(qv.y); qf[3]=bfhi(qv.y);
        qf[4]=bflo(qv.z); qf[5]=bfhi(qv.z); qf[6]=bflo(qv.w); qf[7]=bfhi(qv.w);
        #pragma unroll
        for (int j = 0; j < CHD; ++j) {
            uint4 kv = *(const uint4*)(k + (size_t)j * NPIX + p);
            float kf[8];
            kf[0]=bflo(kv.x); kf[1]=bfhi(kv.x); kf[2]=bflo(kv.y); kf[3]=bfhi(kv.y);
            kf[4]=bflo(kv.z); kf[5]=bfhi(kv.z); kf[6]=bflo(kv.w); kf[7]=bfhi(kv.w);
            float s = 0.f;
            #pragma unroll
            for (int t = 0; t < 8; ++t) s += qf[t] * kf[t];
            acc[j] += s;
        }
    }
    __shared__ float part[4][CHD];
    int wid = threadIdx.x >> 6, lane = threadIdx.x & 63;
    #pragma unroll
    for (int j = 0; j < CHD; ++j) {
        float v = acc[j];
        #pragma unroll
        for (int off = 32; off > 0; off >>= 1) v += __shfl_down(v, off, 64);
        if (lane == 0) part[wid][j] = v;
    }
    __syncthreads();
    if (threadIdx.x < CHD) {
        int j = threadIdx.x;
        float d = part[0][j] + part[1][j] + part[2][j] + part[3][j];
        float val = d * scales[b * 192 + h * CHD + i]
                      * scales[b * 192 + 96 + h * CHD + j] * temp[h];
        attn[(size_t)blk * CHD + j] = val;
    }
}

// ---------------- STS threshold generation + softmax mix ----------------
__global__ __launch_bounds__(256) void sts_kernel(
    const float* __restrict__ attn, const float* __restrict__ tw,
    const float* __restrict__ w1, const float* __restrict__ b1,
    const float* __restrict__ w2, const float* __restrict__ b2,
    float* __restrict__ attn_c) {
    int b = blockIdx.x;
    __shared__ float sat[NHD * CHD * CHD];   // 1152
    __shared__ float avg[NHD];
    __shared__ float thr[4][NHD];
    for (int idx = threadIdx.x; idx < NHD * CHD * CHD; idx += 256)
        sat[idx] = attn[(size_t)b * NHD * CHD * CHD + idx];
    __syncthreads();
    if (threadIdx.x < NHD) {
        float s = 0.f;
        for (int t = 0; t < CHD * CHD; ++t) s += fabsf(sat[threadIdx.x * CHD * CHD + t]);
        avg[threadIdx.x] = s * (1.f / (CHD * CHD));
    }
    __syncthreads();
    if (threadIdx.x < 4) {
        int s = threadIdx.x;
        float t1[NHD];
        for (int hp = 0; hp < NHD; ++hp) {
            float u = b1[s * NHD + hp];
            for (int h = 0; h < NHD; ++h) u += avg[h] * w1[s * 64 + hp * NHD + h];
            t1[hp] = fmaxf(u, 0.f);
        }
        for (int hp = 0; hp < NHD; ++hp) {
            float u = b2[s * NHD + hp];
            for (int h = 0; h < NHD; ++h) u += t1[h] * w2[s * 64 + hp * NHD + h];
            float gg = 1.f / (1.f + expf(-u));
            thr[s][hp] = avg[hp] * gg;
        }
    }
    __syncthreads();
    if (threadIdx.x < NHD * CHD) {
        int h = threadIdx.x / CHD, i = threadIdx.x % CHD;
        const float* arow = sat + (h * CHD + i) * CHD;
        float acc[CHD];
        #pragma unroll
        for (int j = 0; j < CHD; ++j) acc[j] = 0.f;
        for (int s = 0; s < 4; ++s) {
            float comp[CHD]; float m = -1e30f;
            #pragma unroll
            for (int j = 0; j < CHD; ++j) {
                float a = arow[j];
                float sg = (a > 0.f) ? 1.f : ((a < 0.f) ? -1.f : 0.f);
                float c = sg * fmaxf(fabsf(a) - thr[s][h], 0.f);
                comp[j] = c; m = fmaxf(m, c);
            }
            float sum = 0.f;
            #pragma unroll
            for (int j = 0; j < CHD; ++j) { comp[j] = expf(comp[j] - m); sum += comp[j]; }
            float wts = tw[s] / sum;
            #pragma unroll
            for (int j = 0; j < CHD; ++j) acc[j] += wts * comp[j];
        }
        for (int j = 0; j < CHD; ++j)
            attn_c[(size_t)b * NHD * CHD * CHD + (h * CHD + i) * CHD + j] = acc[j];
    }
}

// ---------------- out = attn_c @ v, 4 px/thread ----------------
__global__ __launch_bounds__(256) void av_kernel(
    const float* __restrict__ attn_c, const u16* __restrict__ qkv2,
    float* __restrict__ outv) {
    int p0 = (blockIdx.x * 256 + threadIdx.x) * 4;
    int bc = blockIdx.y;           // b*96 + hc
    int b = bc / NC, hc = bc % NC; int h = hc / CHD, i = hc % CHD;
    const float* a = attn_c + ((size_t)(b * NHD + h) * CHD + i) * CHD;
    const u16* v = qkv2 + ((size_t)b * 288 + 192 + h * CHD) * NPIX;
    float av[CHD];
    #pragma unroll
    for (int j = 0; j < CHD; ++j) av[j] = a[j];
    float o[4] = {0.f, 0.f, 0.f, 0.f};
    #pragma unroll
    for (int j = 0; j < CHD; ++j) {
        uint2 t = *(const uint2*)(v + (size_t)j * NPIX + p0);
        o[0] += av[j] * bflo(t.x); o[1] += av[j] * bfhi(t.x);
        o[2] += av[j] * bflo(t.y); o[3] += av[j] * bfhi(t.y);
    }
    *(float4*)(outv + ((size_t)b * NC + hc) * NPIX + p0) = make_float4(o[0], o[1], o[2], o[3]);
}

// ---------------- launch ----------------
extern "C" void kernel_launch(void* const* d_in, const int* in_sizes, int n_in,
                              void* d_out, int out_size, void* d_ws, size_t ws_size,
                              hipStream_t stream) {
    const float* x       = (const float*)d_in[0];
    const float* norm1_w = (const float*)d_in[1];
    const float* norm1_b = (const float*)d_in[2];
    const float* qkv_w   = (const float*)d_in[3];
    const float* qkv_dw  = (const float*)d_in[4];
    const float* proj_w  = (const float*)d_in[5];
    const float* temp    = (const float*)d_in[6];
    const float* thw     = (const float*)d_in[7];
    const float* aw1     = (const float*)d_in[8];
    const float* ab1     = (const float*)d_in[9];
    const float* aw2     = (const float*)d_in[10];
    const float* ab2     = (const float*)d_in[11];
    const float* norm2_w = (const float*)d_in[12];
    const float* norm2_b = (const float*)d_in[13];
    const float* in_w    = (const float*)d_in[14];
    const float* main_w  = (const float*)d_in[15];
    const float* lp_w    = (const float*)d_in[16];
    const float* hp_w    = (const float*)d_in[17];
    const float* ld_w    = (const float*)d_in[18];
    const float* hd_w    = (const float*)d_in[19];
    const float* out_w   = (const float*)d_in[20];
    float* out = (float*)d_out;

    // ---- workspace layout (total ~113 MB) ----
    char* ws = (char*)d_ws;
    float* x1    = (float*)(ws + 0);            // 12.6 MB fp32 residual stream
    float* xn    = (float*)(ws + 12582912);     // 12.6 MB LN out / attn-out
    bf16*  qkv1  = (bf16*)(ws + 25165824);      // 18.9 MB bf16 288ch; later per-batch yi
    bf16*  qkv2  = (bf16*)(ws + 44040192);      // 18.9 MB bf16 288ch; later per-batch cat
    float* scl   = (float*)(ws + 62914560);
    float* attn  = (float*)(ws + 62930944);
    float* attnc = (float*)(ws + 62947328);
    bf16*  fA    = (bf16*)(ws + 62963712);      // 16.7 MB per-batch ym -> lp_out
    bf16*  fB    = (bf16*)(ws + 79675392);      // 16.7 MB per-batch l  -> hp_out
    bf16*  fC    = (bf16*)(ws + 96387072);      // 16.7 MB per-batch hb

    dim3 blk(256);
    // ---- attention half ----
    ln_kernel<<<dim3(NB * NPIX / 32), blk, 0, stream>>>(x, norm1_w, norm1_b, xn);
    conv1x1_kernel<float, bf16, false, 8><<<dim3(16, NB * 36), blk, 0, stream>>>(
        xn, qkv_w, nullptr, qkv1, 96, 288);
    dwconv3x3_kernel<false><<<dim3(8, NB * 288), blk, 0, stream>>>(
        (const u16*)qkv1, qkv_dw, (u16*)qkv2, 288, 288, 1);
    qknorm_kernel<<<dim3(NB * 192), blk, 0, stream>>>((const u16*)qkv2, scl);
    attn_kernel<<<dim3(NB * NHD * CHD), blk, 0, stream>>>((const u16*)qkv2, scl, temp, attn);
    sts_kernel<<<dim3(NB), blk, 0, stream>>>(attn, thw, aw1, ab1, aw2, ab2, attnc);
    av_kernel<<<dim3(16, NB * NC), blk, 0, stream>>>(attnc, (const u16*)qkv2, xn);
    conv1x1_kernel<float, float, true, 4><<<dim3(16, NB * 24), blk, 0, stream>>>(
        xn, proj_w, x, x1, 96, 96);
    // ---- FFN half ----
    ln_kernel<<<dim3(NB * NPIX / 32), blk, 0, stream>>>(x1, norm2_w, norm2_b, xn);
    for (int b = 0; b < NB; ++b) {
        const float* ynb = xn + (size_t)b * NC * NPIX;
        bf16* yi  = qkv1;   // per-batch reuse
        bf16* cat = qkv2;
        conv1x1_kernel<float, bf16, false, 8><<<dim3(16, 64), blk, 0, stream>>>(
            ynb, in_w, nullptr, yi, 96, 510);
        dwconv3x3_kernel<true><<<dim3(8, H4C), blk, 0, stream>>>(
            (const u16*)yi, main_w, (u16*)fA, H4C, H2C, 2);
        boxhb_kernel<<<dim3(8, H4C), blk, 0, stream>>>((const u16*)fA, (u16*)fB, (u16*)fC);
        dwconv3x3_kernel<true><<<dim3(8, H4C), blk, 0, stream>>>(
            (const u16*)fB, lp_w, (u16*)fA, H4C, H4C, 1);
        dwconv3x3_kernel<true><<<dim3(8, H4C), blk, 0, stream>>>(
            (const u16*)fC, hp_w, (u16*)fB, H4C, H4C, 1);
        ldhd_kernel<<<dim3(8, H2C), blk, 0, stream>>>(
            (const u16*)fA, (const u16*)fB, ld_w, hd_w, (u16*)cat);
        conv1x1_kernel<bf16, float, true, 4><<<dim3(16, 24), blk, 0, stream>>>(
            cat, out_w, x1 + (size_t)b * NC * NPIX, out + (size_t)b * NC * NPIX, H2C, 96);
    }
}

// Round 4
// 700.145 us; speedup vs baseline: 2.8685x; 1.0421x over previous
//
#include <hip/hip_runtime.h>
#include <hip/hip_bf16.h>

// Problem constants
#define NB   2
#define NC   96
#define NW   128
#define NPIX 16384   // 128*128
#define NHD  8
#define CHD  12
#define HIDC 255
#define H2C  510
#define H4C  1020

typedef __hip_bfloat16 bf16;
typedef unsigned short u16;
typedef unsigned int   u32;

__device__ __forceinline__ float bfu(u16 u)  { return __uint_as_float(((u32)u) << 16); }
__device__ __forceinline__ float bflo(u32 u) { return __uint_as_float(u << 16); }
__device__ __forceinline__ float bfhi(u32 u) { return __uint_as_float(u & 0xffff0000u); }
__device__ __forceinline__ u32 packbf(float a, float b) {
    bf16 x = __float2bfloat16(a), y = __float2bfloat16(b);
    u16 ux = *(u16*)&x, uy = *(u16*)&y;
    return (u32)ux | ((u32)uy << 16);
}
__device__ __forceinline__ void load4(const float* p, float f[4]) {
    float4 t = *(const float4*)p; f[0]=t.x; f[1]=t.y; f[2]=t.z; f[3]=t.w;
}
__device__ __forceinline__ void load4(const u16* p, float f[4]) {
    uint2 t = *(const uint2*)p;
    f[0]=bflo(t.x); f[1]=bfhi(t.x); f[2]=bflo(t.y); f[3]=bfhi(t.y);
}
__device__ __forceinline__ void store4(float* p, const float f[4]) {
    *(float4*)p = make_float4(f[0], f[1], f[2], f[3]);
}
__device__ __forceinline__ void store4(u16* p, const float f[4]) {
    uint2 t; t.x = packbf(f[0], f[1]); t.y = packbf(f[2], f[3]);
    *(uint2*)p = t;
}

// ---------------- LayerNorm (fp32 in, bf16 out), channel-split blocks ----------------
// block = 256 threads = 32 pixels x 8 channel-groups(12 ch); grid = NB*NPIX/32
__global__ __launch_bounds__(256) void ln_kernel(
    const float* __restrict__ x, const float* __restrict__ g,
    const float* __restrict__ bta, u16* __restrict__ out) {
    int blk = blockIdx.x;
    int b = blk >> 9;
    int p = ((blk & 511) << 5) + (threadIdx.x & 31);
    int cg = threadIdx.x >> 5;
    const float* xb = x + (size_t)b * NC * NPIX + p;
    float v[12]; float s = 0.f, s2 = 0.f;
    #pragma unroll
    for (int j = 0; j < 12; ++j) {
        float t = xb[(size_t)(cg * 12 + j) * NPIX];
        v[j] = t; s += t; s2 += t * t;
    }
    __shared__ float ss[8][32], qq[8][32], smu[32], sinv[32];
    ss[cg][threadIdx.x & 31] = s; qq[cg][threadIdx.x & 31] = s2;
    __syncthreads();
    if (threadIdx.x < 32) {
        float S = 0.f, Q = 0.f;
        #pragma unroll
        for (int k = 0; k < 8; ++k) { S += ss[k][threadIdx.x]; Q += qq[k][threadIdx.x]; }
        float mu = S * (1.f / NC);
        float var = Q * (1.f / NC) - mu * mu;
        smu[threadIdx.x] = mu; sinv[threadIdx.x] = rsqrtf(var + 1e-5f);
    }
    __syncthreads();
    float mu = smu[threadIdx.x & 31], inv = sinv[threadIdx.x & 31];
    u16* ob = out + (size_t)b * NC * NPIX + p;
    #pragma unroll
    for (int j = 0; j < 12; ++j) {
        int c = cg * 12 + j;
        float o = (v[j] - mu) * inv * g[c] + bta[c];
        bf16 h = __float2bfloat16(o);
        ob[(size_t)c * NPIX] = *(u16*)&h;
    }
}

// ---------------- 1x1 conv, split-K over 4 waves + LDS reduce ----------------
// bf16 input planes. Block: 256 thr; lane covers 4 px, wave covers IC/4 chunk.
// grid.x = NPIX/256 = 64, grid.y = batches * ceil(OC/OCB)
template <typename TOut, bool RES, int OCB>
__global__ __launch_bounds__(256) void conv1x1_kernel(
    const u16* __restrict__ in, const float* __restrict__ w,
    const float* __restrict__ res, TOut* __restrict__ out, int IC, int OC) {
    __shared__ float red[3][64][33];
    int wave = threadIdx.x >> 6, lane = threadIdx.x & 63;
    int nOcG = (OC + OCB - 1) / OCB;
    int b   = blockIdx.y / nOcG;
    int oc0 = (blockIdx.y % nOcG) * OCB;
    int px0 = blockIdx.x * 256 + lane * 4;
    const u16* inb = in + (size_t)b * IC * NPIX + px0;
    int KC  = (IC + 3) >> 2;
    int ic0 = wave * KC, ic1 = min(ic0 + KC, IC);
    float acc[OCB][4];
    #pragma unroll
    for (int j = 0; j < OCB; ++j)
        #pragma unroll
        for (int k = 0; k < 4; ++k) acc[j][k] = 0.f;
    #pragma unroll 8
    for (int ic = ic0; ic < ic1; ++ic) {
        uint2 t = *(const uint2*)(inb + (size_t)ic * NPIX);
        float f0 = bflo(t.x), f1 = bfhi(t.x), f2 = bflo(t.y), f3 = bfhi(t.y);
        #pragma unroll
        for (int j = 0; j < OCB; ++j) {
            int oc = oc0 + j;
            float wv = (oc < OC) ? w[(size_t)oc * IC + ic] : 0.f;
            acc[j][0] += wv * f0; acc[j][1] += wv * f1;
            acc[j][2] += wv * f2; acc[j][3] += wv * f3;
        }
    }
    if (wave > 0) {
        #pragma unroll
        for (int j = 0; j < OCB; ++j)
            #pragma unroll
            for (int k = 0; k < 4; ++k) red[wave - 1][lane][j * 4 + k] = acc[j][k];
    }
    __syncthreads();
    if (wave == 0) {
        #pragma unroll
        for (int j = 0; j < OCB; ++j) {
            int oc = oc0 + j;
            if (oc < OC) {
                float o[4];
                #pragma unroll
                for (int k = 0; k < 4; ++k)
                    o[k] = acc[j][k] + red[0][lane][j * 4 + k]
                         + red[1][lane][j * 4 + k] + red[2][lane][j * 4 + k];
                if (RES) {
                    float r[4];
                    load4(res + (size_t)b * OC * NPIX + (size_t)oc * NPIX + px0, r);
                    #pragma unroll
                    for (int k = 0; k < 4; ++k) o[k] += r[k];
                }
                store4(out + (size_t)b * OC * NPIX + (size_t)oc * NPIX + px0, o);
            }
        }
    }
}

// load a 1x10 window row (8 aligned + 2 halo) with zero padding outside
__device__ __forceinline__ void load_row_zpad(const u16* ib, int iy, int x0, float a[10]) {
    if (iy < 0 || iy >= NW) {
        #pragma unroll
        for (int k = 0; k < 10; ++k) a[k] = 0.f;
        return;
    }
    const u16* rp = ib + iy * NW;
    uint4 v = *(const uint4*)(rp + x0);
    a[1]=bflo(v.x); a[2]=bfhi(v.x); a[3]=bflo(v.y); a[4]=bfhi(v.y);
    a[5]=bflo(v.z); a[6]=bfhi(v.z); a[7]=bflo(v.w); a[8]=bfhi(v.w);
    a[0] = (x0 > 0)   ? bfu(rp[x0 - 1]) : 0.f;
    a[9] = (x0 < 120) ? bfu(rp[x0 + 8]) : 0.f;
}

// ---------------- depthwise / grouped-1-in 3x3, zero pad, 2 rows x 8 px/thread ----------------
// grid (4, batches*CHN)
template <bool RELU>
__global__ __launch_bounds__(256) void dwconv3x3_kernel(
    const u16* __restrict__ in, const float* __restrict__ w,
    u16* __restrict__ out, int CHN, int ICN, int idiv) {
    int id = blockIdx.x * 256 + threadIdx.x;   // 0..1023
    int ty = id >> 4, tx = id & 15;
    int y0 = ty * 2, x0 = tx * 8;
    int b = blockIdx.y / CHN, oc = blockIdx.y % CHN;
    int ic = oc / idiv;
    const u16* ib = in + ((size_t)b * ICN + ic) * NPIX;
    float a[4][10];
    #pragma unroll
    for (int k = 0; k < 4; ++k) load_row_zpad(ib, y0 - 1 + k, x0, a[k]);
    const float* wr = w + (size_t)oc * 9;
    float w9[9];
    #pragma unroll
    for (int k = 0; k < 9; ++k) w9[k] = wr[k];
    float o0[8], o1[8];
    #pragma unroll
    for (int j = 0; j < 8; ++j) {
        float s0 = 0.f, s1 = 0.f;
        #pragma unroll
        for (int r = 0; r < 3; ++r)
            #pragma unroll
            for (int kx = 0; kx < 3; ++kx) {
                s0 += w9[r * 3 + kx] * a[r][j + kx];
                s1 += w9[r * 3 + kx] * a[r + 1][j + kx];
            }
        o0[j] = RELU ? fmaxf(s0, 0.f) : s0;
        o1[j] = RELU ? fmaxf(s1, 0.f) : s1;
    }
    u16* ob = out + ((size_t)b * CHN + oc) * NPIX + y0 * NW + x0;
    uint4 v0, v1;
    v0.x = packbf(o0[0], o0[1]); v0.y = packbf(o0[2], o0[3]);
    v0.z = packbf(o0[4], o0[5]); v0.w = packbf(o0[6], o0[7]);
    v1.x = packbf(o1[0], o1[1]); v1.y = packbf(o1[2], o1[3]);
    v1.z = packbf(o1[4], o1[5]); v1.w = packbf(o1[6], o1[7]);
    *(uint4*)ob = v0;
    *(uint4*)(ob + NW) = v1;
}

// ---------------- fused: 3x3 box (replicate) -> l, hb; 3x3 lp/hp conv (zero pad) + relu ----------
// grid (8, H4C) per batch. Avoids materializing l/hb.
__global__ __launch_bounds__(256) void boxlh_kernel(
    const u16* __restrict__ ym, const float* __restrict__ lpw_all,
    const float* __restrict__ hpw_all, u16* __restrict__ lpo, u16* __restrict__ hpo) {
    int p0 = (blockIdx.x * 256 + threadIdx.x) * 8;
    int y = p0 >> 7, x0 = p0 & (NW - 1);
    int ch = blockIdx.y;
    const u16* ib = ym + (size_t)ch * NPIX;
    // stream 5 replicate-clamped rows -> row sums + center values
    float rs[5][10];   // 3-wide horizontal sums at centers x0-1+n
    float c3[3][10];   // ym centers for rows y-1..y+1, cols x0-1+n
    #pragma unroll
    for (int k = 0; k < 5; ++k) {
        int ry = min(max(y - 2 + k, 0), NW - 1);
        const u16* rp = ib + ry * NW;
        float ar[12];
        uint4 v = *(const uint4*)(rp + x0);
        ar[2]=bflo(v.x); ar[3]=bfhi(v.x); ar[4]=bflo(v.y); ar[5]=bfhi(v.y);
        ar[6]=bflo(v.z); ar[7]=bfhi(v.z); ar[8]=bflo(v.w); ar[9]=bfhi(v.w);
        if (x0 >= 2) { ar[0] = bfu(rp[x0 - 2]); ar[1] = bfu(rp[x0 - 1]); }
        else         { ar[0] = ar[2];           ar[1] = ar[2]; }          // x0==0
        if (x0 <= 118) { ar[10] = bfu(rp[x0 + 8]); ar[11] = bfu(rp[x0 + 9]); }
        else           { ar[10] = ar[9];           ar[11] = ar[9]; }      // x0==120
        #pragma unroll
        for (int n = 0; n < 10; ++n) rs[k][n] = ar[n] + ar[n + 1] + ar[n + 2];
        if (k >= 1 && k <= 3) {
            #pragma unroll
            for (int n = 0; n < 10; ++n) c3[k - 1][n] = ar[n + 1];
        }
    }
    const float* lw = lpw_all + (size_t)ch * 9;
    const float* hw = hpw_all + (size_t)ch * 9;
    float wl[9], wh[9];
    #pragma unroll
    for (int k = 0; k < 9; ++k) { wl[k] = lw[k]; wh[k] = hw[k]; }
    float lo[8], ho[8];
    #pragma unroll
    for (int j2 = 0; j2 < 8; ++j2) { lo[j2] = 0.f; ho[j2] = 0.f; }
    #pragma unroll
    for (int j = 0; j < 3; ++j) {       // l/hb row y-1+j
        int r = y - 1 + j;
        bool rowok = (r >= 0) && (r < NW);
        float lrow[10], hrow[10];
        #pragma unroll
        for (int n = 0; n < 10; ++n) {
            int c = x0 - 1 + n;
            bool ok = rowok && (c >= 0) && (c < NW);
            float lv = (rs[j][n] + rs[j + 1][n] + rs[j + 2][n]) * (1.f / 9.f);
            lrow[n] = ok ? lv : 0.f;
            hrow[n] = ok ? (c3[j][n] - lv) : 0.f;
        }
        #pragma unroll
        for (int p = 0; p < 8; ++p)
            #pragma unroll
            for (int d = 0; d < 3; ++d) {
                lo[p] += wl[j * 3 + d] * lrow[p + d];
                ho[p] += wh[j * 3 + d] * hrow[p + d];
            }
    }
    uint4 lv4, hv4;
    lv4.x = packbf(fmaxf(lo[0],0.f), fmaxf(lo[1],0.f));
    lv4.y = packbf(fmaxf(lo[2],0.f), fmaxf(lo[3],0.f));
    lv4.z = packbf(fmaxf(lo[4],0.f), fmaxf(lo[5],0.f));
    lv4.w = packbf(fmaxf(lo[6],0.f), fmaxf(lo[7],0.f));
    hv4.x = packbf(fmaxf(ho[0],0.f), fmaxf(ho[1],0.f));
    hv4.y = packbf(fmaxf(ho[2],0.f), fmaxf(ho[3],0.f));
    hv4.z = packbf(fmaxf(ho[4],0.f), fmaxf(ho[5],0.f));
    hv4.w = packbf(fmaxf(ho[6],0.f), fmaxf(ho[7],0.f));
    *(uint4*)(lpo + (size_t)ch * NPIX + p0) = lv4;
    *(uint4*)(hpo + (size_t)ch * NPIX + p0) = hv4;
}

// ---------------- ld/hd grouped 4->1 conv -> concat, 8 px/thread (per batch) --------------
__global__ __launch_bounds__(256) void ldhd_kernel(
    const u16* __restrict__ lp, const u16* __restrict__ hp,
    const float* __restrict__ ldw, const float* __restrict__ hdw,
    u16* __restrict__ cat) {
    int p0 = (blockIdx.x * 256 + threadIdx.x) * 8;
    int y = p0 >> 7, x0 = p0 & (NW - 1);
    int cc = blockIdx.y;
    bool isl = cc < HIDC; int g = isl ? cc : cc - HIDC;
    const float* wr = (isl ? ldw : hdw) + (size_t)g * 36;
    float o[8];
    #pragma unroll
    for (int j = 0; j < 8; ++j) o[j] = 0.f;
    #pragma unroll
    for (int ii = 0; ii < 4; ++ii) {
        int ch = 4 * g + ii;
        const u16* src = ((ch < H2C) == isl) ? lp : hp;
        const u16* ib = src + (size_t)ch * NPIX;
        float a[3][10];
        #pragma unroll
        for (int r = 0; r < 3; ++r) load_row_zpad(ib, y + r - 1, x0, a[r]);
        #pragma unroll
        for (int j = 0; j < 8; ++j) {
            float s = 0.f;
            #pragma unroll
            for (int r = 0; r < 3; ++r)
                #pragma unroll
                for (int kx = 0; kx < 3; ++kx) s += wr[ii * 9 + r * 3 + kx] * a[r][j + kx];
            o[j] += s;
        }
    }
    uint4 ov;
    ov.x = packbf(fmaxf(o[0],0.f), fmaxf(o[1],0.f));
    ov.y = packbf(fmaxf(o[2],0.f), fmaxf(o[3],0.f));
    ov.z = packbf(fmaxf(o[4],0.f), fmaxf(o[5],0.f));
    ov.w = packbf(fmaxf(o[6],0.f), fmaxf(o[7],0.f));
    *(uint4*)(cat + (size_t)cc * NPIX + p0) = ov;
}

// ---------------- q/k row L2 norms -> reciprocal scales ----------------
__global__ __launch_bounds__(256) void qknorm_kernel(
    const u16* __restrict__ qkv2, float* __restrict__ scales) {
    int r = blockIdx.x;           // 0 .. NB*192
    int b = r / 192, ch = r % 192;
    const u16* src = qkv2 + ((size_t)b * 288 + ch) * NPIX;
    float s = 0.f;
    for (int p = threadIdx.x * 8; p < NPIX; p += 2048) {
        uint4 v = *(const uint4*)(src + p);
        float f[8];
        f[0]=bflo(v.x); f[1]=bfhi(v.x); f[2]=bflo(v.y); f[3]=bfhi(v.y);
        f[4]=bflo(v.z); f[5]=bfhi(v.z); f[6]=bflo(v.w); f[7]=bfhi(v.w);
        #pragma unroll
        for (int k = 0; k < 8; ++k) s += f[k] * f[k];
    }
    #pragma unroll
    for (int off = 32; off > 0; off >>= 1) s += __shfl_down(s, off, 64);
    __shared__ float part[4];
    int wid = threadIdx.x >> 6;
    if ((threadIdx.x & 63) == 0) part[wid] = s;
    __syncthreads();
    if (threadIdx.x == 0) {
        float tot = part[0] + part[1] + part[2] + part[3];
        scales[r] = 1.f / fmaxf(sqrtf(tot), 1e-12f);
    }
}

// ---------------- attn[b,h,i,:] = scaled q_i . k_j * temperature ----------------
__global__ __launch_bounds__(256) void attn_kernel(
    const u16* __restrict__ qkv2, const float* __restrict__ scales,
    const float* __restrict__ temp, float* __restrict__ attn) {
    int blk = blockIdx.x;  // ((b*NHD+h)*CHD+i)
    int i = blk % CHD; int h = (blk / CHD) % NHD; int b = blk / (CHD * NHD);
    const u16* q = qkv2 + ((size_t)b * 288 + h * CHD + i) * NPIX;
    const u16* k = qkv2 + ((size_t)b * 288 + 96 + h * CHD) * NPIX;
    float acc[CHD];
    #pragma unroll
    for (int j = 0; j < CHD; ++j) acc[j] = 0.f;
    for (int p = threadIdx.x * 8; p < NPIX; p += 2048) {
        uint4 qv = *(const uint4*)(q + p);
        float qf[8];
        qf[0]=bflo(qv.x); qf[1]=bfhi(qv.x); qf[2]=bflo(qv.y); qf[3]=bfhi(qv.y);
        qf[4]=bflo(qv.z); qf[5]=bfhi(qv.z); qf[6]=bflo(qv.w); qf[7]=bfhi(qv.w);
        #pragma unroll
        for (int j = 0; j < CHD; ++j) {
            uint4 kv = *(const uint4*)(k + (size_t)j * NPIX + p);
            float s = qf[0]*bflo(kv.x) + qf[1]*bfhi(kv.x) + qf[2]*bflo(kv.y) + qf[3]*bfhi(kv.y)
                    + qf[4]*bflo(kv.z) + qf[5]*bfhi(kv.z) + qf[6]*bflo(kv.w) + qf[7]*bfhi(kv.w);
            acc[j] += s;
        }
    }
    __shared__ float part[4][CHD];
    int wid = threadIdx.x >> 6, lane = threadIdx.x & 63;
    #pragma unroll
    for (int j = 0; j < CHD; ++j) {
        float v = acc[j];
        #pragma unroll
        for (int off = 32; off > 0; off >>= 1) v += __shfl_down(v, off, 64);
        if (lane == 0) part[wid][j] = v;
    }
    __syncthreads();
    if (threadIdx.x < CHD) {
        int j = threadIdx.x;
        float d = part[0][j] + part[1][j] + part[2][j] + part[3][j];
        float val = d * scales[b * 192 + h * CHD + i]
                      * scales[b * 192 + 96 + h * CHD + j] * temp[h];
        attn[(size_t)blk * CHD + j] = val;
    }
}

// ---------------- STS threshold generation + softmax mix ----------------
__global__ __launch_bounds__(256) void sts_kernel(
    const float* __restrict__ attn, const float* __restrict__ tw,
    const float* __restrict__ w1, const float* __restrict__ b1,
    const float* __restrict__ w2, const float* __restrict__ b2,
    float* __restrict__ attn_c) {
    int b = blockIdx.x;
    __shared__ float sat[NHD * CHD * CHD];
    __shared__ float avg[NHD];
    __shared__ float thr[4][NHD];
    for (int idx = threadIdx.x; idx < NHD * CHD * CHD; idx += 256)
        sat[idx] = attn[(size_t)b * NHD * CHD * CHD + idx];
    __syncthreads();
    if (threadIdx.x < NHD) {
        float s = 0.f;
        for (int t = 0; t < CHD * CHD; ++t) s += fabsf(sat[threadIdx.x * CHD * CHD + t]);
        avg[threadIdx.x] = s * (1.f / (CHD * CHD));
    }
    __syncthreads();
    if (threadIdx.x < 4) {
        int s = threadIdx.x;
        float t1[NHD];
        for (int hp = 0; hp < NHD; ++hp) {
            float u = b1[s * NHD + hp];
            for (int h = 0; h < NHD; ++h) u += avg[h] * w1[s * 64 + hp * NHD + h];
            t1[hp] = fmaxf(u, 0.f);
        }
        for (int hp = 0; hp < NHD; ++hp) {
            float u = b2[s * NHD + hp];
            for (int h = 0; h < NHD; ++h) u += t1[h] * w2[s * 64 + hp * NHD + h];
            float gg = 1.f / (1.f + expf(-u));
            thr[s][hp] = avg[hp] * gg;
        }
    }
    __syncthreads();
    if (threadIdx.x < NHD * CHD) {
        int h = threadIdx.x / CHD, i = threadIdx.x % CHD;
        const float* arow = sat + (h * CHD + i) * CHD;
        float acc[CHD];
        #pragma unroll
        for (int j = 0; j < CHD; ++j) acc[j] = 0.f;
        for (int s = 0; s < 4; ++s) {
            float comp[CHD]; float m = -1e30f;
            #pragma unroll
            for (int j = 0; j < CHD; ++j) {
                float a = arow[j];
                float sg = (a > 0.f) ? 1.f : ((a < 0.f) ? -1.f : 0.f);
                float c = sg * fmaxf(fabsf(a) - thr[s][h], 0.f);
                comp[j] = c; m = fmaxf(m, c);
            }
            float sum = 0.f;
            #pragma unroll
            for (int j = 0; j < CHD; ++j) { comp[j] = expf(comp[j] - m); sum += comp[j]; }
            float wts = tw[s] / sum;
            #pragma unroll
            for (int j = 0; j < CHD; ++j) acc[j] += wts * comp[j];
        }
        for (int j = 0; j < CHD; ++j)
            attn_c[(size_t)b * NHD * CHD * CHD + (h * CHD + i) * CHD + j] = acc[j];
    }
}

// ---------------- out = attn_c @ v, 4 px/thread, bf16 out ----------------
__global__ __launch_bounds__(256) void av_kernel(
    const float* __restrict__ attn_c, const u16* __restrict__ qkv2,
    u16* __restrict__ outv) {
    int p0 = (blockIdx.x * 256 + threadIdx.x) * 4;
    int bc = blockIdx.y;           // b*96 + hc
    int b = bc / NC, hc = bc % NC; int h = hc / CHD, i = hc % CHD;
    const float* a = attn_c + ((size_t)(b * NHD + h) * CHD + i) * CHD;
    const u16* v = qkv2 + ((size_t)b * 288 + 192 + h * CHD) * NPIX;
    float av[CHD];
    #pragma unroll
    for (int j = 0; j < CHD; ++j) av[j] = a[j];
    float o[4] = {0.f, 0.f, 0.f, 0.f};
    #pragma unroll
    for (int j = 0; j < CHD; ++j) {
        uint2 t = *(const uint2*)(v + (size_t)j * NPIX + p0);
        o[0] += av[j] * bflo(t.x); o[1] += av[j] * bfhi(t.x);
        o[2] += av[j] * bflo(t.y); o[3] += av[j] * bfhi(t.y);
    }
    store4(outv + ((size_t)b * NC + hc) * NPIX + p0, o);
}

// ---------------- launch ----------------
extern "C" void kernel_launch(void* const* d_in, const int* in_sizes, int n_in,
                              void* d_out, int out_size, void* d_ws, size_t ws_size,
                              hipStream_t stream) {
    const float* x       = (const float*)d_in[0];
    const float* norm1_w = (const float*)d_in[1];
    const float* norm1_b = (const float*)d_in[2];
    const float* qkv_w   = (const float*)d_in[3];
    const float* qkv_dw  = (const float*)d_in[4];
    const float* proj_w  = (const float*)d_in[5];
    const float* temp    = (const float*)d_in[6];
    const float* thw     = (const float*)d_in[7];
    const float* aw1     = (const float*)d_in[8];
    const float* ab1     = (const float*)d_in[9];
    const float* aw2     = (const float*)d_in[10];
    const float* ab2     = (const float*)d_in[11];
    const float* norm2_w = (const float*)d_in[12];
    const float* norm2_b = (const float*)d_in[13];
    const float* in_w    = (const float*)d_in[14];
    const float* main_w  = (const float*)d_in[15];
    const float* lp_w    = (const float*)d_in[16];
    const float* hp_w    = (const float*)d_in[17];
    const float* ld_w    = (const float*)d_in[18];
    const float* hd_w    = (const float*)d_in[19];
    const float* out_w   = (const float*)d_in[20];
    float* out = (float*)d_out;

    // ---- workspace layout ----
    char* ws = (char*)d_ws;
    float* x1    = (float*)(ws + 0);            // 12.6 MB fp32 residual stream
    u16*   xnb   = (u16*)(ws + 12582912);       // 6.3 MB bf16 LN out / attn-out
    u16*   qkv1  = (u16*)(ws + 25165824);       // 18.9 MB bf16 288ch; later per-batch yi
    u16*   qkv2  = (u16*)(ws + 44040192);       // 18.9 MB bf16 288ch; later per-batch cat
    float* scl   = (float*)(ws + 62914560);
    float* attn  = (float*)(ws + 62930944);
    float* attnc = (float*)(ws + 62947328);
    u16*   fA    = (u16*)(ws + 62963712);       // 16.7 MB per-batch ym
    u16*   fB    = (u16*)(ws + 79675392);       // 16.7 MB per-batch lp_out
    u16*   fC    = (u16*)(ws + 96387072);       // 16.7 MB per-batch hp_out

    dim3 blk(256);
    // ---- attention half ----
    ln_kernel<<<dim3(NB * NPIX / 32), blk, 0, stream>>>(x, norm1_w, norm1_b, xnb);
    conv1x1_kernel<u16, false, 8><<<dim3(64, NB * 36), blk, 0, stream>>>(
        xnb, qkv_w, nullptr, qkv1, 96, 288);
    dwconv3x3_kernel<false><<<dim3(4, NB * 288), blk, 0, stream>>>(
        qkv1, qkv_dw, qkv2, 288, 288, 1);
    qknorm_kernel<<<dim3(NB * 192), blk, 0, stream>>>(qkv2, scl);
    attn_kernel<<<dim3(NB * NHD * CHD), blk, 0, stream>>>(qkv2, scl, temp, attn);
    sts_kernel<<<dim3(NB), blk, 0, stream>>>(attn, thw, aw1, ab1, aw2, ab2, attnc);
    av_kernel<<<dim3(16, NB * NC), blk, 0, stream>>>(attnc, qkv2, xnb);
    conv1x1_kernel<float, true, 8><<<dim3(64, NB * 12), blk, 0, stream>>>(
        xnb, proj_w, x, x1, 96, 96);
    // ---- FFN half ----
    ln_kernel<<<dim3(NB * NPIX / 32), blk, 0, stream>>>(x1, norm2_w, norm2_b, xnb);
    for (int b = 0; b < NB; ++b) {
        u16* yi  = qkv1;   // per-batch reuse
        u16* cat = qkv2;
        conv1x1_kernel<u16, false, 8><<<dim3(64, 64), blk, 0, stream>>>(
            xnb + (size_t)b * NC * NPIX, in_w, nullptr, yi, 96, 510);
        dwconv3x3_kernel<true><<<dim3(4, H4C), blk, 0, stream>>>(
            yi, main_w, fA, H4C, H2C, 2);
        boxlh_kernel<<<dim3(8, H4C), blk, 0, stream>>>(fA, lp_w, hp_w, fB, fC);
        ldhd_kernel<<<dim3(8, H2C), blk, 0, stream>>>(fB, fC, ld_w, hd_w, cat);
        conv1x1_kernel<float, true, 8><<<dim3(64, 12), blk, 0, stream>>>(
            cat, out_w, x1 + (size_t)b * NC * NPIX, out + (size_t)b * NC * NPIX, 510, 96);
    }
}

// Round 5
// 507.675 us; speedup vs baseline: 3.9560x; 1.3791x over previous
//
#include <hip/hip_runtime.h>
#include <hip/hip_bf16.h>

// Problem constants
#define NB   2
#define NC   96
#define NW   128
#define NPIX 16384   // 128*128
#define NHD  8
#define CHD  12
#define HIDC 255
#define H2C  510
#define H4C  1020

typedef __hip_bfloat16 bf16;
typedef unsigned short u16;
typedef unsigned int   u32;

typedef __attribute__((ext_vector_type(8))) __bf16 bfrag;
typedef __attribute__((ext_vector_type(4))) float  ffrag;

__device__ __forceinline__ float bfu(u16 u)  { return __uint_as_float(((u32)u) << 16); }
__device__ __forceinline__ float bflo(u32 u) { return __uint_as_float(u << 16); }
__device__ __forceinline__ float bfhi(u32 u) { return __uint_as_float(u & 0xffff0000u); }
__device__ __forceinline__ u16 f2u16(float a) {
    bf16 x = __float2bfloat16(a); return *(u16*)&x;
}
__device__ __forceinline__ u32 packbf(float a, float b) {
    return (u32)f2u16(a) | ((u32)f2u16(b) << 16);
}

// ================= MFMA GEMM for 1x1 convs =================
// C[M][NPIX] (+res) = A[M][K] (fp32 weights) x B[K][NPIX] (bf16 planes)
// Tiles: BM=64, BN=128, BK=32. Block 256 thr = 4 waves, wave w owns rows
// [w*16, w*16+16) of the tile, 8 n-tiles of 16.
// grid = (NPIX/128, ceil(M/64), nz); batch z offsets B/C/res by strides.
template <typename TOut, bool RES>
__global__ __launch_bounds__(256) void gemm1x1_kernel(
    const u16* __restrict__ Bm, const float* __restrict__ Am,
    const float* __restrict__ res, TOut* __restrict__ Cm,
    int M, int K, size_t strideB, size_t strideC) {
    __shared__ u16 Ash[64 * 40];    // [m][k] k-contig, row pad 40
    __shared__ u16 Bsh[128 * 40];   // [n][k] k-contig (transposed), row pad 40
    const u16* Bz = Bm + (size_t)blockIdx.z * strideB;
    int n0 = blockIdx.x * 128;
    int m0 = blockIdx.y * 64;
    int tid = threadIdx.x;
    int w = tid >> 6, l15 = tid & 15, q = (tid & 63) >> 4;
    // staging maps
    int amm = tid >> 2, akc = (tid & 3) * 8;       // A: row 0..63, k-chunk of 8
    int bkk = tid >> 3, bs0 = tid & 7;             // B: k-row 0..31, seg 0..7 (+8)

    ffrag acc[8];
    #pragma unroll
    for (int nt = 0; nt < 8; ++nt)
        #pragma unroll
        for (int e = 0; e < 4; ++e) acc[nt][e] = 0.f;

    for (int k0 = 0; k0 < K; k0 += 32) {
        // ---- stage A tile (64 x 32) fp32 -> bf16, guarded ----
        {
            int gm = m0 + amm;
            float f[8];
            #pragma unroll
            for (int e = 0; e < 8; ++e) {
                int gk = k0 + akc + e;
                f[e] = (gm < M && gk < K) ? Am[(size_t)gm * K + gk] : 0.f;
            }
            u32* dst = (u32*)&Ash[amm * 40 + akc];
            #pragma unroll
            for (int e = 0; e < 4; ++e) dst[e] = packbf(f[2 * e], f[2 * e + 1]);
        }
        // ---- stage B tile (32 x 128) -> transposed LDS [n][k], guarded ----
        {
            int gk = k0 + bkk;
            bool ok = gk < K;
            const u16* src = Bz + (size_t)gk * NPIX + n0;
            #pragma unroll
            for (int pass = 0; pass < 2; ++pass) {
                int nn = (bs0 + pass * 8) * 8;
                if (ok) {
                    uint4 v = *(const uint4*)(src + nn);
                    Bsh[(nn + 0) * 40 + bkk] = (u16)(v.x & 0xffff);
                    Bsh[(nn + 1) * 40 + bkk] = (u16)(v.x >> 16);
                    Bsh[(nn + 2) * 40 + bkk] = (u16)(v.y & 0xffff);
                    Bsh[(nn + 3) * 40 + bkk] = (u16)(v.y >> 16);
                    Bsh[(nn + 4) * 40 + bkk] = (u16)(v.z & 0xffff);
                    Bsh[(nn + 5) * 40 + bkk] = (u16)(v.z >> 16);
                    Bsh[(nn + 6) * 40 + bkk] = (u16)(v.w & 0xffff);
                    Bsh[(nn + 7) * 40 + bkk] = (u16)(v.w >> 16);
                } else {
                    #pragma unroll
                    for (int e = 0; e < 8; ++e) Bsh[(nn + e) * 40 + bkk] = 0;
                }
            }
        }
        __syncthreads();
        bfrag af = *(const bfrag*)&Ash[(w * 16 + l15) * 40 + q * 8];
        #pragma unroll
        for (int nt = 0; nt < 8; ++nt) {
            bfrag bf = *(const bfrag*)&Bsh[(nt * 16 + l15) * 40 + q * 8];
            acc[nt] = __builtin_amdgcn_mfma_f32_16x16x32_bf16(af, bf, acc[nt], 0, 0, 0);
        }
        __syncthreads();
    }
    // ---- epilogue ----
    TOut* Cz = Cm + (size_t)blockIdx.z * strideC;
    const float* rz = res + (RES ? (size_t)blockIdx.z * strideC : 0);
    int mrow = m0 + w * 16 + q * 4;
    #pragma unroll
    for (int nt = 0; nt < 8; ++nt) {
        int col = n0 + nt * 16 + l15;
        #pragma unroll
        for (int r = 0; r < 4; ++r) {
            int row = mrow + r;
            if (row < M) {
                float v = acc[nt][r];
                if (RES) v += rz[(size_t)row * NPIX + col];
                if constexpr (sizeof(TOut) == 2) {
                    u16 h = f2u16(v);
                    ((u16*)Cz)[(size_t)row * NPIX + col] = h;
                } else {
                    ((float*)Cz)[(size_t)row * NPIX + col] = v;
                }
            }
        }
    }
}

// ---------------- LayerNorm (fp32 in, bf16 out), channel-split blocks ----------------
__global__ __launch_bounds__(256) void ln_kernel(
    const float* __restrict__ x, const float* __restrict__ g,
    const float* __restrict__ bta, u16* __restrict__ out) {
    int blk = blockIdx.x;
    int b = blk >> 9;
    int p = ((blk & 511) << 5) + (threadIdx.x & 31);
    int cg = threadIdx.x >> 5;
    const float* xb = x + (size_t)b * NC * NPIX + p;
    float v[12]; float s = 0.f, s2 = 0.f;
    #pragma unroll
    for (int j = 0; j < 12; ++j) {
        float t = xb[(size_t)(cg * 12 + j) * NPIX];
        v[j] = t; s += t; s2 += t * t;
    }
    __shared__ float ss[8][32], qq[8][32], smu[32], sinv[32];
    ss[cg][threadIdx.x & 31] = s; qq[cg][threadIdx.x & 31] = s2;
    __syncthreads();
    if (threadIdx.x < 32) {
        float S = 0.f, Q = 0.f;
        #pragma unroll
        for (int k = 0; k < 8; ++k) { S += ss[k][threadIdx.x]; Q += qq[k][threadIdx.x]; }
        float mu = S * (1.f / NC);
        float var = Q * (1.f / NC) - mu * mu;
        smu[threadIdx.x] = mu; sinv[threadIdx.x] = rsqrtf(var + 1e-5f);
    }
    __syncthreads();
    float mu = smu[threadIdx.x & 31], inv = sinv[threadIdx.x & 31];
    u16* ob = out + (size_t)b * NC * NPIX + p;
    #pragma unroll
    for (int j = 0; j < 12; ++j) {
        int c = cg * 12 + j;
        ob[(size_t)c * NPIX] = f2u16((v[j] - mu) * inv * g[c] + bta[c]);
    }
}

// load a 1x10 window row (8 aligned + 2 halo) with zero padding outside
__device__ __forceinline__ void load_row_zpad(const u16* ib, int iy, int x0, float a[10]) {
    if (iy < 0 || iy >= NW) {
        #pragma unroll
        for (int k = 0; k < 10; ++k) a[k] = 0.f;
        return;
    }
    const u16* rp = ib + iy * NW;
    uint4 v = *(const uint4*)(rp + x0);
    a[1]=bflo(v.x); a[2]=bfhi(v.x); a[3]=bflo(v.y); a[4]=bfhi(v.y);
    a[5]=bflo(v.z); a[6]=bfhi(v.z); a[7]=bflo(v.w); a[8]=bfhi(v.w);
    a[0] = (x0 > 0)   ? bfu(rp[x0 - 1]) : 0.f;
    a[9] = (x0 < 120) ? bfu(rp[x0 + 8]) : 0.f;
}

// ---------------- depthwise / grouped-1-in 3x3, zero pad, 2 rows x 8 px/thread ----------------
template <bool RELU>
__global__ __launch_bounds__(256) void dwconv3x3_kernel(
    const u16* __restrict__ in, const float* __restrict__ w,
    u16* __restrict__ out, int CHN, int ICN, int idiv) {
    int id = blockIdx.x * 256 + threadIdx.x;
    int ty = id >> 4, tx = id & 15;
    int y0 = ty * 2, x0 = tx * 8;
    int b = blockIdx.y / CHN, oc = blockIdx.y % CHN;
    int ic = oc / idiv;
    const u16* ib = in + ((size_t)b * ICN + ic) * NPIX;
    float a[4][10];
    #pragma unroll
    for (int k = 0; k < 4; ++k) load_row_zpad(ib, y0 - 1 + k, x0, a[k]);
    const float* wr = w + (size_t)oc * 9;
    float w9[9];
    #pragma unroll
    for (int k = 0; k < 9; ++k) w9[k] = wr[k];
    float o0[8], o1[8];
    #pragma unroll
    for (int j = 0; j < 8; ++j) {
        float s0 = 0.f, s1 = 0.f;
        #pragma unroll
        for (int r = 0; r < 3; ++r)
            #pragma unroll
            for (int kx = 0; kx < 3; ++kx) {
                s0 += w9[r * 3 + kx] * a[r][j + kx];
                s1 += w9[r * 3 + kx] * a[r + 1][j + kx];
            }
        o0[j] = RELU ? fmaxf(s0, 0.f) : s0;
        o1[j] = RELU ? fmaxf(s1, 0.f) : s1;
    }
    u16* ob = out + ((size_t)b * CHN + oc) * NPIX + y0 * NW + x0;
    uint4 v0, v1;
    v0.x = packbf(o0[0], o0[1]); v0.y = packbf(o0[2], o0[3]);
    v0.z = packbf(o0[4], o0[5]); v0.w = packbf(o0[6], o0[7]);
    v1.x = packbf(o1[0], o1[1]); v1.y = packbf(o1[2], o1[3]);
    v1.z = packbf(o1[4], o1[5]); v1.w = packbf(o1[6], o1[7]);
    *(uint4*)ob = v0;
    *(uint4*)(ob + NW) = v1;
}

// ---------------- fused: box(replicate)->l,hb; lp/hp 3x3 (zero pad) + relu ----------------
// grid (8, nb*H4C); data contiguous [b][ch][px]; weight idx = blockIdx.y % H4C
__global__ __launch_bounds__(256) void boxlh_kernel(
    const u16* __restrict__ ym, const float* __restrict__ lpw_all,
    const float* __restrict__ hpw_all, u16* __restrict__ lpo, u16* __restrict__ hpo) {
    int p0 = (blockIdx.x * 256 + threadIdx.x) * 8;
    int y = p0 >> 7, x0 = p0 & (NW - 1);
    int ch = blockIdx.y % H4C;
    const u16* ib = ym + (size_t)blockIdx.y * NPIX;
    float rs[5][10];
    float c3[3][10];
    #pragma unroll
    for (int k = 0; k < 5; ++k) {
        int ry = min(max(y - 2 + k, 0), NW - 1);
        const u16* rp = ib + ry * NW;
        float ar[12];
        uint4 v = *(const uint4*)(rp + x0);
        ar[2]=bflo(v.x); ar[3]=bfhi(v.x); ar[4]=bflo(v.y); ar[5]=bfhi(v.y);
        ar[6]=bflo(v.z); ar[7]=bfhi(v.z); ar[8]=bflo(v.w); ar[9]=bfhi(v.w);
        if (x0 >= 2) { ar[0] = bfu(rp[x0 - 2]); ar[1] = bfu(rp[x0 - 1]); }
        else         { ar[0] = ar[2];           ar[1] = ar[2]; }
        if (x0 <= 118) { ar[10] = bfu(rp[x0 + 8]); ar[11] = bfu(rp[x0 + 9]); }
        else           { ar[10] = ar[9];           ar[11] = ar[9]; }
        #pragma unroll
        for (int n = 0; n < 10; ++n) rs[k][n] = ar[n] + ar[n + 1] + ar[n + 2];
        if (k >= 1 && k <= 3) {
            #pragma unroll
            for (int n = 0; n < 10; ++n) c3[k - 1][n] = ar[n + 1];
        }
    }
    const float* lw = lpw_all + (size_t)ch * 9;
    const float* hw = hpw_all + (size_t)ch * 9;
    float wl[9], wh[9];
    #pragma unroll
    for (int k = 0; k < 9; ++k) { wl[k] = lw[k]; wh[k] = hw[k]; }
    float lo[8], ho[8];
    #pragma unroll
    for (int j2 = 0; j2 < 8; ++j2) { lo[j2] = 0.f; ho[j2] = 0.f; }
    #pragma unroll
    for (int j = 0; j < 3; ++j) {
        int r = y - 1 + j;
        bool rowok = (r >= 0) && (r < NW);
        float lrow[10], hrow[10];
        #pragma unroll
        for (int n = 0; n < 10; ++n) {
            int c = x0 - 1 + n;
            bool ok = rowok && (c >= 0) && (c < NW);
            float lv = (rs[j][n] + rs[j + 1][n] + rs[j + 2][n]) * (1.f / 9.f);
            lrow[n] = ok ? lv : 0.f;
            hrow[n] = ok ? (c3[j][n] - lv) : 0.f;
        }
        #pragma unroll
        for (int p = 0; p < 8; ++p)
            #pragma unroll
            for (int d = 0; d < 3; ++d) {
                lo[p] += wl[j * 3 + d] * lrow[p + d];
                ho[p] += wh[j * 3 + d] * hrow[p + d];
            }
    }
    uint4 lv4, hv4;
    lv4.x = packbf(fmaxf(lo[0],0.f), fmaxf(lo[1],0.f));
    lv4.y = packbf(fmaxf(lo[2],0.f), fmaxf(lo[3],0.f));
    lv4.z = packbf(fmaxf(lo[4],0.f), fmaxf(lo[5],0.f));
    lv4.w = packbf(fmaxf(lo[6],0.f), fmaxf(lo[7],0.f));
    hv4.x = packbf(fmaxf(ho[0],0.f), fmaxf(ho[1],0.f));
    hv4.y = packbf(fmaxf(ho[2],0.f), fmaxf(ho[3],0.f));
    hv4.z = packbf(fmaxf(ho[4],0.f), fmaxf(ho[5],0.f));
    hv4.w = packbf(fmaxf(ho[6],0.f), fmaxf(ho[7],0.f));
    *(uint4*)(lpo + (size_t)blockIdx.y * NPIX + p0) = lv4;
    *(uint4*)(hpo + (size_t)blockIdx.y * NPIX + p0) = hv4;
}

// ---------------- ld/hd grouped 4->1 conv -> concat, 8 px/thread ----------------
// grid (8, nb*H2C); lp/hp are full [b][1020][px]; cat [b][510][px]
__global__ __launch_bounds__(256) void ldhd_kernel(
    const u16* __restrict__ lp, const u16* __restrict__ hp,
    const float* __restrict__ ldw, const float* __restrict__ hdw,
    u16* __restrict__ cat) {
    int p0 = (blockIdx.x * 256 + threadIdx.x) * 8;
    int y = p0 >> 7, x0 = p0 & (NW - 1);
    int b = blockIdx.y / H2C, cc = blockIdx.y % H2C;
    bool isl = cc < HIDC; int g = isl ? cc : cc - HIDC;
    const float* wr = (isl ? ldw : hdw) + (size_t)g * 36;
    float o[8];
    #pragma unroll
    for (int j = 0; j < 8; ++j) o[j] = 0.f;
    #pragma unroll
    for (int ii = 0; ii < 4; ++ii) {
        int ch = 4 * g + ii;
        const u16* src = ((ch < H2C) == isl) ? lp : hp;
        const u16* ib = src + ((size_t)b * H4C + ch) * NPIX;
        float a[3][10];
        #pragma unroll
        for (int r = 0; r < 3; ++r) load_row_zpad(ib, y + r - 1, x0, a[r]);
        #pragma unroll
        for (int j = 0; j < 8; ++j) {
            float s = 0.f;
            #pragma unroll
            for (int r = 0; r < 3; ++r)
                #pragma unroll
                for (int kx = 0; kx < 3; ++kx) s += wr[ii * 9 + r * 3 + kx] * a[r][j + kx];
            o[j] += s;
        }
    }
    uint4 ov;
    ov.x = packbf(fmaxf(o[0],0.f), fmaxf(o[1],0.f));
    ov.y = packbf(fmaxf(o[2],0.f), fmaxf(o[3],0.f));
    ov.z = packbf(fmaxf(o[4],0.f), fmaxf(o[5],0.f));
    ov.w = packbf(fmaxf(o[6],0.f), fmaxf(o[7],0.f));
    *(uint4*)(cat + ((size_t)b * H2C + cc) * NPIX + p0) = ov;
}

// ---------------- q/k row L2 norms -> reciprocal scales ----------------
__global__ __launch_bounds__(256) void qknorm_kernel(
    const u16* __restrict__ qkv2, float* __restrict__ scales) {
    int r = blockIdx.x;
    int b = r / 192, ch = r % 192;
    const u16* src = qkv2 + ((size_t)b * 288 + ch) * NPIX;
    float s = 0.f;
    for (int p = threadIdx.x * 8; p < NPIX; p += 2048) {
        uint4 v = *(const uint4*)(src + p);
        float f[8];
        f[0]=bflo(v.x); f[1]=bfhi(v.x); f[2]=bflo(v.y); f[3]=bfhi(v.y);
        f[4]=bflo(v.z); f[5]=bfhi(v.z); f[6]=bflo(v.w); f[7]=bfhi(v.w);
        #pragma unroll
        for (int k = 0; k < 8; ++k) s += f[k] * f[k];
    }
    #pragma unroll
    for (int off = 32; off > 0; off >>= 1) s += __shfl_down(s, off, 64);
    __shared__ float part[4];
    int wid = threadIdx.x >> 6;
    if ((threadIdx.x & 63) == 0) part[wid] = s;
    __syncthreads();
    if (threadIdx.x == 0) {
        float tot = part[0] + part[1] + part[2] + part[3];
        scales[r] = 1.f / fmaxf(sqrtf(tot), 1e-12f);
    }
}

// ---------------- attn[b,h,i,:] = scaled q_i . k_j * temperature ----------------
__global__ __launch_bounds__(256) void attn_kernel(
    const u16* __restrict__ qkv2, const float* __restrict__ scales,
    const float* __restrict__ temp, float* __restrict__ attn) {
    int blk = blockIdx.x;
    int i = blk % CHD; int h = (blk / CHD) % NHD; int b = blk / (CHD * NHD);
    const u16* q = qkv2 + ((size_t)b * 288 + h * CHD + i) * NPIX;
    const u16* k = qkv2 + ((size_t)b * 288 + 96 + h * CHD) * NPIX;
    float acc[CHD];
    #pragma unroll
    for (int j = 0; j < CHD; ++j) acc[j] = 0.f;
    for (int p = threadIdx.x * 8; p < NPIX; p += 2048) {
        uint4 qv = *(const uint4*)(q + p);
        float qf[8];
        qf[0]=bflo(qv.x); qf[1]=bfhi(qv.x); qf[2]=bflo(qv.y); qf[3]=bfhi(qv.y);
        qf[4]=bflo(qv.z); qf[5]=bfhi(qv.z); qf[6]=bflo(qv.w); qf[7]=bfhi(qv.w);
        #pragma unroll
        for (int j = 0; j < CHD; ++j) {
            uint4 kv = *(const uint4*)(k + (size_t)j * NPIX + p);
            float s = qf[0]*bflo(kv.x) + qf[1]*bfhi(kv.x) + qf[2]*bflo(kv.y) + qf[3]*bfhi(kv.y)
                    + qf[4]*bflo(kv.z) + qf[5]*bfhi(kv.z) + qf[6]*bflo(kv.w) + qf[7]*bfhi(kv.w);
            acc[j] += s;
        }
    }
    __shared__ float part[4][CHD];
    int wid = threadIdx.x >> 6, lane = threadIdx.x & 63;
    #pragma unroll
    for (int j = 0; j < CHD; ++j) {
        float v = acc[j];
        #pragma unroll
        for (int off = 32; off > 0; off >>= 1) v += __shfl_down(v, off, 64);
        if (lane == 0) part[wid][j] = v;
    }
    __syncthreads();
    if (threadIdx.x < CHD) {
        int j = threadIdx.x;
        float d = part[0][j] + part[1][j] + part[2][j] + part[3][j];
        float val = d * scales[b * 192 + h * CHD + i]
                      * scales[b * 192 + 96 + h * CHD + j] * temp[h];
        attn[(size_t)blk * CHD + j] = val;
    }
}

// ---------------- STS threshold generation + softmax mix ----------------
__global__ __launch_bounds__(256) void sts_kernel(
    const float* __restrict__ attn, const float* __restrict__ tw,
    const float* __restrict__ w1, const float* __restrict__ b1,
    const float* __restrict__ w2, const float* __restrict__ b2,
    float* __restrict__ attn_c) {
    int b = blockIdx.x;
    __shared__ float sat[NHD * CHD * CHD];
    __shared__ float avg[NHD];
    __shared__ float thr[4][NHD];
    for (int idx = threadIdx.x; idx < NHD * CHD * CHD; idx += 256)
        sat[idx] = attn[(size_t)b * NHD * CHD * CHD + idx];
    __syncthreads();
    if (threadIdx.x < NHD) {
        float s = 0.f;
        for (int t = 0; t < CHD * CHD; ++t) s += fabsf(sat[threadIdx.x * CHD * CHD + t]);
        avg[threadIdx.x] = s * (1.f / (CHD * CHD));
    }
    __syncthreads();
    if (threadIdx.x < 4) {
        int s = threadIdx.x;
        float t1[NHD];
        for (int hp = 0; hp < NHD; ++hp) {
            float u = b1[s * NHD + hp];
            for (int h = 0; h < NHD; ++h) u += avg[h] * w1[s * 64 + hp * NHD + h];
            t1[hp] = fmaxf(u, 0.f);
        }
        for (int hp = 0; hp < NHD; ++hp) {
            float u = b2[s * NHD + hp];
            for (int h = 0; h < NHD; ++h) u += t1[h] * w2[s * 64 + hp * NHD + h];
            float gg = 1.f / (1.f + expf(-u));
            thr[s][hp] = avg[hp] * gg;
        }
    }
    __syncthreads();
    if (threadIdx.x < NHD * CHD) {
        int h = threadIdx.x / CHD, i = threadIdx.x % CHD;
        const float* arow = sat + (h * CHD + i) * CHD;
        float acc[CHD];
        #pragma unroll
        for (int j = 0; j < CHD; ++j) acc[j] = 0.f;
        for (int s = 0; s < 4; ++s) {
            float comp[CHD]; float m = -1e30f;
            #pragma unroll
            for (int j = 0; j < CHD; ++j) {
                float a = arow[j];
                float sg = (a > 0.f) ? 1.f : ((a < 0.f) ? -1.f : 0.f);
                float c = sg * fmaxf(fabsf(a) - thr[s][h], 0.f);
                comp[j] = c; m = fmaxf(m, c);
            }
            float sum = 0.f;
            #pragma unroll
            for (int j = 0; j < CHD; ++j) { comp[j] = expf(comp[j] - m); sum += comp[j]; }
            float wts = tw[s] / sum;
            #pragma unroll
            for (int j = 0; j < CHD; ++j) acc[j] += wts * comp[j];
        }
        for (int j = 0; j < CHD; ++j)
            attn_c[(size_t)b * NHD * CHD * CHD + (h * CHD + i) * CHD + j] = acc[j];
    }
}

// ---------------- out = attn_c @ v, 4 px/thread, bf16 out ----------------
__global__ __launch_bounds__(256) void av_kernel(
    const float* __restrict__ attn_c, const u16* __restrict__ qkv2,
    u16* __restrict__ outv) {
    int p0 = (blockIdx.x * 256 + threadIdx.x) * 4;
    int bc = blockIdx.y;
    int b = bc / NC, hc = bc % NC; int h = hc / CHD, i = hc % CHD;
    const float* a = attn_c + ((size_t)(b * NHD + h) * CHD + i) * CHD;
    const u16* v = qkv2 + ((size_t)b * 288 + 192 + h * CHD) * NPIX;
    float av[CHD];
    #pragma unroll
    for (int j = 0; j < CHD; ++j) av[j] = a[j];
    float o[4] = {0.f, 0.f, 0.f, 0.f};
    #pragma unroll
    for (int j = 0; j < CHD; ++j) {
        uint2 t = *(const uint2*)(v + (size_t)j * NPIX + p0);
        o[0] += av[j] * bflo(t.x); o[1] += av[j] * bfhi(t.x);
        o[2] += av[j] * bflo(t.y); o[3] += av[j] * bfhi(t.y);
    }
    uint2 t; t.x = packbf(o[0], o[1]); t.y = packbf(o[2], o[3]);
    *(uint2*)(outv + ((size_t)b * NC + hc) * NPIX + p0) = t;
}

// ---------------- launch ----------------
extern "C" void kernel_launch(void* const* d_in, const int* in_sizes, int n_in,
                              void* d_out, int out_size, void* d_ws, size_t ws_size,
                              hipStream_t stream) {
    const float* x       = (const float*)d_in[0];
    const float* norm1_w = (const float*)d_in[1];
    const float* norm1_b = (const float*)d_in[2];
    const float* qkv_w   = (const float*)d_in[3];
    const float* qkv_dw  = (const float*)d_in[4];
    const float* proj_w  = (const float*)d_in[5];
    const float* temp    = (const float*)d_in[6];
    const float* thw     = (const float*)d_in[7];
    const float* aw1     = (const float*)d_in[8];
    const float* ab1     = (const float*)d_in[9];
    const float* aw2     = (const float*)d_in[10];
    const float* ab2     = (const float*)d_in[11];
    const float* norm2_w = (const float*)d_in[12];
    const float* norm2_b = (const float*)d_in[13];
    const float* in_w    = (const float*)d_in[14];
    const float* main_w  = (const float*)d_in[15];
    const float* lp_w    = (const float*)d_in[16];
    const float* hp_w    = (const float*)d_in[17];
    const float* ld_w    = (const float*)d_in[18];
    const float* hd_w    = (const float*)d_in[19];
    const float* out_w   = (const float*)d_in[20];
    float* out = (float*)d_out;

    // ---- workspace layout ----
    char* ws = (char*)d_ws;
    float* x1    = (float*)(ws + 0);            // 12,582,912 fp32 residual stream
    u16*   xnb   = (u16*)(ws + 12582912);       // 6,291,456  bf16 LN/attn-out
    u16*   qkv1  = (u16*)(ws + 18874368);       // 18,874,368 bf16 [2][288][NPIX]
    u16*   qkv2  = (u16*)(ws + 37748736);       // 18,874,368 bf16 [2][288][NPIX]
    float* scl   = (float*)(ws + 56623104);     // 16 KB
    float* attn  = (float*)(ws + 56639488);     // 16 KB
    float* attnc = (float*)(ws + 56655872);     // 16 KB
    char*  F0    = ws + 56672256;               // FFN big buffers
    const size_t S_full = 33423360, S_pb = 16711680;
    bool full = ws_size >= (size_t)56672256 + 3 * S_full;   // 156,942,336

    dim3 blk(256);
    // ---- attention half ----
    ln_kernel<<<dim3(NB * NPIX / 32), blk, 0, stream>>>(x, norm1_w, norm1_b, xnb);
    gemm1x1_kernel<u16, false><<<dim3(128, 5, NB), blk, 0, stream>>>(
        xnb, qkv_w, nullptr, qkv1, 288, 96, (size_t)NC * NPIX, (size_t)288 * NPIX);
    dwconv3x3_kernel<false><<<dim3(4, NB * 288), blk, 0, stream>>>(
        qkv1, qkv_dw, qkv2, 288, 288, 1);
    qknorm_kernel<<<dim3(NB * 192), blk, 0, stream>>>(qkv2, scl);
    attn_kernel<<<dim3(NB * NHD * CHD), blk, 0, stream>>>(qkv2, scl, temp, attn);
    sts_kernel<<<dim3(NB), blk, 0, stream>>>(attn, thw, aw1, ab1, aw2, ab2, attnc);
    av_kernel<<<dim3(16, NB * NC), blk, 0, stream>>>(attnc, qkv2, xnb);
    gemm1x1_kernel<float, true><<<dim3(128, 2, NB), blk, 0, stream>>>(
        xnb, proj_w, x, x1, 96, 96, (size_t)NC * NPIX, (size_t)NC * NPIX);
    // ---- FFN half ----
    ln_kernel<<<dim3(NB * NPIX / 32), blk, 0, stream>>>(x1, norm2_w, norm2_b, xnb);
    if (full) {
        u16* yi  = qkv1;                 // 33.4 MB spanning qkv1+qkv2 (dead now)
        u16* cat = qkv1;                 // reused after yi dead
        u16* fA = (u16*)F0;
        u16* fB = (u16*)(F0 + S_full);
        u16* fC = (u16*)(F0 + 2 * S_full);
        gemm1x1_kernel<u16, false><<<dim3(128, 8, NB), blk, 0, stream>>>(
            xnb, in_w, nullptr, yi, H2C, 96, (size_t)NC * NPIX, (size_t)H2C * NPIX);
        dwconv3x3_kernel<true><<<dim3(4, NB * H4C), blk, 0, stream>>>(
            yi, main_w, fA, H4C, H2C, 2);
        boxlh_kernel<<<dim3(8, NB * H4C), blk, 0, stream>>>(fA, lp_w, hp_w, fB, fC);
        ldhd_kernel<<<dim3(8, NB * H2C), blk, 0, stream>>>(fB, fC, ld_w, hd_w, cat);
        gemm1x1_kernel<float, true><<<dim3(128, 2, NB), blk, 0, stream>>>(
            cat, out_w, x1, out, 96, H2C, (size_t)H2C * NPIX, (size_t)NC * NPIX);
    } else {
        for (int b = 0; b < NB; ++b) {
            u16* yi  = qkv1;
            u16* cat = qkv2;
            u16* fA = (u16*)F0;
            u16* fB = (u16*)(F0 + S_pb);
            u16* fC = (u16*)(F0 + 2 * S_pb);
            gemm1x1_kernel<u16, false><<<dim3(128, 8, 1), blk, 0, stream>>>(
                xnb + (size_t)b * NC * NPIX, in_w, nullptr, yi, H2C, 96, 0, 0);
            dwconv3x3_kernel<true><<<dim3(4, H4C), blk, 0, stream>>>(
                yi, main_w, fA, H4C, H2C, 2);
            boxlh_kernel<<<dim3(8, H4C), blk, 0, stream>>>(fA, lp_w, hp_w, fB, fC);
            ldhd_kernel<<<dim3(8, H2C), blk, 0, stream>>>(fB, fC, ld_w, hd_w, cat);
            gemm1x1_kernel<float, true><<<dim3(128, 2, 1), blk, 0, stream>>>(
                cat, out_w, x1 + (size_t)b * NC * NPIX, out + (size_t)b * NC * NPIX,
                96, H2C, 0, 0);
        }
    }
}

// Round 6
// 506.185 us; speedup vs baseline: 3.9676x; 1.0029x over previous
//
#include <hip/hip_runtime.h>
#include <hip/hip_bf16.h>

// Problem constants
#define NB   2
#define NC   96
#define NW   128
#define NPIX 16384   // 128*128
#define NHD  8
#define CHD  12
#define HIDC 255
#define H2C  510
#define H4C  1020

typedef __hip_bfloat16 bf16;
typedef unsigned short u16;
typedef unsigned int   u32;

typedef __attribute__((ext_vector_type(8))) __bf16 bfrag;
typedef __attribute__((ext_vector_type(4))) float  ffrag;

__device__ __forceinline__ float bfu(u16 u)  { return __uint_as_float(((u32)u) << 16); }
__device__ __forceinline__ float bflo(u32 u) { return __uint_as_float(u << 16); }
__device__ __forceinline__ float bfhi(u32 u) { return __uint_as_float(u & 0xffff0000u); }
__device__ __forceinline__ u16 f2u16(float a) {
    bf16 x = __float2bfloat16(a); return *(u16*)&x;
}
__device__ __forceinline__ u32 packbf(float a, float b) {
    return (u32)f2u16(a) | ((u32)f2u16(b) << 16);
}
__device__ __forceinline__ uint4 pack8(const float o[8]) {
    uint4 r; r.x = packbf(o[0], o[1]); r.y = packbf(o[2], o[3]);
    r.z = packbf(o[4], o[5]); r.w = packbf(o[6], o[7]); return r;
}

// read 10 floats (image cols c0-1 .. c0+8) from an LDS row (halo layout: idx = 8 + col)
#define LSTR 144
__device__ __forceinline__ void lrow10(const u16* rowbase, int c0, float a[10]) {
    const u16* p = rowbase + 8 + c0;           // 16B-aligned for c0 % 8 == 0
    u32 lo = *(const u32*)(p - 2);             // cols c0-2, c0-1
    uint4 v = *(const uint4*)p;                // cols c0 .. c0+7
    u32 hi = *(const u32*)(p + 8);             // cols c0+8, c0+9
    a[0] = bfhi(lo);
    a[1] = bflo(v.x); a[2] = bfhi(v.x); a[3] = bflo(v.y); a[4] = bfhi(v.y);
    a[5] = bflo(v.z); a[6] = bfhi(v.z); a[7] = bflo(v.w); a[8] = bfhi(v.w);
    a[9] = bflo(hi);
}

// ================= fused FFN midsection =================
// yi[b][510][npix] --main dw(2 out/grp)+relu--> ym --box(replicate)--> l, hb=ym-l
//  --lp/hp dw+relu--> lp,hp --ld/hd (4->1 grouped)+relu--> cat[b][510][npix]
// Block = (8-row tile, group g of 4 channels, batch). All intermediates in LDS.
__global__ __launch_bounds__(256) void ffnmid_kernel(
    const u16* __restrict__ yi, const float* __restrict__ main_w,
    const float* __restrict__ lp_w, const float* __restrict__ hp_w,
    const float* __restrict__ ld_w, const float* __restrict__ hd_w,
    u16* __restrict__ cat) {
    __shared__ __align__(16) u16 yis[2][16][LSTR];  // yi rows y0-4 .. y0+11 (zero-pad)
    __shared__ __align__(16) u16 yms[4][14][LSTR];  // ym rows y0-3 .. y0+10 (replicate col halo)
    __shared__ __align__(16) u16 lls[4][12][LSTR];  // l  rows y0-2 .. y0+9  (zero halos)
    __shared__ __align__(16) u16 lps[4][10][LSTR];  // lp rows y0-1 .. y0+8  (zero halos)
    __shared__ __align__(16) u16 hps[4][10][LSTR];  // hp rows y0-1 .. y0+8  (zero halos)
    __shared__ float wts[180];  // [main 36][lp 36][hp 36][ld 36][hd 36]

    int g  = blockIdx.y;
    int y0 = blockIdx.x * 8;
    int tid = threadIdx.x;
    const u16* yib = yi + (size_t)blockIdx.z * H2C * NPIX;
    u16* catb = cat + (size_t)blockIdx.z * H2C * NPIX;

    // ---- weights -> LDS; zero yi buffer ----
    if (tid < 180) {
        int idx = tid; float v;
        if (idx < 36)       v = main_w[(4 * g) * 9 + idx];
        else if (idx < 72)  v = lp_w[(4 * g) * 9 + (idx - 36)];
        else if (idx < 108) v = hp_w[(4 * g) * 9 + (idx - 72)];
        else if (idx < 144) v = ld_w[g * 36 + (idx - 108)];
        else                v = hd_w[g * 36 + (idx - 144)];
        wts[idx] = v;
    }
    {
        u32* z = (u32*)&yis[0][0][0];
        #pragma unroll
        for (int k = 0; k < 9; ++k) {
            int i = tid + k * 256;
            if (i < 2304) z[i] = 0;
        }
    }
    __syncthreads();
    // ---- stage yi (2 ch x 16 rows x 128 cols) ----
    #pragma unroll
    for (int k = 0; k < 2; ++k) {
        int t = tid + k * 256;            // 0..511
        int seg = t & 15, s = (t >> 4) & 15, lc = t >> 8;
        int row = y0 - 4 + s;
        if ((unsigned)row < 128u) {
            uint4 v = *(const uint4*)(yib + (size_t)(2 * g + lc) * NPIX + row * NW + seg * 8);
            *(uint4*)&yis[lc][s][8 + seg * 8] = v;
        }
    }
    __syncthreads();
    // ---- S2: ym = relu(main conv, zero pad) ----
    for (int t = tid; t < 896; t += 256) {
        int seg = t & 15, s = (t >> 4) % 14, ii = t / 224;
        int row = y0 - 3 + s;
        if ((unsigned)row >= 128u) continue;  // never read (replicate clamp)
        int lc = ii >> 1;
        float a0[10], a1[10], a2[10];
        lrow10(&yis[lc][s][0],     seg * 8, a0);
        lrow10(&yis[lc][s + 1][0], seg * 8, a1);
        lrow10(&yis[lc][s + 2][0], seg * 8, a2);
        const float* w9 = &wts[ii * 9];
        float o[8];
        #pragma unroll
        for (int j = 0; j < 8; ++j) {
            float v = 0.f;
            #pragma unroll
            for (int d = 0; d < 3; ++d)
                v += w9[d] * a0[j + d] + w9[3 + d] * a1[j + d] + w9[6 + d] * a2[j + d];
            o[j] = fmaxf(v, 0.f);
        }
        *(uint4*)&yms[ii][s][8 + seg * 8] = pack8(o);
        if (seg == 0)  yms[ii][s][7]   = f2u16(o[0]);   // replicate col halo
        if (seg == 15) yms[ii][s][136] = f2u16(o[7]);
    }
    __syncthreads();
    // ---- S3: l = box3x3(ym) replicate pad; zero outside image ----
    for (int t = tid; t < 768; t += 256) {
        int seg = t & 15, s = (t >> 4) % 12, ii = t / 192;
        int row = y0 - 2 + s;
        uint4 out = make_uint4(0, 0, 0, 0);
        if ((unsigned)row < 128u) {
            int r0 = max(row - 1, 0) - (y0 - 3);
            int r1 = row - (y0 - 3);
            int r2 = min(row + 1, 127) - (y0 - 3);
            float a0[10], a1[10], a2[10];
            lrow10(&yms[ii][r0][0], seg * 8, a0);
            lrow10(&yms[ii][r1][0], seg * 8, a1);
            lrow10(&yms[ii][r2][0], seg * 8, a2);
            float cs[10];
            #pragma unroll
            for (int n = 0; n < 10; ++n) cs[n] = a0[n] + a1[n] + a2[n];
            float o[8];
            #pragma unroll
            for (int j = 0; j < 8; ++j) o[j] = (cs[j] + cs[j + 1] + cs[j + 2]) * (1.f / 9.f);
            out = pack8(o);
        }
        *(uint4*)&lls[ii][s][8 + seg * 8] = out;
        if (seg == 0)  lls[ii][s][7]   = 0;   // zero-pad halo
        if (seg == 15) lls[ii][s][136] = 0;
    }
    __syncthreads();
    // ---- S4: lp = relu(conv(l)), hp = relu(conv(hb)), hb = ym - l (zero pad) ----
    for (int t = tid; t < 1280; t += 256) {
        int kind = t / 640;            // 0 = lp, 1 = hp
        int r = t % 640;
        int ii = r / 160, s = (r >> 4) % 10, seg = r & 15;
        int row = y0 - 1 + s;
        u16* dst = kind ? &hps[ii][s][0] : &lps[ii][s][0];
        uint4 out = make_uint4(0, 0, 0, 0);
        if ((unsigned)row < 128u) {
            const float* w9 = &wts[(kind ? 72 : 36) + ii * 9];
            float o[8] = {0.f, 0.f, 0.f, 0.f, 0.f, 0.f, 0.f, 0.f};
            if (kind == 0) {
                #pragma unroll
                for (int r3 = 0; r3 < 3; ++r3) {
                    float a[10];
                    lrow10(&lls[ii][s + r3][0], seg * 8, a);
                    #pragma unroll
                    for (int j = 0; j < 8; ++j)
                        o[j] += w9[r3 * 3] * a[j] + w9[r3 * 3 + 1] * a[j + 1]
                              + w9[r3 * 3 + 2] * a[j + 2];
                }
            } else {
                #pragma unroll
                for (int r3 = 0; r3 < 3; ++r3) {
                    int rr = row - 1 + r3;
                    bool valid = (unsigned)rr < 128u;
                    float al[10], am[10], hb[10];
                    lrow10(&lls[ii][s + r3][0],     seg * 8, al);
                    lrow10(&yms[ii][s + 1 + r3][0], seg * 8, am);
                    #pragma unroll
                    for (int n = 0; n < 10; ++n) hb[n] = valid ? (am[n] - al[n]) : 0.f;
                    if (seg == 0)  hb[0] = 0.f;   // col -1 zero-pad
                    if (seg == 15) hb[9] = 0.f;   // col 128 zero-pad
                    #pragma unroll
                    for (int j = 0; j < 8; ++j)
                        o[j] += w9[r3 * 3] * hb[j] + w9[r3 * 3 + 1] * hb[j + 1]
                              + w9[r3 * 3 + 2] * hb[j + 2];
                }
            }
            float oo[8];
            #pragma unroll
            for (int j = 0; j < 8; ++j) oo[j] = fmaxf(o[j], 0.f);
            out = pack8(oo);
        }
        *(uint4*)&dst[8 + seg * 8] = out;
        if (seg == 0)  dst[7]   = 0;
        if (seg == 15) dst[136] = 0;
    }
    __syncthreads();
    // ---- S5: ld & hd (4->1 grouped conv, zero pad) -> cat ----
    {
        int kind = tid >> 7, s = (tid >> 4) & 7, seg = tid & 15;
        int row = y0 + s;
        const float* w36 = &wts[kind ? 144 : 108];
        float o[8] = {0.f, 0.f, 0.f, 0.f, 0.f, 0.f, 0.f, 0.f};
        #pragma unroll
        for (int ii = 0; ii < 4; ++ii) {
            int ch = 4 * g + ii;
            bool uselp = (ch < H2C) == (kind == 0);
            #pragma unroll
            for (int r3 = 0; r3 < 3; ++r3) {
                float a[10];
                const u16* rb = uselp ? &lps[ii][s + r3][0] : &hps[ii][s + r3][0];
                lrow10(rb, seg * 8, a);
                float wa = w36[ii * 9 + r3 * 3], wb = w36[ii * 9 + r3 * 3 + 1],
                      wc = w36[ii * 9 + r3 * 3 + 2];
                #pragma unroll
                for (int j = 0; j < 8; ++j)
                    o[j] += wa * a[j] + wb * a[j + 1] + wc * a[j + 2];
            }
        }
        float oo[8];
        #pragma unroll
        for (int j = 0; j < 8; ++j) oo[j] = fmaxf(o[j], 0.f);
        int cc = kind ? (HIDC + g) : g;
        *(uint4*)(catb + (size_t)cc * NPIX + row * NW + seg * 8) = pack8(oo);
    }
}

// ================= MFMA GEMM for 1x1 convs =================
template <typename TOut, bool RES>
__global__ __launch_bounds__(256) void gemm1x1_kernel(
    const u16* __restrict__ Bm, const float* __restrict__ Am,
    const float* __restrict__ res, TOut* __restrict__ Cm,
    int M, int K, size_t strideB, size_t strideC) {
    __shared__ u16 Ash[64 * 40];    // [m][k] k-contig, row pad 40
    __shared__ u16 Bsh[128 * 40];   // [n][k] k-contig (transposed), row pad 40
    const u16* Bz = Bm + (size_t)blockIdx.z * strideB;
    int n0 = blockIdx.x * 128;
    int m0 = blockIdx.y * 64;
    int tid = threadIdx.x;
    int w = tid >> 6, l15 = tid & 15, q = (tid & 63) >> 4;
    int amm = tid >> 2, akc = (tid & 3) * 8;
    int bkk = tid >> 3, bs0 = tid & 7;

    ffrag acc[8];
    #pragma unroll
    for (int nt = 0; nt < 8; ++nt)
        #pragma unroll
        for (int e = 0; e < 4; ++e) acc[nt][e] = 0.f;

    for (int k0 = 0; k0 < K; k0 += 32) {
        {
            int gm = m0 + amm;
            float f[8];
            #pragma unroll
            for (int e = 0; e < 8; ++e) {
                int gk = k0 + akc + e;
                f[e] = (gm < M && gk < K) ? Am[(size_t)gm * K + gk] : 0.f;
            }
            u32* dst = (u32*)&Ash[amm * 40 + akc];
            #pragma unroll
            for (int e = 0; e < 4; ++e) dst[e] = packbf(f[2 * e], f[2 * e + 1]);
        }
        {
            int gk = k0 + bkk;
            bool ok = gk < K;
            const u16* src = Bz + (size_t)gk * NPIX + n0;
            #pragma unroll
            for (int pass = 0; pass < 2; ++pass) {
                int nn = (bs0 + pass * 8) * 8;
                if (ok) {
                    uint4 v = *(const uint4*)(src + nn);
                    Bsh[(nn + 0) * 40 + bkk] = (u16)(v.x & 0xffff);
                    Bsh[(nn + 1) * 40 + bkk] = (u16)(v.x >> 16);
                    Bsh[(nn + 2) * 40 + bkk] = (u16)(v.y & 0xffff);
                    Bsh[(nn + 3) * 40 + bkk] = (u16)(v.y >> 16);
                    Bsh[(nn + 4) * 40 + bkk] = (u16)(v.z & 0xffff);
                    Bsh[(nn + 5) * 40 + bkk] = (u16)(v.z >> 16);
                    Bsh[(nn + 6) * 40 + bkk] = (u16)(v.w & 0xffff);
                    Bsh[(nn + 7) * 40 + bkk] = (u16)(v.w >> 16);
                } else {
                    #pragma unroll
                    for (int e = 0; e < 8; ++e) Bsh[(nn + e) * 40 + bkk] = 0;
                }
            }
        }
        __syncthreads();
        bfrag af = *(const bfrag*)&Ash[(w * 16 + l15) * 40 + q * 8];
        #pragma unroll
        for (int nt = 0; nt < 8; ++nt) {
            bfrag bf = *(const bfrag*)&Bsh[(nt * 16 + l15) * 40 + q * 8];
            acc[nt] = __builtin_amdgcn_mfma_f32_16x16x32_bf16(af, bf, acc[nt], 0, 0, 0);
        }
        __syncthreads();
    }
    TOut* Cz = Cm + (size_t)blockIdx.z * strideC;
    const float* rz = res + (RES ? (size_t)blockIdx.z * strideC : 0);
    int mrow = m0 + w * 16 + q * 4;
    #pragma unroll
    for (int nt = 0; nt < 8; ++nt) {
        int col = n0 + nt * 16 + l15;
        #pragma unroll
        for (int r = 0; r < 4; ++r) {
            int row = mrow + r;
            if (row < M) {
                float v = acc[nt][r];
                if (RES) v += rz[(size_t)row * NPIX + col];
                if constexpr (sizeof(TOut) == 2) {
                    ((u16*)Cz)[(size_t)row * NPIX + col] = f2u16(v);
                } else {
                    ((float*)Cz)[(size_t)row * NPIX + col] = v;
                }
            }
        }
    }
}

// ---------------- LayerNorm (fp32 in, bf16 out), channel-split blocks ----------------
__global__ __launch_bounds__(256) void ln_kernel(
    const float* __restrict__ x, const float* __restrict__ g,
    const float* __restrict__ bta, u16* __restrict__ out) {
    int blk = blockIdx.x;
    int b = blk >> 9;
    int p = ((blk & 511) << 5) + (threadIdx.x & 31);
    int cg = threadIdx.x >> 5;
    const float* xb = x + (size_t)b * NC * NPIX + p;
    float v[12]; float s = 0.f, s2 = 0.f;
    #pragma unroll
    for (int j = 0; j < 12; ++j) {
        float t = xb[(size_t)(cg * 12 + j) * NPIX];
        v[j] = t; s += t; s2 += t * t;
    }
    __shared__ float ss[8][32], qq[8][32], smu[32], sinv[32];
    ss[cg][threadIdx.x & 31] = s; qq[cg][threadIdx.x & 31] = s2;
    __syncthreads();
    if (threadIdx.x < 32) {
        float S = 0.f, Q = 0.f;
        #pragma unroll
        for (int k = 0; k < 8; ++k) { S += ss[k][threadIdx.x]; Q += qq[k][threadIdx.x]; }
        float mu = S * (1.f / NC);
        float var = Q * (1.f / NC) - mu * mu;
        smu[threadIdx.x] = mu; sinv[threadIdx.x] = rsqrtf(var + 1e-5f);
    }
    __syncthreads();
    float mu = smu[threadIdx.x & 31], inv = sinv[threadIdx.x & 31];
    u16* ob = out + (size_t)b * NC * NPIX + p;
    #pragma unroll
    for (int j = 0; j < 12; ++j) {
        int c = cg * 12 + j;
        ob[(size_t)c * NPIX] = f2u16((v[j] - mu) * inv * g[c] + bta[c]);
    }
}

// load a 1x10 window row (8 aligned + 2 halo) with zero padding (global memory)
__device__ __forceinline__ void load_row_zpad(const u16* ib, int iy, int x0, float a[10]) {
    if (iy < 0 || iy >= NW) {
        #pragma unroll
        for (int k = 0; k < 10; ++k) a[k] = 0.f;
        return;
    }
    const u16* rp = ib + iy * NW;
    uint4 v = *(const uint4*)(rp + x0);
    a[1]=bflo(v.x); a[2]=bfhi(v.x); a[3]=bflo(v.y); a[4]=bfhi(v.y);
    a[5]=bflo(v.z); a[6]=bfhi(v.z); a[7]=bflo(v.w); a[8]=bfhi(v.w);
    a[0] = (x0 > 0)   ? bfu(rp[x0 - 1]) : 0.f;
    a[9] = (x0 < 120) ? bfu(rp[x0 + 8]) : 0.f;
}

// ---------------- depthwise 3x3 (qkv), zero pad, 2 rows x 8 px/thread ----------------
template <bool RELU>
__global__ __launch_bounds__(256) void dwconv3x3_kernel(
    const u16* __restrict__ in, const float* __restrict__ w,
    u16* __restrict__ out, int CHN, int ICN, int idiv) {
    int id = blockIdx.x * 256 + threadIdx.x;
    int ty = id >> 4, tx = id & 15;
    int y0 = ty * 2, x0 = tx * 8;
    int b = blockIdx.y / CHN, oc = blockIdx.y % CHN;
    int ic = oc / idiv;
    const u16* ib = in + ((size_t)b * ICN + ic) * NPIX;
    float a[4][10];
    #pragma unroll
    for (int k = 0; k < 4; ++k) load_row_zpad(ib, y0 - 1 + k, x0, a[k]);
    const float* wr = w + (size_t)oc * 9;
    float w9[9];
    #pragma unroll
    for (int k = 0; k < 9; ++k) w9[k] = wr[k];
    float o0[8], o1[8];
    #pragma unroll
    for (int j = 0; j < 8; ++j) {
        float s0 = 0.f, s1 = 0.f;
        #pragma unroll
        for (int r = 0; r < 3; ++r)
            #pragma unroll
            for (int kx = 0; kx < 3; ++kx) {
                s0 += w9[r * 3 + kx] * a[r][j + kx];
                s1 += w9[r * 3 + kx] * a[r + 1][j + kx];
            }
        o0[j] = RELU ? fmaxf(s0, 0.f) : s0;
        o1[j] = RELU ? fmaxf(s1, 0.f) : s1;
    }
    u16* ob = out + ((size_t)b * CHN + oc) * NPIX + y0 * NW + x0;
    uint4 v0, v1;
    v0.x = packbf(o0[0], o0[1]); v0.y = packbf(o0[2], o0[3]);
    v0.z = packbf(o0[4], o0[5]); v0.w = packbf(o0[6], o0[7]);
    v1.x = packbf(o1[0], o1[1]); v1.y = packbf(o1[2], o1[3]);
    v1.z = packbf(o1[4], o1[5]); v1.w = packbf(o1[6], o1[7]);
    *(uint4*)ob = v0;
    *(uint4*)(ob + NW) = v1;
}

// ---------------- q/k row L2 norms -> reciprocal scales ----------------
__global__ __launch_bounds__(256) void qknorm_kernel(
    const u16* __restrict__ qkv2, float* __restrict__ scales) {
    int r = blockIdx.x;
    int b = r / 192, ch = r % 192;
    const u16* src = qkv2 + ((size_t)b * 288 + ch) * NPIX;
    float s = 0.f;
    for (int p = threadIdx.x * 8; p < NPIX; p += 2048) {
        uint4 v = *(const uint4*)(src + p);
        float f[8];
        f[0]=bflo(v.x); f[1]=bfhi(v.x); f[2]=bflo(v.y); f[3]=bfhi(v.y);
        f[4]=bflo(v.z); f[5]=bfhi(v.z); f[6]=bflo(v.w); f[7]=bfhi(v.w);
        #pragma unroll
        for (int k = 0; k < 8; ++k) s += f[k] * f[k];
    }
    #pragma unroll
    for (int off = 32; off > 0; off >>= 1) s += __shfl_down(s, off, 64);
    __shared__ float part[4];
    int wid = threadIdx.x >> 6;
    if ((threadIdx.x & 63) == 0) part[wid] = s;
    __syncthreads();
    if (threadIdx.x == 0) {
        float tot = part[0] + part[1] + part[2] + part[3];
        scales[r] = 1.f / fmaxf(sqrtf(tot), 1e-12f);
    }
}

// ---------------- attn[b,h,i,:] = scaled q_i . k_j * temperature ----------------
__global__ __launch_bounds__(256) void attn_kernel(
    const u16* __restrict__ qkv2, const float* __restrict__ scales,
    const float* __restrict__ temp, float* __restrict__ attn) {
    int blk = blockIdx.x;
    int i = blk % CHD; int h = (blk / CHD) % NHD; int b = blk / (CHD * NHD);
    const u16* q = qkv2 + ((size_t)b * 288 + h * CHD + i) * NPIX;
    const u16* k = qkv2 + ((size_t)b * 288 + 96 + h * CHD) * NPIX;
    float acc[CHD];
    #pragma unroll
    for (int j = 0; j < CHD; ++j) acc[j] = 0.f;
    for (int p = threadIdx.x * 8; p < NPIX; p += 2048) {
        uint4 qv = *(const uint4*)(q + p);
        float qf[8];
        qf[0]=bflo(qv.x); qf[1]=bfhi(qv.x); qf[2]=bflo(qv.y); qf[3]=bfhi(qv.y);
        qf[4]=bflo(qv.z); qf[5]=bfhi(qv.z); qf[6]=bflo(qv.w); qf[7]=bfhi(qv.w);
        #pragma unroll
        for (int j = 0; j < CHD; ++j) {
            uint4 kv = *(const uint4*)(k + (size_t)j * NPIX + p);
            float s = qf[0]*bflo(kv.x) + qf[1]*bfhi(kv.x) + qf[2]*bflo(kv.y) + qf[3]*bfhi(kv.y)
                    + qf[4]*bflo(kv.z) + qf[5]*bfhi(kv.z) + qf[6]*bflo(kv.w) + qf[7]*bfhi(kv.w);
            acc[j] += s;
        }
    }
    __shared__ float part[4][CHD];
    int wid = threadIdx.x >> 6, lane = threadIdx.x & 63;
    #pragma unroll
    for (int j = 0; j < CHD; ++j) {
        float v = acc[j];
        #pragma unroll
        for (int off = 32; off > 0; off >>= 1) v += __shfl_down(v, off, 64);
        if (lane == 0) part[wid][j] = v;
    }
    __syncthreads();
    if (threadIdx.x < CHD) {
        int j = threadIdx.x;
        float d = part[0][j] + part[1][j] + part[2][j] + part[3][j];
        float val = d * scales[b * 192 + h * CHD + i]
                      * scales[b * 192 + 96 + h * CHD + j] * temp[h];
        attn[(size_t)blk * CHD + j] = val;
    }
}

// ---------------- STS threshold generation + softmax mix ----------------
__global__ __launch_bounds__(256) void sts_kernel(
    const float* __restrict__ attn, const float* __restrict__ tw,
    const float* __restrict__ w1, const float* __restrict__ b1,
    const float* __restrict__ w2, const float* __restrict__ b2,
    float* __restrict__ attn_c) {
    int b = blockIdx.x;
    __shared__ float sat[NHD * CHD * CHD];
    __shared__ float avg[NHD];
    __shared__ float thr[4][NHD];
    for (int idx = threadIdx.x; idx < NHD * CHD * CHD; idx += 256)
        sat[idx] = attn[(size_t)b * NHD * CHD * CHD + idx];
    __syncthreads();
    if (threadIdx.x < NHD) {
        float s = 0.f;
        for (int t = 0; t < CHD * CHD; ++t) s += fabsf(sat[threadIdx.x * CHD * CHD + t]);
        avg[threadIdx.x] = s * (1.f / (CHD * CHD));
    }
    __syncthreads();
    if (threadIdx.x < 4) {
        int s = threadIdx.x;
        float t1[NHD];
        for (int hp = 0; hp < NHD; ++hp) {
            float u = b1[s * NHD + hp];
            for (int h = 0; h < NHD; ++h) u += avg[h] * w1[s * 64 + hp * NHD + h];
            t1[hp] = fmaxf(u, 0.f);
        }
        for (int hp = 0; hp < NHD; ++hp) {
            float u = b2[s * NHD + hp];
            for (int h = 0; h < NHD; ++h) u += t1[h] * w2[s * 64 + hp * NHD + h];
            float gg = 1.f / (1.f + expf(-u));
            thr[s][hp] = avg[hp] * gg;
        }
    }
    __syncthreads();
    if (threadIdx.x < NHD * CHD) {
        int h = threadIdx.x / CHD, i = threadIdx.x % CHD;
        const float* arow = sat + (h * CHD + i) * CHD;
        float acc[CHD];
        #pragma unroll
        for (int j = 0; j < CHD; ++j) acc[j] = 0.f;
        for (int s = 0; s < 4; ++s) {
            float comp[CHD]; float m = -1e30f;
            #pragma unroll
            for (int j = 0; j < CHD; ++j) {
                float a = arow[j];
                float sg = (a > 0.f) ? 1.f : ((a < 0.f) ? -1.f : 0.f);
                float c = sg * fmaxf(fabsf(a) - thr[s][h], 0.f);
                comp[j] = c; m = fmaxf(m, c);
            }
            float sum = 0.f;
            #pragma unroll
            for (int j = 0; j < CHD; ++j) { comp[j] = expf(comp[j] - m); sum += comp[j]; }
            float wts = tw[s] / sum;
            #pragma unroll
            for (int j = 0; j < CHD; ++j) acc[j] += wts * comp[j];
        }
        for (int j = 0; j < CHD; ++j)
            attn_c[(size_t)b * NHD * CHD * CHD + (h * CHD + i) * CHD + j] = acc[j];
    }
}

// ---------------- out = attn_c @ v, 4 px/thread, bf16 out ----------------
__global__ __launch_bounds__(256) void av_kernel(
    const float* __restrict__ attn_c, const u16* __restrict__ qkv2,
    u16* __restrict__ outv) {
    int p0 = (blockIdx.x * 256 + threadIdx.x) * 4;
    int bc = blockIdx.y;
    int b = bc / NC, hc = bc % NC; int h = hc / CHD, i = hc % CHD;
    const float* a = attn_c + ((size_t)(b * NHD + h) * CHD + i) * CHD;
    const u16* v = qkv2 + ((size_t)b * 288 + 192 + h * CHD) * NPIX;
    float av[CHD];
    #pragma unroll
    for (int j = 0; j < CHD; ++j) av[j] = a[j];
    float o[4] = {0.f, 0.f, 0.f, 0.f};
    #pragma unroll
    for (int j = 0; j < CHD; ++j) {
        uint2 t = *(const uint2*)(v + (size_t)j * NPIX + p0);
        o[0] += av[j] * bflo(t.x); o[1] += av[j] * bfhi(t.x);
        o[2] += av[j] * bflo(t.y); o[3] += av[j] * bfhi(t.y);
    }
    uint2 t; t.x = packbf(o[0], o[1]); t.y = packbf(o[2], o[3]);
    *(uint2*)(outv + ((size_t)b * NC + hc) * NPIX + p0) = t;
}

// ---------------- launch ----------------
extern "C" void kernel_launch(void* const* d_in, const int* in_sizes, int n_in,
                              void* d_out, int out_size, void* d_ws, size_t ws_size,
                              hipStream_t stream) {
    const float* x       = (const float*)d_in[0];
    const float* norm1_w = (const float*)d_in[1];
    const float* norm1_b = (const float*)d_in[2];
    const float* qkv_w   = (const float*)d_in[3];
    const float* qkv_dw  = (const float*)d_in[4];
    const float* proj_w  = (const float*)d_in[5];
    const float* temp    = (const float*)d_in[6];
    const float* thw     = (const float*)d_in[7];
    const float* aw1     = (const float*)d_in[8];
    const float* ab1     = (const float*)d_in[9];
    const float* aw2     = (const float*)d_in[10];
    const float* ab2     = (const float*)d_in[11];
    const float* norm2_w = (const float*)d_in[12];
    const float* norm2_b = (const float*)d_in[13];
    const float* in_w    = (const float*)d_in[14];
    const float* main_w  = (const float*)d_in[15];
    const float* lp_w    = (const float*)d_in[16];
    const float* hp_w    = (const float*)d_in[17];
    const float* ld_w    = (const float*)d_in[18];
    const float* hd_w    = (const float*)d_in[19];
    const float* out_w   = (const float*)d_in[20];
    float* out = (float*)d_out;

    // ---- workspace layout ----
    char* ws = (char*)d_ws;
    float* x1    = (float*)(ws + 0);            // 12,582,912 fp32 residual stream
    u16*   xnb   = (u16*)(ws + 12582912);       // 6,291,456  bf16 LN/attn-out
    u16*   qkv1  = (u16*)(ws + 18874368);       // 18,874,368 bf16 [2][288][NPIX]
    u16*   qkv2  = (u16*)(ws + 37748736);       // 18,874,368 bf16 [2][288][NPIX]
    float* scl   = (float*)(ws + 56623104);
    float* attn  = (float*)(ws + 56639488);
    float* attnc = (float*)(ws + 56655872);
    char*  F0    = ws + 56672256;
    const size_t S_full = 33423360, S_pb = 16711680;
    bool full = ws_size >= (size_t)56672256 + S_full;   // 90,095,616

    dim3 blk(256);
    // ---- attention half ----
    ln_kernel<<<dim3(NB * NPIX / 32), blk, 0, stream>>>(x, norm1_w, norm1_b, xnb);
    gemm1x1_kernel<u16, false><<<dim3(128, 5, NB), blk, 0, stream>>>(
        xnb, qkv_w, nullptr, qkv1, 288, 96, (size_t)NC * NPIX, (size_t)288 * NPIX);
    dwconv3x3_kernel<false><<<dim3(4, NB * 288), blk, 0, stream>>>(
        qkv1, qkv_dw, qkv2, 288, 288, 1);
    qknorm_kernel<<<dim3(NB * 192), blk, 0, stream>>>(qkv2, scl);
    attn_kernel<<<dim3(NB * NHD * CHD), blk, 0, stream>>>(qkv2, scl, temp, attn);
    sts_kernel<<<dim3(NB), blk, 0, stream>>>(attn, thw, aw1, ab1, aw2, ab2, attnc);
    av_kernel<<<dim3(16, NB * NC), blk, 0, stream>>>(attnc, qkv2, xnb);
    gemm1x1_kernel<float, true><<<dim3(128, 2, NB), blk, 0, stream>>>(
        xnb, proj_w, x, x1, 96, 96, (size_t)NC * NPIX, (size_t)NC * NPIX);
    // ---- FFN half ----
    ln_kernel<<<dim3(NB * NPIX / 32), blk, 0, stream>>>(x1, norm2_w, norm2_b, xnb);
    if (full) {
        u16* yi  = qkv1;     // 33.4 MB spanning qkv1+qkv2 (dead now)
        u16* cat = (u16*)F0; // separate — blocks read yi while others write cat
        gemm1x1_kernel<u16, false><<<dim3(128, 8, NB), blk, 0, stream>>>(
            xnb, in_w, nullptr, yi, H2C, 96, (size_t)NC * NPIX, (size_t)H2C * NPIX);
        ffnmid_kernel<<<dim3(16, HIDC, NB), blk, 0, stream>>>(
            yi, main_w, lp_w, hp_w, ld_w, hd_w, cat);
        gemm1x1_kernel<float, true><<<dim3(128, 2, NB), blk, 0, stream>>>(
            cat, out_w, x1, out, 96, H2C, (size_t)H2C * NPIX, (size_t)NC * NPIX);
    } else {
        for (int b = 0; b < NB; ++b) {
            u16* yi  = qkv1;
            u16* cat = qkv2;
            gemm1x1_kernel<u16, false><<<dim3(128, 8, 1), blk, 0, stream>>>(
                xnb + (size_t)b * NC * NPIX, in_w, nullptr, yi, H2C, 96, 0, 0);
            ffnmid_kernel<<<dim3(16, HIDC, 1), blk, 0, stream>>>(
                yi, main_w, lp_w, hp_w, ld_w, hd_w, cat);
            gemm1x1_kernel<float, true><<<dim3(128, 2, 1), blk, 0, stream>>>(
                cat, out_w, x1 + (size_t)b * NC * NPIX, out + (size_t)b * NC * NPIX,
                96, H2C, 0, 0);
        }
    }
}

// Round 7
// 474.887 us; speedup vs baseline: 4.2291x; 1.0659x over previous
//
#include <hip/hip_runtime.h>
#include <hip/hip_bf16.h>

// Problem constants
#define NB   2
#define NC   96
#define NW   128
#define NPIX 16384   // 128*128
#define NHD  8
#define CHD  12
#define HIDC 255
#define H2C  510
#define H4C  1020

typedef __hip_bfloat16 bf16;
typedef unsigned short u16;
typedef unsigned int   u32;

typedef __attribute__((ext_vector_type(8))) __bf16 bfrag;
typedef __attribute__((ext_vector_type(4))) float  ffrag;

__device__ __forceinline__ float bfu(u16 u)  { return __uint_as_float(((u32)u) << 16); }
__device__ __forceinline__ float bflo(u32 u) { return __uint_as_float(u << 16); }
__device__ __forceinline__ float bfhi(u32 u) { return __uint_as_float(u & 0xffff0000u); }
__device__ __forceinline__ u16 f2u16(float a) {
    bf16 x = __float2bfloat16(a); return *(u16*)&x;
}
__device__ __forceinline__ u32 packbf(float a, float b) {
    return (u32)f2u16(a) | ((u32)f2u16(b) << 16);
}
__device__ __forceinline__ uint4 pack8(const float o[8]) {
    uint4 r; r.x = packbf(o[0], o[1]); r.y = packbf(o[2], o[3]);
    r.z = packbf(o[4], o[5]); r.w = packbf(o[6], o[7]); return r;
}

// ---- LDS row layout: [8-u16 halo chunk][128 data], stride LSTR=136 u16 (272 B, 16B-mult).
// Left halo (col -1) at index 7; right halo (col 128) stored at index 136 = NEXT row's
// chunk-0 word-0 (no collision: left halo is word 3). One 8-u16 tail chunk per buffer.
// All window reads are 3 aligned ds_read_b128 -> quarter-wave same-row consecutive
// chunks -> bank-conflict-free (fixes R5's 5.6e7 conflicts from unaligned b32s).
#define LSTR 136
__device__ __forceinline__ void lrow10(const u16* rowbase, int seg, float a[10]) {
    const uint4* q = (const uint4*)(rowbase + seg * 8);
    uint4 vL = q[0], v = q[1], vR = q[2];
    a[0] = bfhi(vL.w);
    a[1] = bflo(v.x); a[2] = bfhi(v.x); a[3] = bflo(v.y); a[4] = bfhi(v.y);
    a[5] = bflo(v.z); a[6] = bfhi(v.z); a[7] = bflo(v.w); a[8] = bfhi(v.w);
    a[9] = bflo(vR.x);
}

// ================= fused FFN midsection =================
// yi --main dw+relu--> ym --box(replicate)--> l, hb=ym-l --lp/hp dw+relu-->
// lp,hp --ld/hd(4->1)+relu--> cat. Block = (8-row tile, group g, batch).
__global__ __launch_bounds__(256) void ffnmid_kernel(
    const u16* __restrict__ yi, const float* __restrict__ main_w,
    const float* __restrict__ lp_w, const float* __restrict__ hp_w,
    const float* __restrict__ ld_w, const float* __restrict__ hd_w,
    u16* __restrict__ cat) {
    // u16 offsets (all 16B aligned). yis aliased with lps/hps (disjoint lifetimes).
    const int oLPS = 0;       // [4][10][LSTR]+8 = 5448
    const int oHPS = 5448;    // [4][10][LSTR]+8 -> 10896
    const int oYIS = 0;       // [2][16][LSTR]+8 = 4360  (dead after S2)
    const int oYMS = 10896;   // [4][14][LSTR]+8 = 7624 -> 18520
    const int oLLS = 18520;   // [4][12][LSTR]+8 = 6536 -> 25056
    const int oHBS = 25056;   // [4][12][LSTR]+8 = 6536 -> 31592
    __shared__ __align__(16) u16 lds[31600];
    __shared__ float wts[180];  // [main 36][lp 36][hp 36][ld 36][hd 36]

    int g  = blockIdx.y;
    int y0 = blockIdx.x * 8;
    int tid = threadIdx.x;
    const u16* yib = yi + (size_t)blockIdx.z * H2C * NPIX;
    u16* catb = cat + (size_t)blockIdx.z * H2C * NPIX;

    // ---- weights -> LDS; zero yis region (zero-pad source of truth) ----
    if (tid < 180) {
        int idx = tid; float v;
        if (idx < 36)       v = main_w[(4 * g) * 9 + idx];
        else if (idx < 72)  v = lp_w[(4 * g) * 9 + (idx - 36)];
        else if (idx < 108) v = hp_w[(4 * g) * 9 + (idx - 72)];
        else if (idx < 144) v = ld_w[g * 36 + (idx - 108)];
        else                v = hd_w[g * 36 + (idx - 144)];
        wts[idx] = v;
    }
    {
        u32* z = (u32*)&lds[oYIS];
        #pragma unroll
        for (int k = 0; k < 9; ++k) {
            int i = tid + k * 256;
            if (i < 2180) z[i] = 0;
        }
    }
    __syncthreads();
    // ---- S1: stage yi (2 ch x 16 rows) ----
    #pragma unroll
    for (int k = 0; k < 2; ++k) {
        int t = tid + k * 256;            // 0..511
        int seg = t & 15, s = (t >> 4) & 15, lc = t >> 8;
        int row = y0 - 4 + s;
        if ((unsigned)row < 128u) {
            uint4 v = *(const uint4*)(yib + (size_t)(2 * g + lc) * NPIX + row * NW + seg * 8);
            *(uint4*)&lds[oYIS + (lc * 16 + s) * LSTR + 8 + seg * 8] = v;
        }
    }
    __syncthreads();
    // ---- S2: ym = relu(main conv, zero pad); replicate col halos ----
    for (int t = tid; t < 896; t += 256) {
        int seg = t & 15; int u = t >> 4; int s = u % 14, ii = u / 14;
        int row = y0 - 3 + s;
        if ((unsigned)row >= 128u) continue;  // never read (replicate clamp)
        int lc = ii >> 1;
        const u16* y0p = &lds[oYIS + (lc * 16 + s) * LSTR];
        float a0[10], a1[10], a2[10];
        lrow10(y0p,            seg, a0);
        lrow10(y0p + LSTR,     seg, a1);
        lrow10(y0p + 2 * LSTR, seg, a2);
        const float* w9 = &wts[ii * 9];
        float o[8];
        #pragma unroll
        for (int j = 0; j < 8; ++j) {
            float v = 0.f;
            #pragma unroll
            for (int d = 0; d < 3; ++d)
                v += w9[d] * a0[j + d] + w9[3 + d] * a1[j + d] + w9[6 + d] * a2[j + d];
            o[j] = fmaxf(v, 0.f);
        }
        u16* ymr = &lds[oYMS + (ii * 14 + s) * LSTR];
        *(uint4*)(ymr + 8 + seg * 8) = pack8(o);
        if (seg == 0)  ymr[7]   = f2u16(o[0]);   // replicate left halo
        if (seg == 15) ymr[136] = f2u16(o[7]);   // replicate right halo
    }
    __syncthreads();
    // ---- S3: l = box3x3(ym) replicate pad; hb = ym - l; zero outside image ----
    for (int t = tid; t < 768; t += 256) {
        int seg = t & 15; int u = t >> 4; int s = u % 12, ii = u / 12;
        int row = y0 - 2 + s;
        uint4 lout = make_uint4(0, 0, 0, 0), hout = make_uint4(0, 0, 0, 0);
        if ((unsigned)row < 128u) {
            int r0 = max(row - 1, 0) - (y0 - 3);
            int r1 = row - (y0 - 3);
            int r2 = min(row + 1, 127) - (y0 - 3);
            const u16* ymb = &lds[oYMS + (ii * 14) * LSTR];
            float a0[10], a1[10], a2[10];
            lrow10(ymb + r0 * LSTR, seg, a0);
            lrow10(ymb + r1 * LSTR, seg, a1);
            lrow10(ymb + r2 * LSTR, seg, a2);
            float cs[10];
            #pragma unroll
            for (int n = 0; n < 10; ++n) cs[n] = a0[n] + a1[n] + a2[n];
            float lo[8], ho[8];
            #pragma unroll
            for (int j = 0; j < 8; ++j) {
                float lv = (cs[j] + cs[j + 1] + cs[j + 2]) * (1.f / 9.f);
                lo[j] = lv; ho[j] = a1[j + 1] - lv;
            }
            lout = pack8(lo); hout = pack8(ho);
        }
        u16* llr = &lds[oLLS + (ii * 12 + s) * LSTR];
        u16* hbr = &lds[oHBS + (ii * 12 + s) * LSTR];
        *(uint4*)(llr + 8 + seg * 8) = lout;
        *(uint4*)(hbr + 8 + seg * 8) = hout;
        if (seg == 0)  { llr[7] = 0;   hbr[7] = 0; }
        if (seg == 15) { llr[136] = 0; hbr[136] = 0; }
    }
    __syncthreads();
    // ---- S4: lp = relu(conv(l)), hp = relu(conv(hb)) (both zero pad) ----
    for (int t = tid; t < 1280; t += 256) {
        int kind = t >= 640;
        int r = t - (kind ? 640 : 0);
        int ii = r / 160; int rem = r - ii * 160;
        int s = rem >> 4, seg = rem & 15;
        int row = y0 - 1 + s;
        u16* dst = &lds[(kind ? oHPS : oLPS) + (ii * 10 + s) * LSTR];
        uint4 out = make_uint4(0, 0, 0, 0);
        if ((unsigned)row < 128u) {
            const u16* srcb = &lds[(kind ? oHBS : oLLS) + (ii * 12 + s) * LSTR];
            const float* w9 = &wts[(kind ? 72 : 36) + ii * 9];
            float o[8] = {0.f, 0.f, 0.f, 0.f, 0.f, 0.f, 0.f, 0.f};
            #pragma unroll
            for (int r3 = 0; r3 < 3; ++r3) {
                float a[10];
                lrow10(srcb + r3 * LSTR, seg, a);
                #pragma unroll
                for (int j = 0; j < 8; ++j)
                    o[j] += w9[r3 * 3] * a[j] + w9[r3 * 3 + 1] * a[j + 1]
                          + w9[r3 * 3 + 2] * a[j + 2];
            }
            float oo[8];
            #pragma unroll
            for (int j = 0; j < 8; ++j) oo[j] = fmaxf(o[j], 0.f);
            out = pack8(oo);
        }
        *(uint4*)(dst + 8 + seg * 8) = out;
        if (seg == 0)  dst[7]   = 0;
        if (seg == 15) dst[136] = 0;
    }
    __syncthreads();
    // ---- S5: ld & hd (4->1 grouped conv, zero pad) -> cat ----
    {
        int kind = tid >> 7, s = (tid >> 4) & 7, seg = tid & 15;
        int row = y0 + s;
        const float* w36 = &wts[kind ? 144 : 108];
        float o[8] = {0.f, 0.f, 0.f, 0.f, 0.f, 0.f, 0.f, 0.f};
        #pragma unroll
        for (int ii = 0; ii < 4; ++ii) {
            int ch = 4 * g + ii;
            bool uselp = (ch < H2C) == (kind == 0);
            const u16* rb = &lds[(uselp ? oLPS : oHPS) + (ii * 10 + s) * LSTR];
            #pragma unroll
            for (int r3 = 0; r3 < 3; ++r3) {
                float a[10];
                lrow10(rb + r3 * LSTR, seg, a);
                float wa = w36[ii * 9 + r3 * 3], wb = w36[ii * 9 + r3 * 3 + 1],
                      wc = w36[ii * 9 + r3 * 3 + 2];
                #pragma unroll
                for (int j = 0; j < 8; ++j)
                    o[j] += wa * a[j] + wb * a[j + 1] + wc * a[j + 2];
            }
        }
        float oo[8];
        #pragma unroll
        for (int j = 0; j < 8; ++j) oo[j] = fmaxf(o[j], 0.f);
        int cc = kind ? (HIDC + g) : g;
        *(uint4*)(catb + (size_t)cc * NPIX + row * NW + seg * 8) = pack8(oo);
    }
}

// ================= MFMA GEMM for 1x1 convs =================
template <typename TOut, bool RES>
__global__ __launch_bounds__(256) void gemm1x1_kernel(
    const u16* __restrict__ Bm, const float* __restrict__ Am,
    const float* __restrict__ res, TOut* __restrict__ Cm,
    int M, int K, size_t strideB, size_t strideC) {
    __shared__ u16 Ash[64 * 40];    // [m][k] k-contig, row pad 40
    __shared__ u16 Bsh[128 * 40];   // [n][k] k-contig (transposed), row pad 40
    const u16* Bz = Bm + (size_t)blockIdx.z * strideB;
    int n0 = blockIdx.x * 128;
    int m0 = blockIdx.y * 64;
    int tid = threadIdx.x;
    int w = tid >> 6, l15 = tid & 15, q = (tid & 63) >> 4;
    int amm = tid >> 2, akc = (tid & 3) * 8;
    int bkk = tid >> 3, bs0 = tid & 7;

    ffrag acc[8];
    #pragma unroll
    for (int nt = 0; nt < 8; ++nt)
        #pragma unroll
        for (int e = 0; e < 4; ++e) acc[nt][e] = 0.f;

    for (int k0 = 0; k0 < K; k0 += 32) {
        {
            int gm = m0 + amm;
            float f[8];
            #pragma unroll
            for (int e = 0; e < 8; ++e) {
                int gk = k0 + akc + e;
                f[e] = (gm < M && gk < K) ? Am[(size_t)gm * K + gk] : 0.f;
            }
            u32* dst = (u32*)&Ash[amm * 40 + akc];
            #pragma unroll
            for (int e = 0; e < 4; ++e) dst[e] = packbf(f[2 * e], f[2 * e + 1]);
        }
        {
            int gk = k0 + bkk;
            bool ok = gk < K;
            const u16* src = Bz + (size_t)gk * NPIX + n0;
            #pragma unroll
            for (int pass = 0; pass < 2; ++pass) {
                int nn = (bs0 + pass * 8) * 8;
                if (ok) {
                    uint4 v = *(const uint4*)(src + nn);
                    Bsh[(nn + 0) * 40 + bkk] = (u16)(v.x & 0xffff);
                    Bsh[(nn + 1) * 40 + bkk] = (u16)(v.x >> 16);
                    Bsh[(nn + 2) * 40 + bkk] = (u16)(v.y & 0xffff);
                    Bsh[(nn + 3) * 40 + bkk] = (u16)(v.y >> 16);
                    Bsh[(nn + 4) * 40 + bkk] = (u16)(v.z & 0xffff);
                    Bsh[(nn + 5) * 40 + bkk] = (u16)(v.z >> 16);
                    Bsh[(nn + 6) * 40 + bkk] = (u16)(v.w & 0xffff);
                    Bsh[(nn + 7) * 40 + bkk] = (u16)(v.w >> 16);
                } else {
                    #pragma unroll
                    for (int e = 0; e < 8; ++e) Bsh[(nn + e) * 40 + bkk] = 0;
                }
            }
        }
        __syncthreads();
        bfrag af = *(const bfrag*)&Ash[(w * 16 + l15) * 40 + q * 8];
        #pragma unroll
        for (int nt = 0; nt < 8; ++nt) {
            bfrag bf = *(const bfrag*)&Bsh[(nt * 16 + l15) * 40 + q * 8];
            acc[nt] = __builtin_amdgcn_mfma_f32_16x16x32_bf16(af, bf, acc[nt], 0, 0, 0);
        }
        __syncthreads();
    }
    TOut* Cz = Cm + (size_t)blockIdx.z * strideC;
    const float* rz = res + (RES ? (size_t)blockIdx.z * strideC : 0);
    int mrow = m0 + w * 16 + q * 4;
    #pragma unroll
    for (int nt = 0; nt < 8; ++nt) {
        int col = n0 + nt * 16 + l15;
        #pragma unroll
        for (int r = 0; r < 4; ++r) {
            int row = mrow + r;
            if (row < M) {
                float v = acc[nt][r];
                if (RES) v += rz[(size_t)row * NPIX + col];
                if constexpr (sizeof(TOut) == 2) {
                    ((u16*)Cz)[(size_t)row * NPIX + col] = f2u16(v);
                } else {
                    ((float*)Cz)[(size_t)row * NPIX + col] = v;
                }
            }
        }
    }
}

// ---------------- LayerNorm (fp32 in, bf16 out), channel-split blocks ----------------
__global__ __launch_bounds__(256) void ln_kernel(
    const float* __restrict__ x, const float* __restrict__ g,
    const float* __restrict__ bta, u16* __restrict__ out) {
    int blk = blockIdx.x;
    int b = blk >> 9;
    int p = ((blk & 511) << 5) + (threadIdx.x & 31);
    int cg = threadIdx.x >> 5;
    const float* xb = x + (size_t)b * NC * NPIX + p;
    float v[12]; float s = 0.f, s2 = 0.f;
    #pragma unroll
    for (int j = 0; j < 12; ++j) {
        float t = xb[(size_t)(cg * 12 + j) * NPIX];
        v[j] = t; s += t; s2 += t * t;
    }
    __shared__ float ss[8][32], qq[8][32], smu[32], sinv[32];
    ss[cg][threadIdx.x & 31] = s; qq[cg][threadIdx.x & 31] = s2;
    __syncthreads();
    if (threadIdx.x < 32) {
        float S = 0.f, Q = 0.f;
        #pragma unroll
        for (int k = 0; k < 8; ++k) { S += ss[k][threadIdx.x]; Q += qq[k][threadIdx.x]; }
        float mu = S * (1.f / NC);
        float var = Q * (1.f / NC) - mu * mu;
        smu[threadIdx.x] = mu; sinv[threadIdx.x] = rsqrtf(var + 1e-5f);
    }
    __syncthreads();
    float mu = smu[threadIdx.x & 31], inv = sinv[threadIdx.x & 31];
    u16* ob = out + (size_t)b * NC * NPIX + p;
    #pragma unroll
    for (int j = 0; j < 12; ++j) {
        int c = cg * 12 + j;
        ob[(size_t)c * NPIX] = f2u16((v[j] - mu) * inv * g[c] + bta[c]);
    }
}

// load a 1x10 window row (8 aligned + 2 halo) with zero padding (global memory)
__device__ __forceinline__ void load_row_zpad(const u16* ib, int iy, int x0, float a[10]) {
    if (iy < 0 || iy >= NW) {
        #pragma unroll
        for (int k = 0; k < 10; ++k) a[k] = 0.f;
        return;
    }
    const u16* rp = ib + iy * NW;
    uint4 v = *(const uint4*)(rp + x0);
    a[1]=bflo(v.x); a[2]=bfhi(v.x); a[3]=bflo(v.y); a[4]=bfhi(v.y);
    a[5]=bflo(v.z); a[6]=bfhi(v.z); a[7]=bflo(v.w); a[8]=bfhi(v.w);
    a[0] = (x0 > 0)   ? bfu(rp[x0 - 1]) : 0.f;
    a[9] = (x0 < 120) ? bfu(rp[x0 + 8]) : 0.f;
}

// ---------------- depthwise 3x3 (qkv), zero pad, 4 rows x 8 px/thread ----------------
// grid (2, batches*CHN)
template <bool RELU>
__global__ __launch_bounds__(256) void dwconv3x3_kernel(
    const u16* __restrict__ in, const float* __restrict__ w,
    u16* __restrict__ out, int CHN, int ICN, int idiv) {
    int id = blockIdx.x * 256 + threadIdx.x;   // 0..511
    int ty = id >> 4, tx = id & 15;
    int y0 = ty * 4, x0 = tx * 8;
    int b = blockIdx.y / CHN, oc = blockIdx.y % CHN;
    int ic = oc / idiv;
    const u16* ib = in + ((size_t)b * ICN + ic) * NPIX;
    float a[6][10];
    #pragma unroll
    for (int k = 0; k < 6; ++k) load_row_zpad(ib, y0 - 1 + k, x0, a[k]);
    const float* wr = w + (size_t)oc * 9;
    float w9[9];
    #pragma unroll
    for (int k = 0; k < 9; ++k) w9[k] = wr[k];
    u16* ob = out + ((size_t)b * CHN + oc) * NPIX + y0 * NW + x0;
    #pragma unroll
    for (int jr = 0; jr < 4; ++jr) {
        float o[8];
        #pragma unroll
        for (int j = 0; j < 8; ++j) {
            float s = 0.f;
            #pragma unroll
            for (int r = 0; r < 3; ++r)
                #pragma unroll
                for (int kx = 0; kx < 3; ++kx)
                    s += w9[r * 3 + kx] * a[jr + r][j + kx];
            o[j] = RELU ? fmaxf(s, 0.f) : s;
        }
        *(uint4*)(ob + jr * NW) = pack8(o);
    }
}

// ---------------- q/k row L2 norms -> reciprocal scales ----------------
__global__ __launch_bounds__(256) void qknorm_kernel(
    const u16* __restrict__ qkv2, float* __restrict__ scales) {
    int r = blockIdx.x;
    int b = r / 192, ch = r % 192;
    const u16* src = qkv2 + ((size_t)b * 288 + ch) * NPIX;
    float s = 0.f;
    for (int p = threadIdx.x * 8; p < NPIX; p += 2048) {
        uint4 v = *(const uint4*)(src + p);
        float f[8];
        f[0]=bflo(v.x); f[1]=bfhi(v.x); f[2]=bflo(v.y); f[3]=bfhi(v.y);
        f[4]=bflo(v.z); f[5]=bfhi(v.z); f[6]=bflo(v.w); f[7]=bfhi(v.w);
        #pragma unroll
        for (int k = 0; k < 8; ++k) s += f[k] * f[k];
    }
    #pragma unroll
    for (int off = 32; off > 0; off >>= 1) s += __shfl_down(s, off, 64);
    __shared__ float part[4];
    int wid = threadIdx.x >> 6;
    if ((threadIdx.x & 63) == 0) part[wid] = s;
    __syncthreads();
    if (threadIdx.x == 0) {
        float tot = part[0] + part[1] + part[2] + part[3];
        scales[r] = 1.f / fmaxf(sqrtf(tot), 1e-12f);
    }
}

// ---------------- attn[b,h,i,:] = scaled q_i . k_j * temperature ----------------
__global__ __launch_bounds__(256) void attn_kernel(
    const u16* __restrict__ qkv2, const float* __restrict__ scales,
    const float* __restrict__ temp, float* __restrict__ attn) {
    int blk = blockIdx.x;
    int i = blk % CHD; int h = (blk / CHD) % NHD; int b = blk / (CHD * NHD);
    const u16* q = qkv2 + ((size_t)b * 288 + h * CHD + i) * NPIX;
    const u16* k = qkv2 + ((size_t)b * 288 + 96 + h * CHD) * NPIX;
    float acc[CHD];
    #pragma unroll
    for (int j = 0; j < CHD; ++j) acc[j] = 0.f;
    for (int p = threadIdx.x * 8; p < NPIX; p += 2048) {
        uint4 qv = *(const uint4*)(q + p);
        float qf[8];
        qf[0]=bflo(qv.x); qf[1]=bfhi(qv.x); qf[2]=bflo(qv.y); qf[3]=bfhi(qv.y);
        qf[4]=bflo(qv.z); qf[5]=bfhi(qv.z); qf[6]=bflo(qv.w); qf[7]=bfhi(qv.w);
        #pragma unroll
        for (int j = 0; j < CHD; ++j) {
            uint4 kv = *(const uint4*)(k + (size_t)j * NPIX + p);
            float s = qf[0]*bflo(kv.x) + qf[1]*bfhi(kv.x) + qf[2]*bflo(kv.y) + qf[3]*bfhi(kv.y)
                    + qf[4]*bflo(kv.z) + qf[5]*bfhi(kv.z) + qf[6]*bflo(kv.w) + qf[7]*bfhi(kv.w);
            acc[j] += s;
        }
    }
    __shared__ float part[4][CHD];
    int wid = threadIdx.x >> 6, lane = threadIdx.x & 63;
    #pragma unroll
    for (int j = 0; j < CHD; ++j) {
        float v = acc[j];
        #pragma unroll
        for (int off = 32; off > 0; off >>= 1) v += __shfl_down(v, off, 64);
        if (lane == 0) part[wid][j] = v;
    }
    __syncthreads();
    if (threadIdx.x < CHD) {
        int j = threadIdx.x;
        float d = part[0][j] + part[1][j] + part[2][j] + part[3][j];
        float val = d * scales[b * 192 + h * CHD + i]
                      * scales[b * 192 + 96 + h * CHD + j] * temp[h];
        attn[(size_t)blk * CHD + j] = val;
    }
}

// ---------------- STS threshold generation + softmax mix ----------------
__global__ __launch_bounds__(256) void sts_kernel(
    const float* __restrict__ attn, const float* __restrict__ tw,
    const float* __restrict__ w1, const float* __restrict__ b1,
    const float* __restrict__ w2, const float* __restrict__ b2,
    float* __restrict__ attn_c) {
    int b = blockIdx.x;
    __shared__ float sat[NHD * CHD * CHD];
    __shared__ float avg[NHD];
    __shared__ float thr[4][NHD];
    for (int idx = threadIdx.x; idx < NHD * CHD * CHD; idx += 256)
        sat[idx] = attn[(size_t)b * NHD * CHD * CHD + idx];
    __syncthreads();
    if (threadIdx.x < NHD) {
        float s = 0.f;
        for (int t = 0; t < CHD * CHD; ++t) s += fabsf(sat[threadIdx.x * CHD * CHD + t]);
        avg[threadIdx.x] = s * (1.f / (CHD * CHD));
    }
    __syncthreads();
    if (threadIdx.x < 4) {
        int s = threadIdx.x;
        float t1[NHD];
        for (int hp = 0; hp < NHD; ++hp) {
            float u = b1[s * NHD + hp];
            for (int h = 0; h < NHD; ++h) u += avg[h] * w1[s * 64 + hp * NHD + h];
            t1[hp] = fmaxf(u, 0.f);
        }
        for (int hp = 0; hp < NHD; ++hp) {
            float u = b2[s * NHD + hp];
            for (int h = 0; h < NHD; ++h) u += t1[h] * w2[s * 64 + hp * NHD + h];
            float gg = 1.f / (1.f + expf(-u));
            thr[s][hp] = avg[hp] * gg;
        }
    }
    __syncthreads();
    if (threadIdx.x < NHD * CHD) {
        int h = threadIdx.x / CHD, i = threadIdx.x % CHD;
        const float* arow = sat + (h * CHD + i) * CHD;
        float acc[CHD];
        #pragma unroll
        for (int j = 0; j < CHD; ++j) acc[j] = 0.f;
        for (int s = 0; s < 4; ++s) {
            float comp[CHD]; float m = -1e30f;
            #pragma unroll
            for (int j = 0; j < CHD; ++j) {
                float a = arow[j];
                float sg = (a > 0.f) ? 1.f : ((a < 0.f) ? -1.f : 0.f);
                float c = sg * fmaxf(fabsf(a) - thr[s][h], 0.f);
                comp[j] = c; m = fmaxf(m, c);
            }
            float sum = 0.f;
            #pragma unroll
            for (int j = 0; j < CHD; ++j) { comp[j] = expf(comp[j] - m); sum += comp[j]; }
            float wts2 = tw[s] / sum;
            #pragma unroll
            for (int j = 0; j < CHD; ++j) acc[j] += wts2 * comp[j];
        }
        for (int j = 0; j < CHD; ++j)
            attn_c[(size_t)b * NHD * CHD * CHD + (h * CHD + i) * CHD + j] = acc[j];
    }
}

// ---------------- out = attn_c @ v, 4 px/thread, bf16 out ----------------
__global__ __launch_bounds__(256) void av_kernel(
    const float* __restrict__ attn_c, const u16* __restrict__ qkv2,
    u16* __restrict__ outv) {
    int p0 = (blockIdx.x * 256 + threadIdx.x) * 4;
    int bc = blockIdx.y;
    int b = bc / NC, hc = bc % NC; int h = hc / CHD, i = hc % CHD;
    const float* a = attn_c + ((size_t)(b * NHD + h) * CHD + i) * CHD;
    const u16* v = qkv2 + ((size_t)b * 288 + 192 + h * CHD) * NPIX;
    float av[CHD];
    #pragma unroll
    for (int j = 0; j < CHD; ++j) av[j] = a[j];
    float o[4] = {0.f, 0.f, 0.f, 0.f};
    #pragma unroll
    for (int j = 0; j < CHD; ++j) {
        uint2 t = *(const uint2*)(v + (size_t)j * NPIX + p0);
        o[0] += av[j] * bflo(t.x); o[1] += av[j] * bfhi(t.x);
        o[2] += av[j] * bflo(t.y); o[3] += av[j] * bfhi(t.y);
    }
    uint2 t; t.x = packbf(o[0], o[1]); t.y = packbf(o[2], o[3]);
    *(uint2*)(outv + ((size_t)b * NC + hc) * NPIX + p0) = t;
}

// ---------------- launch ----------------
extern "C" void kernel_launch(void* const* d_in, const int* in_sizes, int n_in,
                              void* d_out, int out_size, void* d_ws, size_t ws_size,
                              hipStream_t stream) {
    const float* x       = (const float*)d_in[0];
    const float* norm1_w = (const float*)d_in[1];
    const float* norm1_b = (const float*)d_in[2];
    const float* qkv_w   = (const float*)d_in[3];
    const float* qkv_dw  = (const float*)d_in[4];
    const float* proj_w  = (const float*)d_in[5];
    const float* temp    = (const float*)d_in[6];
    const float* thw     = (const float*)d_in[7];
    const float* aw1     = (const float*)d_in[8];
    const float* ab1     = (const float*)d_in[9];
    const float* aw2     = (const float*)d_in[10];
    const float* ab2     = (const float*)d_in[11];
    const float* norm2_w = (const float*)d_in[12];
    const float* norm2_b = (const float*)d_in[13];
    const float* in_w    = (const float*)d_in[14];
    const float* main_w  = (const float*)d_in[15];
    const float* lp_w    = (const float*)d_in[16];
    const float* hp_w    = (const float*)d_in[17];
    const float* ld_w    = (const float*)d_in[18];
    const float* hd_w    = (const float*)d_in[19];
    const float* out_w   = (const float*)d_in[20];
    float* out = (float*)d_out;

    // ---- workspace layout ----
    char* ws = (char*)d_ws;
    float* x1    = (float*)(ws + 0);            // 12,582,912 fp32 residual stream
    u16*   xnb   = (u16*)(ws + 12582912);       // 6,291,456  bf16 LN/attn-out
    u16*   qkv1  = (u16*)(ws + 18874368);       // 18,874,368 bf16 [2][288][NPIX]
    u16*   qkv2  = (u16*)(ws + 37748736);       // 18,874,368 bf16 [2][288][NPIX]
    float* scl   = (float*)(ws + 56623104);
    float* attn  = (float*)(ws + 56639488);
    float* attnc = (float*)(ws + 56655872);
    char*  F0    = ws + 56672256;
    const size_t S_full = 33423360, S_pb = 16711680;
    bool full = ws_size >= (size_t)56672256 + S_full;   // 90,095,616

    dim3 blk(256);
    // ---- attention half ----
    ln_kernel<<<dim3(NB * NPIX / 32), blk, 0, stream>>>(x, norm1_w, norm1_b, xnb);
    gemm1x1_kernel<u16, false><<<dim3(128, 5, NB), blk, 0, stream>>>(
        xnb, qkv_w, nullptr, qkv1, 288, 96, (size_t)NC * NPIX, (size_t)288 * NPIX);
    dwconv3x3_kernel<false><<<dim3(2, NB * 288), blk, 0, stream>>>(
        qkv1, qkv_dw, qkv2, 288, 288, 1);
    qknorm_kernel<<<dim3(NB * 192), blk, 0, stream>>>(qkv2, scl);
    attn_kernel<<<dim3(NB * NHD * CHD), blk, 0, stream>>>(qkv2, scl, temp, attn);
    sts_kernel<<<dim3(NB), blk, 0, stream>>>(attn, thw, aw1, ab1, aw2, ab2, attnc);
    av_kernel<<<dim3(16, NB * NC), blk, 0, stream>>>(attnc, qkv2, xnb);
    gemm1x1_kernel<float, true><<<dim3(128, 2, NB), blk, 0, stream>>>(
        xnb, proj_w, x, x1, 96, 96, (size_t)NC * NPIX, (size_t)NC * NPIX);
    // ---- FFN half ----
    ln_kernel<<<dim3(NB * NPIX / 32), blk, 0, stream>>>(x1, norm2_w, norm2_b, xnb);
    if (full) {
        u16* yi  = qkv1;     // 33.4 MB spanning qkv1+qkv2 (dead now)
        u16* cat = (u16*)F0;
        gemm1x1_kernel<u16, false><<<dim3(128, 8, NB), blk, 0, stream>>>(
            xnb, in_w, nullptr, yi, H2C, 96, (size_t)NC * NPIX, (size_t)H2C * NPIX);
        ffnmid_kernel<<<dim3(16, HIDC, NB), blk, 0, stream>>>(
            yi, main_w, lp_w, hp_w, ld_w, hd_w, cat);
        gemm1x1_kernel<float, true><<<dim3(128, 2, NB), blk, 0, stream>>>(
            cat, out_w, x1, out, 96, H2C, (size_t)H2C * NPIX, (size_t)NC * NPIX);
    } else {
        for (int b = 0; b < NB; ++b) {
            u16* yi  = qkv1;
            u16* cat = qkv2;
            gemm1x1_kernel<u16, false><<<dim3(128, 8, 1), blk, 0, stream>>>(
                xnb + (size_t)b * NC * NPIX, in_w, nullptr, yi, H2C, 96, 0, 0);
            ffnmid_kernel<<<dim3(16, HIDC, 1), blk, 0, stream>>>(
                yi, main_w, lp_w, hp_w, ld_w, hd_w, cat);
            gemm1x1_kernel<float, true><<<dim3(128, 2, 1), blk, 0, stream>>>(
                cat, out_w, x1 + (size_t)b * NC * NPIX, out + (size_t)b * NC * NPIX,
                96, H2C, 0, 0);
        }
    }
}

// Round 8
// 465.136 us; speedup vs baseline: 4.3178x; 1.0210x over previous
//
#include <hip/hip_runtime.h>
#include <hip/hip_bf16.h>

// Problem constants
#define NB   2
#define NC   96
#define NW   128
#define NPIX 16384   // 128*128
#define NHD  8
#define CHD  12
#define HIDC 255
#define H2C  510
#define H4C  1020

typedef __hip_bfloat16 bf16;
typedef unsigned short u16;
typedef unsigned int   u32;

typedef __attribute__((ext_vector_type(8))) __bf16 bfrag;
typedef __attribute__((ext_vector_type(4))) float  ffrag;

__device__ __forceinline__ float bfu(u16 u)  { return __uint_as_float(((u32)u) << 16); }
__device__ __forceinline__ float bflo(u32 u) { return __uint_as_float(u << 16); }
__device__ __forceinline__ float bfhi(u32 u) { return __uint_as_float(u & 0xffff0000u); }
__device__ __forceinline__ u16 f2u16(float a) {
    bf16 x = __float2bfloat16(a); return *(u16*)&x;
}
__device__ __forceinline__ u32 packbf(float a, float b) {
    return (u32)f2u16(a) | ((u32)f2u16(b) << 16);
}
__device__ __forceinline__ uint4 pack8(const float o[8]) {
    uint4 r; r.x = packbf(o[0], o[1]); r.y = packbf(o[2], o[3]);
    r.z = packbf(o[4], o[5]); r.w = packbf(o[6], o[7]); return r;
}

// ---- LDS row layout: [8-u16 halo chunk][128 data], stride LSTR=136 u16.
// Left halo (col -1) at idx 7; right halo (col 128) at idx 136 = next row's chunk-0
// word-0. Window reads = 3 aligned ds_read_b128.
#define LSTR 136
__device__ __forceinline__ void lrow10(const u16* rowbase, int seg, float a[10]) {
    const uint4* q = (const uint4*)(rowbase + seg * 8);
    uint4 vL = q[0], v = q[1], vR = q[2];
    a[0] = bfhi(vL.w);
    a[1] = bflo(v.x); a[2] = bfhi(v.x); a[3] = bflo(v.y); a[4] = bfhi(v.y);
    a[5] = bflo(v.z); a[6] = bfhi(v.z); a[7] = bflo(v.w); a[8] = bfhi(v.w);
    a[9] = bflo(vR.x);
}

// ================= fused FFN midsection =================
// yi --main dw+relu--> ym --box(replicate)--> l, hb=ym-l --lp/hp dw+relu-->
// lp,hp --ld/hd(4->1)+relu--> cat. Block = (8-row tile, group g, batch).
// LDS 50.8 KB -> 3 blocks/CU (R6 was 63.2 KB -> 2 blocks/CU).
__global__ __launch_bounds__(256) void ffnmid_kernel(
    const u16* __restrict__ yi, const float* __restrict__ main_w,
    const float* __restrict__ lp_w, const float* __restrict__ hp_w,
    const float* __restrict__ ld_w, const float* __restrict__ hd_w,
    u16* __restrict__ cat) {
    // u16 offsets (16B aligned). yis aliased with lps/hps (disjoint lifetimes).
    const int oLPS = 0;       // [4][10][LSTR]+8 = 5448
    const int oHPS = 5448;    // -> 10896
    const int oYIS = 0;       // [2][16][LSTR]+8 = 4360 (dead after S2)
    const int oYMS = 10896;   // [4][14][LSTR]+8 = 7624 -> 18520
    const int oLLS = 18520;   // [4][12][LSTR]+8 = 6536 -> 25056
    __shared__ __align__(16) u16 lds[25056];
    __shared__ float wts[180];  // [main 36][lp 36][hp 36][ld 36][hd 36]

    int g  = blockIdx.y;
    int y0 = blockIdx.x * 8;
    int tid = threadIdx.x;
    const u16* yib = yi + (size_t)blockIdx.z * H2C * NPIX;
    u16* catb = cat + (size_t)blockIdx.z * H2C * NPIX;

    if (tid < 180) {
        int idx = tid; float v;
        if (idx < 36)       v = main_w[(4 * g) * 9 + idx];
        else if (idx < 72)  v = lp_w[(4 * g) * 9 + (idx - 36)];
        else if (idx < 108) v = hp_w[(4 * g) * 9 + (idx - 72)];
        else if (idx < 144) v = ld_w[g * 36 + (idx - 108)];
        else                v = hd_w[g * 36 + (idx - 144)];
        wts[idx] = v;
    }
    {
        u32* z = (u32*)&lds[oYIS];
        #pragma unroll
        for (int k = 0; k < 9; ++k) {
            int i = tid + k * 256;
            if (i < 2180) z[i] = 0;
        }
    }
    __syncthreads();
    // ---- S1: stage yi (2 ch x 16 rows) ----
    #pragma unroll
    for (int k = 0; k < 2; ++k) {
        int t = tid + k * 256;
        int seg = t & 15, s = (t >> 4) & 15, lc = t >> 8;
        int row = y0 - 4 + s;
        if ((unsigned)row < 128u) {
            uint4 v = *(const uint4*)(yib + (size_t)(2 * g + lc) * NPIX + row * NW + seg * 8);
            *(uint4*)&lds[oYIS + (lc * 16 + s) * LSTR + 8 + seg * 8] = v;
        }
    }
    __syncthreads();
    // ---- S2: ym = relu(main conv, zero pad); replicate col halos ----
    for (int t = tid; t < 896; t += 256) {
        int seg = t & 15; int u = t >> 4; int s = u % 14, ii = u / 14;
        int row = y0 - 3 + s;
        if ((unsigned)row >= 128u) continue;  // out-of-image ym rows never read (masked)
        int lc = ii >> 1;
        const u16* y0p = &lds[oYIS + (lc * 16 + s) * LSTR];
        float a0[10], a1[10], a2[10];
        lrow10(y0p,            seg, a0);
        lrow10(y0p + LSTR,     seg, a1);
        lrow10(y0p + 2 * LSTR, seg, a2);
        const float* w9 = &wts[ii * 9];
        float o[8];
        #pragma unroll
        for (int j = 0; j < 8; ++j) {
            float v = 0.f;
            #pragma unroll
            for (int d = 0; d < 3; ++d)
                v += w9[d] * a0[j + d] + w9[3 + d] * a1[j + d] + w9[6 + d] * a2[j + d];
            o[j] = fmaxf(v, 0.f);
        }
        u16* ymr = &lds[oYMS + (ii * 14 + s) * LSTR];
        *(uint4*)(ymr + 8 + seg * 8) = pack8(o);
        if (seg == 0)  ymr[7]   = f2u16(o[0]);
        if (seg == 15) ymr[136] = f2u16(o[7]);
    }
    __syncthreads();
    // ---- S3: l = box3x3(ym), replicate pad; zero outside image ----
    for (int t = tid; t < 768; t += 256) {
        int seg = t & 15; int u = t >> 4; int s = u % 12, ii = u / 12;
        int row = y0 - 2 + s;
        uint4 lout = make_uint4(0, 0, 0, 0);
        if ((unsigned)row < 128u) {
            int r0 = max(row - 1, 0) - (y0 - 3);
            int r1 = row - (y0 - 3);
            int r2 = min(row + 1, 127) - (y0 - 3);
            const u16* ymb = &lds[oYMS + (ii * 14) * LSTR];
            float a0[10], a1[10], a2[10];
            lrow10(ymb + r0 * LSTR, seg, a0);
            lrow10(ymb + r1 * LSTR, seg, a1);
            lrow10(ymb + r2 * LSTR, seg, a2);
            float cs[10];
            #pragma unroll
            for (int n = 0; n < 10; ++n) cs[n] = a0[n] + a1[n] + a2[n];
            float lo[8];
            #pragma unroll
            for (int j = 0; j < 8; ++j) lo[j] = (cs[j] + cs[j + 1] + cs[j + 2]) * (1.f / 9.f);
            lout = pack8(lo);
        }
        u16* llr = &lds[oLLS + (ii * 12 + s) * LSTR];
        *(uint4*)(llr + 8 + seg * 8) = lout;
        if (seg == 0)  llr[7]   = 0;
        if (seg == 15) llr[136] = 0;
    }
    __syncthreads();
    // ---- S4: lp = relu(conv(l)); hp = relu(conv(hb)), hb = ym - l on the fly ----
    for (int t = tid; t < 1280; t += 256) {
        int kind = t >= 640;
        int r = t - (kind ? 640 : 0);
        int ii = r / 160; int rem = r - ii * 160;
        int s = rem >> 4, seg = rem & 15;
        int row = y0 - 1 + s;
        u16* dst = &lds[(kind ? oHPS : oLPS) + (ii * 10 + s) * LSTR];
        uint4 out = make_uint4(0, 0, 0, 0);
        if ((unsigned)row < 128u) {
            const float* w9 = &wts[(kind ? 72 : 36) + ii * 9];
            float o[8] = {0.f, 0.f, 0.f, 0.f, 0.f, 0.f, 0.f, 0.f};
            if (kind == 0) {
                const u16* srcb = &lds[oLLS + (ii * 12 + s) * LSTR];
                #pragma unroll
                for (int r3 = 0; r3 < 3; ++r3) {
                    float a[10];
                    lrow10(srcb + r3 * LSTR, seg, a);
                    #pragma unroll
                    for (int j = 0; j < 8; ++j)
                        o[j] += w9[r3 * 3] * a[j] + w9[r3 * 3 + 1] * a[j + 1]
                              + w9[r3 * 3 + 2] * a[j + 2];
                }
            } else {
                #pragma unroll
                for (int r3 = 0; r3 < 3; ++r3) {
                    int rr = row - 1 + r3;
                    bool valid = (unsigned)rr < 128u;
                    float al[10], am[10], hb[10];
                    lrow10(&lds[oLLS + (ii * 12 + s + r3) * LSTR],     seg, al);
                    lrow10(&lds[oYMS + (ii * 14 + s + 1 + r3) * LSTR], seg, am);
                    #pragma unroll
                    for (int n = 0; n < 10; ++n) hb[n] = valid ? (am[n] - al[n]) : 0.f;
                    if (seg == 0)  hb[0] = 0.f;   // col -1 zero-pad
                    if (seg == 15) hb[9] = 0.f;   // col 128 zero-pad
                    #pragma unroll
                    for (int j = 0; j < 8; ++j)
                        o[j] += w9[r3 * 3] * hb[j] + w9[r3 * 3 + 1] * hb[j + 1]
                              + w9[r3 * 3 + 2] * hb[j + 2];
                }
            }
            float oo[8];
            #pragma unroll
            for (int j = 0; j < 8; ++j) oo[j] = fmaxf(o[j], 0.f);
            out = pack8(oo);
        }
        *(uint4*)(dst + 8 + seg * 8) = out;
        if (seg == 0)  dst[7]   = 0;
        if (seg == 15) dst[136] = 0;
    }
    __syncthreads();
    // ---- S5: ld & hd (4->1 grouped conv, zero pad) -> cat ----
    {
        int kind = tid >> 7, s = (tid >> 4) & 7, seg = tid & 15;
        int row = y0 + s;
        const float* w36 = &wts[kind ? 144 : 108];
        float o[8] = {0.f, 0.f, 0.f, 0.f, 0.f, 0.f, 0.f, 0.f};
        #pragma unroll
        for (int ii = 0; ii < 4; ++ii) {
            int ch = 4 * g + ii;
            bool uselp = (ch < H2C) == (kind == 0);
            const u16* rb = &lds[(uselp ? oLPS : oHPS) + (ii * 10 + s) * LSTR];
            #pragma unroll
            for (int r3 = 0; r3 < 3; ++r3) {
                float a[10];
                lrow10(rb + r3 * LSTR, seg, a);
                float wa = w36[ii * 9 + r3 * 3], wb = w36[ii * 9 + r3 * 3 + 1],
                      wc = w36[ii * 9 + r3 * 3 + 2];
                #pragma unroll
                for (int j = 0; j < 8; ++j)
                    o[j] += wa * a[j] + wb * a[j + 1] + wc * a[j + 2];
            }
        }
        float oo[8];
        #pragma unroll
        for (int j = 0; j < 8; ++j) oo[j] = fmaxf(o[j], 0.f);
        int cc = kind ? (HIDC + g) : g;
        *(uint4*)(catb + (size_t)cc * NPIX + row * NW + seg * 8) = pack8(oo);
    }
}

// ================= MFMA GEMM for 1x1 convs =================
template <typename TOut, bool RES>
__global__ __launch_bounds__(256) void gemm1x1_kernel(
    const u16* __restrict__ Bm, const float* __restrict__ Am,
    const float* __restrict__ res, TOut* __restrict__ Cm,
    int M, int K, size_t strideB, size_t strideC) {
    __shared__ u16 Ash[64 * 40];
    __shared__ u16 Bsh[128 * 40];
    const u16* Bz = Bm + (size_t)blockIdx.z * strideB;
    int n0 = blockIdx.x * 128;
    int m0 = blockIdx.y * 64;
    int tid = threadIdx.x;
    int w = tid >> 6, l15 = tid & 15, q = (tid & 63) >> 4;
    int amm = tid >> 2, akc = (tid & 3) * 8;
    int bkk = tid >> 3, bs0 = tid & 7;

    ffrag acc[8];
    #pragma unroll
    for (int nt = 0; nt < 8; ++nt)
        #pragma unroll
        for (int e = 0; e < 4; ++e) acc[nt][e] = 0.f;

    for (int k0 = 0; k0 < K; k0 += 32) {
        {
            int gm = m0 + amm;
            float f[8];
            #pragma unroll
            for (int e = 0; e < 8; ++e) {
                int gk = k0 + akc + e;
                f[e] = (gm < M && gk < K) ? Am[(size_t)gm * K + gk] : 0.f;
            }
            u32* dst = (u32*)&Ash[amm * 40 + akc];
            #pragma unroll
            for (int e = 0; e < 4; ++e) dst[e] = packbf(f[2 * e], f[2 * e + 1]);
        }
        {
            int gk = k0 + bkk;
            bool ok = gk < K;
            const u16* src = Bz + (size_t)gk * NPIX + n0;
            #pragma unroll
            for (int pass = 0; pass < 2; ++pass) {
                int nn = (bs0 + pass * 8) * 8;
                if (ok) {
                    uint4 v = *(const uint4*)(src + nn);
                    Bsh[(nn + 0) * 40 + bkk] = (u16)(v.x & 0xffff);
                    Bsh[(nn + 1) * 40 + bkk] = (u16)(v.x >> 16);
                    Bsh[(nn + 2) * 40 + bkk] = (u16)(v.y & 0xffff);
                    Bsh[(nn + 3) * 40 + bkk] = (u16)(v.y >> 16);
                    Bsh[(nn + 4) * 40 + bkk] = (u16)(v.z & 0xffff);
                    Bsh[(nn + 5) * 40 + bkk] = (u16)(v.z >> 16);
                    Bsh[(nn + 6) * 40 + bkk] = (u16)(v.w & 0xffff);
                    Bsh[(nn + 7) * 40 + bkk] = (u16)(v.w >> 16);
                } else {
                    #pragma unroll
                    for (int e = 0; e < 8; ++e) Bsh[(nn + e) * 40 + bkk] = 0;
                }
            }
        }
        __syncthreads();
        bfrag af = *(const bfrag*)&Ash[(w * 16 + l15) * 40 + q * 8];
        #pragma unroll
        for (int nt = 0; nt < 8; ++nt) {
            bfrag bf = *(const bfrag*)&Bsh[(nt * 16 + l15) * 40 + q * 8];
            acc[nt] = __builtin_amdgcn_mfma_f32_16x16x32_bf16(af, bf, acc[nt], 0, 0, 0);
        }
        __syncthreads();
    }
    TOut* Cz = Cm + (size_t)blockIdx.z * strideC;
    const float* rz = res + (RES ? (size_t)blockIdx.z * strideC : 0);
    int mrow = m0 + w * 16 + q * 4;
    #pragma unroll
    for (int nt = 0; nt < 8; ++nt) {
        int col = n0 + nt * 16 + l15;
        #pragma unroll
        for (int r = 0; r < 4; ++r) {
            int row = mrow + r;
            if (row < M) {
                float v = acc[nt][r];
                if (RES) v += rz[(size_t)row * NPIX + col];
                if constexpr (sizeof(TOut) == 2) {
                    ((u16*)Cz)[(size_t)row * NPIX + col] = f2u16(v);
                } else {
                    ((float*)Cz)[(size_t)row * NPIX + col] = v;
                }
            }
        }
    }
}

// ---------------- LayerNorm (fp32 in, bf16 out), channel-split blocks ----------------
__global__ __launch_bounds__(256) void ln_kernel(
    const float* __restrict__ x, const float* __restrict__ g,
    const float* __restrict__ bta, u16* __restrict__ out) {
    int blk = blockIdx.x;
    int b = blk >> 9;
    int p = ((blk & 511) << 5) + (threadIdx.x & 31);
    int cg = threadIdx.x >> 5;
    const float* xb = x + (size_t)b * NC * NPIX + p;
    float v[12]; float s = 0.f, s2 = 0.f;
    #pragma unroll
    for (int j = 0; j < 12; ++j) {
        float t = xb[(size_t)(cg * 12 + j) * NPIX];
        v[j] = t; s += t; s2 += t * t;
    }
    __shared__ float ss[8][32], qq[8][32], smu[32], sinv[32];
    ss[cg][threadIdx.x & 31] = s; qq[cg][threadIdx.x & 31] = s2;
    __syncthreads();
    if (threadIdx.x < 32) {
        float S = 0.f, Q = 0.f;
        #pragma unroll
        for (int k = 0; k < 8; ++k) { S += ss[k][threadIdx.x]; Q += qq[k][threadIdx.x]; }
        float mu = S * (1.f / NC);
        float var = Q * (1.f / NC) - mu * mu;
        smu[threadIdx.x] = mu; sinv[threadIdx.x] = rsqrtf(var + 1e-5f);
    }
    __syncthreads();
    float mu = smu[threadIdx.x & 31], inv = sinv[threadIdx.x & 31];
    u16* ob = out + (size_t)b * NC * NPIX + p;
    #pragma unroll
    for (int j = 0; j < 12; ++j) {
        int c = cg * 12 + j;
        ob[(size_t)c * NPIX] = f2u16((v[j] - mu) * inv * g[c] + bta[c]);
    }
}

// load a 1x10 window row (8 aligned + 2 halo) with zero padding (global memory)
__device__ __forceinline__ void load_row_zpad(const u16* ib, int iy, int x0, float a[10]) {
    if (iy < 0 || iy >= NW) {
        #pragma unroll
        for (int k = 0; k < 10; ++k) a[k] = 0.f;
        return;
    }
    const u16* rp = ib + iy * NW;
    uint4 v = *(const uint4*)(rp + x0);
    a[1]=bflo(v.x); a[2]=bfhi(v.x); a[3]=bflo(v.y); a[4]=bfhi(v.y);
    a[5]=bflo(v.z); a[6]=bfhi(v.z); a[7]=bflo(v.w); a[8]=bfhi(v.w);
    a[0] = (x0 > 0)   ? bfu(rp[x0 - 1]) : 0.f;
    a[9] = (x0 < 120) ? bfu(rp[x0 + 8]) : 0.f;
}

// ---------------- depthwise 3x3 (qkv), zero pad, 4 rows x 8 px/thread ----------------
template <bool RELU>
__global__ __launch_bounds__(256) void dwconv3x3_kernel(
    const u16* __restrict__ in, const float* __restrict__ w,
    u16* __restrict__ out, int CHN, int ICN, int idiv) {
    int id = blockIdx.x * 256 + threadIdx.x;   // 0..511
    int ty = id >> 4, tx = id & 15;
    int y0 = ty * 4, x0 = tx * 8;
    int b = blockIdx.y / CHN, oc = blockIdx.y % CHN;
    int ic = oc / idiv;
    const u16* ib = in + ((size_t)b * ICN + ic) * NPIX;
    float a[6][10];
    #pragma unroll
    for (int k = 0; k < 6; ++k) load_row_zpad(ib, y0 - 1 + k, x0, a[k]);
    const float* wr = w + (size_t)oc * 9;
    float w9[9];
    #pragma unroll
    for (int k = 0; k < 9; ++k) w9[k] = wr[k];
    u16* ob = out + ((size_t)b * CHN + oc) * NPIX + y0 * NW + x0;
    #pragma unroll
    for (int jr = 0; jr < 4; ++jr) {
        float o[8];
        #pragma unroll
        for (int j = 0; j < 8; ++j) {
            float s = 0.f;
            #pragma unroll
            for (int r = 0; r < 3; ++r)
                #pragma unroll
                for (int kx = 0; kx < 3; ++kx)
                    s += w9[r * 3 + kx] * a[jr + r][j + kx];
            o[j] = RELU ? fmaxf(s, 0.f) : s;
        }
        *(uint4*)(ob + jr * NW) = pack8(o);
    }
}

// ---------------- q/k row L2 norms -> reciprocal scales ----------------
__global__ __launch_bounds__(256) void qknorm_kernel(
    const u16* __restrict__ qkv2, float* __restrict__ scales) {
    int r = blockIdx.x;
    int b = r / 192, ch = r % 192;
    const u16* src = qkv2 + ((size_t)b * 288 + ch) * NPIX;
    float s = 0.f;
    for (int p = threadIdx.x * 8; p < NPIX; p += 2048) {
        uint4 v = *(const uint4*)(src + p);
        float f[8];
        f[0]=bflo(v.x); f[1]=bfhi(v.x); f[2]=bflo(v.y); f[3]=bfhi(v.y);
        f[4]=bflo(v.z); f[5]=bfhi(v.z); f[6]=bflo(v.w); f[7]=bfhi(v.w);
        #pragma unroll
        for (int k = 0; k < 8; ++k) s += f[k] * f[k];
    }
    #pragma unroll
    for (int off = 32; off > 0; off >>= 1) s += __shfl_down(s, off, 64);
    __shared__ float part[4];
    int wid = threadIdx.x >> 6;
    if ((threadIdx.x & 63) == 0) part[wid] = s;
    __syncthreads();
    if (threadIdx.x == 0) {
        float tot = part[0] + part[1] + part[2] + part[3];
        scales[r] = 1.f / fmaxf(sqrtf(tot), 1e-12f);
    }
}

// ---------------- raw attn dots, 4-way pixel split + atomicAdd ----------------
// attn_raw must be zeroed before launch. Scales/temperature applied in sts_kernel.
__global__ __launch_bounds__(256) void attn_kernel(
    const u16* __restrict__ qkv2, float* __restrict__ attn_raw) {
    int blk = blockIdx.y;  // ((b*NHD+h)*CHD+i)
    int slice = blockIdx.x;
    int i = blk % CHD; int h = (blk / CHD) % NHD; int b = blk / (CHD * NHD);
    const u16* q = qkv2 + ((size_t)b * 288 + h * CHD + i) * NPIX;
    const u16* k = qkv2 + ((size_t)b * 288 + 96 + h * CHD) * NPIX;
    float acc[CHD];
    #pragma unroll
    for (int j = 0; j < CHD; ++j) acc[j] = 0.f;
    int p0 = slice * 4096;
    #pragma unroll
    for (int it = 0; it < 2; ++it) {
        int p = p0 + it * 2048 + threadIdx.x * 8;
        uint4 qv = *(const uint4*)(q + p);
        float qf[8];
        qf[0]=bflo(qv.x); qf[1]=bfhi(qv.x); qf[2]=bflo(qv.y); qf[3]=bfhi(qv.y);
        qf[4]=bflo(qv.z); qf[5]=bfhi(qv.z); qf[6]=bflo(qv.w); qf[7]=bfhi(qv.w);
        #pragma unroll
        for (int j = 0; j < CHD; ++j) {
            uint4 kv = *(const uint4*)(k + (size_t)j * NPIX + p);
            float s = qf[0]*bflo(kv.x) + qf[1]*bfhi(kv.x) + qf[2]*bflo(kv.y) + qf[3]*bfhi(kv.y)
                    + qf[4]*bflo(kv.z) + qf[5]*bfhi(kv.z) + qf[6]*bflo(kv.w) + qf[7]*bfhi(kv.w);
            acc[j] += s;
        }
    }
    __shared__ float part[4][CHD];
    int wid = threadIdx.x >> 6, lane = threadIdx.x & 63;
    #pragma unroll
    for (int j = 0; j < CHD; ++j) {
        float v = acc[j];
        #pragma unroll
        for (int off = 32; off > 0; off >>= 1) v += __shfl_down(v, off, 64);
        if (lane == 0) part[wid][j] = v;
    }
    __syncthreads();
    if (threadIdx.x < CHD) {
        int j = threadIdx.x;
        float d = part[0][j] + part[1][j] + part[2][j] + part[3][j];
        atomicAdd(&attn_raw[(size_t)blk * CHD + j], d);
    }
}

// ---------------- STS: scale raw dots, thresholds, softmax mix ----------------
__global__ __launch_bounds__(256) void sts_kernel(
    const float* __restrict__ attn, const float* __restrict__ scl,
    const float* __restrict__ temp, const float* __restrict__ tw,
    const float* __restrict__ w1, const float* __restrict__ b1,
    const float* __restrict__ w2, const float* __restrict__ b2,
    float* __restrict__ attn_c) {
    int b = blockIdx.x;
    __shared__ float sat[NHD * CHD * CHD];
    __shared__ float avg[NHD];
    __shared__ float thr[4][NHD];
    for (int idx = threadIdx.x; idx < NHD * CHD * CHD; idx += 256) {
        int h = idx / (CHD * CHD); int r = idx % (CHD * CHD);
        int i = r / CHD, j = r % CHD;
        sat[idx] = attn[(size_t)b * NHD * CHD * CHD + idx]
                 * scl[b * 192 + h * CHD + i] * scl[b * 192 + 96 + h * CHD + j] * temp[h];
    }
    __syncthreads();
    if (threadIdx.x < NHD) {
        float s = 0.f;
        for (int t = 0; t < CHD * CHD; ++t) s += fabsf(sat[threadIdx.x * CHD * CHD + t]);
        avg[threadIdx.x] = s * (1.f / (CHD * CHD));
    }
    __syncthreads();
    if (threadIdx.x < 4) {
        int s = threadIdx.x;
        float t1[NHD];
        for (int hp = 0; hp < NHD; ++hp) {
            float u = b1[s * NHD + hp];
            for (int h = 0; h < NHD; ++h) u += avg[h] * w1[s * 64 + hp * NHD + h];
            t1[hp] = fmaxf(u, 0.f);
        }
        for (int hp = 0; hp < NHD; ++hp) {
            float u = b2[s * NHD + hp];
            for (int h = 0; h < NHD; ++h) u += t1[h] * w2[s * 64 + hp * NHD + h];
            float gg = 1.f / (1.f + expf(-u));
            thr[s][hp] = avg[hp] * gg;
        }
    }
    __syncthreads();
    if (threadIdx.x < NHD * CHD) {
        int h = threadIdx.x / CHD, i = threadIdx.x % CHD;
        const float* arow = sat + (h * CHD + i) * CHD;
        float acc[CHD];
        #pragma unroll
        for (int j = 0; j < CHD; ++j) acc[j] = 0.f;
        for (int s = 0; s < 4; ++s) {
            float comp[CHD]; float m = -1e30f;
            #pragma unroll
            for (int j = 0; j < CHD; ++j) {
                float a = arow[j];
                float sg = (a > 0.f) ? 1.f : ((a < 0.f) ? -1.f : 0.f);
                float c = sg * fmaxf(fabsf(a) - thr[s][h], 0.f);
                comp[j] = c; m = fmaxf(m, c);
            }
            float sum = 0.f;
            #pragma unroll
            for (int j = 0; j < CHD; ++j) { comp[j] = expf(comp[j] - m); sum += comp[j]; }
            float wts2 = tw[s] / sum;
            #pragma unroll
            for (int j = 0; j < CHD; ++j) acc[j] += wts2 * comp[j];
        }
        for (int j = 0; j < CHD; ++j)
            attn_c[(size_t)b * NHD * CHD * CHD + (h * CHD + i) * CHD + j] = acc[j];
    }
}

// ---------------- out = attn_c @ v, 4 px/thread, bf16 out ----------------
__global__ __launch_bounds__(256) void av_kernel(
    const float* __restrict__ attn_c, const u16* __restrict__ qkv2,
    u16* __restrict__ outv) {
    int p0 = (blockIdx.x * 256 + threadIdx.x) * 4;
    int bc = blockIdx.y;
    int b = bc / NC, hc = bc % NC; int h = hc / CHD, i = hc % CHD;
    const float* a = attn_c + ((size_t)(b * NHD + h) * CHD + i) * CHD;
    const u16* v = qkv2 + ((size_t)b * 288 + 192 + h * CHD) * NPIX;
    float av[CHD];
    #pragma unroll
    for (int j = 0; j < CHD; ++j) av[j] = a[j];
    float o[4] = {0.f, 0.f, 0.f, 0.f};
    #pragma unroll
    for (int j = 0; j < CHD; ++j) {
        uint2 t = *(const uint2*)(v + (size_t)j * NPIX + p0);
        o[0] += av[j] * bflo(t.x); o[1] += av[j] * bfhi(t.x);
        o[2] += av[j] * bflo(t.y); o[3] += av[j] * bfhi(t.y);
    }
    uint2 t; t.x = packbf(o[0], o[1]); t.y = packbf(o[2], o[3]);
    *(uint2*)(outv + ((size_t)b * NC + hc) * NPIX + p0) = t;
}

// ---------------- launch ----------------
extern "C" void kernel_launch(void* const* d_in, const int* in_sizes, int n_in,
                              void* d_out, int out_size, void* d_ws, size_t ws_size,
                              hipStream_t stream) {
    const float* x       = (const float*)d_in[0];
    const float* norm1_w = (const float*)d_in[1];
    const float* norm1_b = (const float*)d_in[2];
    const float* qkv_w   = (const float*)d_in[3];
    const float* qkv_dw  = (const float*)d_in[4];
    const float* proj_w  = (const float*)d_in[5];
    const float* temp    = (const float*)d_in[6];
    const float* thw     = (const float*)d_in[7];
    const float* aw1     = (const float*)d_in[8];
    const float* ab1     = (const float*)d_in[9];
    const float* aw2     = (const float*)d_in[10];
    const float* ab2     = (const float*)d_in[11];
    const float* norm2_w = (const float*)d_in[12];
    const float* norm2_b = (const float*)d_in[13];
    const float* in_w    = (const float*)d_in[14];
    const float* main_w  = (const float*)d_in[15];
    const float* lp_w    = (const float*)d_in[16];
    const float* hp_w    = (const float*)d_in[17];
    const float* ld_w    = (const float*)d_in[18];
    const float* hd_w    = (const float*)d_in[19];
    const float* out_w   = (const float*)d_in[20];
    float* out = (float*)d_out;

    // ---- workspace layout ----
    char* ws = (char*)d_ws;
    float* x1    = (float*)(ws + 0);            // 12,582,912 fp32 residual stream
    u16*   xnb   = (u16*)(ws + 12582912);       // 6,291,456  bf16 LN/attn-out
    u16*   qkv1  = (u16*)(ws + 18874368);       // 18,874,368 bf16 [2][288][NPIX]
    u16*   qkv2  = (u16*)(ws + 37748736);       // 18,874,368 bf16 [2][288][NPIX]
    float* scl   = (float*)(ws + 56623104);
    float* attn  = (float*)(ws + 56639488);
    float* attnc = (float*)(ws + 56655872);
    char*  F0    = ws + 56672256;
    const size_t S_full = 33423360;
    bool full = ws_size >= (size_t)56672256 + S_full;   // 90,095,616

    dim3 blk(256);
    // ---- attention half ----
    ln_kernel<<<dim3(NB * NPIX / 32), blk, 0, stream>>>(x, norm1_w, norm1_b, xnb);
    gemm1x1_kernel<u16, false><<<dim3(128, 5, NB), blk, 0, stream>>>(
        xnb, qkv_w, nullptr, qkv1, 288, 96, (size_t)NC * NPIX, (size_t)288 * NPIX);
    dwconv3x3_kernel<false><<<dim3(2, NB * 288), blk, 0, stream>>>(
        qkv1, qkv_dw, qkv2, 288, 288, 1);
    qknorm_kernel<<<dim3(NB * 192), blk, 0, stream>>>(qkv2, scl);
    hipMemsetAsync(attn, 0, (size_t)NB * NHD * CHD * CHD * sizeof(float), stream);
    attn_kernel<<<dim3(4, NB * NHD * CHD), blk, 0, stream>>>(qkv2, attn);
    sts_kernel<<<dim3(NB), blk, 0, stream>>>(attn, scl, temp, thw, aw1, ab1, aw2, ab2, attnc);
    av_kernel<<<dim3(16, NB * NC), blk, 0, stream>>>(attnc, qkv2, xnb);
    gemm1x1_kernel<float, true><<<dim3(128, 2, NB), blk, 0, stream>>>(
        xnb, proj_w, x, x1, 96, 96, (size_t)NC * NPIX, (size_t)NC * NPIX);
    // ---- FFN half ----
    ln_kernel<<<dim3(NB * NPIX / 32), blk, 0, stream>>>(x1, norm2_w, norm2_b, xnb);
    if (full) {
        u16* yi  = qkv1;     // 33.4 MB spanning qkv1+qkv2 (dead now)
        u16* cat = (u16*)F0;
        gemm1x1_kernel<u16, false><<<dim3(128, 8, NB), blk, 0, stream>>>(
            xnb, in_w, nullptr, yi, H2C, 96, (size_t)NC * NPIX, (size_t)H2C * NPIX);
        ffnmid_kernel<<<dim3(16, HIDC, NB), blk, 0, stream>>>(
            yi, main_w, lp_w, hp_w, ld_w, hd_w, cat);
        gemm1x1_kernel<float, true><<<dim3(128, 2, NB), blk, 0, stream>>>(
            cat, out_w, x1, out, 96, H2C, (size_t)H2C * NPIX, (size_t)NC * NPIX);
    } else {
        for (int b = 0; b < NB; ++b) {
            u16* yi  = qkv1;
            u16* cat = qkv2;
            gemm1x1_kernel<u16, false><<<dim3(128, 8, 1), blk, 0, stream>>>(
                xnb + (size_t)b * NC * NPIX, in_w, nullptr, yi, H2C, 96, 0, 0);
            ffnmid_kernel<<<dim3(16, HIDC, 1), blk, 0, stream>>>(
                yi, main_w, lp_w, hp_w, ld_w, hd_w, cat);
            gemm1x1_kernel<float, true><<<dim3(128, 2, 1), blk, 0, stream>>>(
                cat, out_w, x1 + (size_t)b * NC * NPIX, out + (size_t)b * NC * NPIX,
                96, H2C, 0, 0);
        }
    }
}